// Round 10
// baseline (715.940 us; speedup 1.0000x reference)
//
#include <hip/hip_runtime.h>
#include <hip/hip_bf16.h>

#define Bsz 4
#define Tt 2048
#define Ll 4096
#define NC 256     // chunks for scan
#define CH 16      // steps per chunk (NC*CH == Ll)

typedef short bf16x8 __attribute__((ext_vector_type(8)));
typedef float f32x4 __attribute__((ext_vector_type(4)));

static __device__ __forceinline__ float bs2f(unsigned short u){
  union{float f; unsigned int i;} v; v.i = ((unsigned int)u)<<16; return v.f;
}
static __device__ __forceinline__ unsigned short f2bs(float f){
  union{float f; unsigned int i;} v; v.f = f;
  unsigned int r = (v.i + 0x7fffu + ((v.i>>16)&1u)) >> 16;
  return (unsigned short)r;
}

// fp32 -> bf16 bulk convert
__global__ void k_cvt(const float* __restrict__ src, unsigned short* __restrict__ dst, int n){
  int i = blockIdx.x*256 + threadIdx.x;
  if (i < n) dst[i] = f2bs(src[i]);
}

// pad xproj_w (4 branches, 40x256) to zero-filled 64x256 bf16
__global__ void k_prepx(const float* __restrict__ xw, unsigned short* __restrict__ wxb){
  int row = blockIdx.x, br = blockIdx.y, col = threadIdx.x;
  float v = (row < 40) ? xw[((size_t)br*40 + row)*256 + col] : 0.f;
  wxb[((size_t)br*64 + row)*256 + col] = f2bs(v);
}

// ---------------------------------------------------------------------------
// Compose upsample-conv weights with fuse matmul; emit bf16 GEMM-ready layouts.
// ---------------------------------------------------------------------------
__global__ void k_compose(const float* __restrict__ up_w, const float* __restrict__ fus_w,
                          const float* __restrict__ fus_b, const float* __restrict__ up_b,
                          unsigned short* __restrict__ WEb, unsigned short* __restrict__ WOb,
                          unsigned short* __restrict__ FWSb, float* __restrict__ BIAS2){
  int i = blockIdx.x;     // 0..255
  int o = threadIdx.x;    // 0..127
  float a0=0.f,a1=0.f,a2=0.f,a3=0.f,a4=0.f;
  for (int c=0;c<256;c++){
    float f = fus_w[o*384+c];
    const float* w = up_w + ((size_t)i*256+c)*5;
    a0 += f*w[0]; a1 += f*w[1]; a2 += f*w[2];
    a3 += f*w[3]; a4 += f*w[4];
  }
  WEb[(size_t)o*768 +       i] = f2bs(a4);
  WEb[(size_t)o*768 + 256 + i] = f2bs(a2);
  WEb[(size_t)o*768 + 512 + i] = f2bs(a0);
  WOb[(size_t)o*512 +       i] = f2bs(a3);
  WOb[(size_t)o*512 + 256 + i] = f2bs(a1);
  if (i<128) FWSb[o*128 + i] = f2bs(fus_w[o*384+256+i]);
  if (i==0){
    float bb = fus_b[o];
    for (int c=0;c<256;c++) bb += fus_w[o*384+c]*up_b[c];
    BIAS2[o]=bb;
  }
}

// transpose x (B,256,T) f32 -> XT (B, T+2, 256) bf16, row t stored at t+1
__global__ __launch_bounds__(256) void k_tx(const float* __restrict__ x, unsigned short* __restrict__ XT){
  __shared__ float tile[64][65];
  int b=blockIdx.z, t0=blockIdx.x*64, i0=blockIdx.y*64;
  int tid=threadIdx.x;
  for (int it=0;it<16;it++){
    int idx=it*256+tid; int ii=idx>>6, tt=idx&63;
    tile[ii][tt] = x[((size_t)b*256+i0+ii)*Tt + t0+tt];
  }
  __syncthreads();
  for (int it=0;it<16;it++){
    int idx=it*256+tid; int tt=idx>>6, ii=idx&63;
    XT[((size_t)b*2050 + t0+tt+1)*256 + i0+ii] = f2bs(tile[ii][tt]);
  }
}

// zero XT halo rows (t=-1 and t=2048)
__global__ void k_zero(unsigned short* __restrict__ XT){
  int tid=threadIdx.x;
  for (int b=0;b<Bsz;b++){
    XT[((size_t)b*2050)*256 + tid] = 0;
    XT[((size_t)b*2050+2049)*256 + tid] = 0;
  }
}

// transpose skip (B,128,L) f32 -> SKT (B,L,128) bf16
__global__ __launch_bounds__(256) void k_ts(const float* __restrict__ skip, unsigned short* __restrict__ SKT){
  __shared__ float tile[64][65];
  int b=blockIdx.z, l0=blockIdx.x*64, s0=blockIdx.y*64;
  int tid=threadIdx.x;
  for (int it=0;it<16;it++){
    int idx=it*256+tid; int ss=idx>>6, ll=idx&63;
    tile[ss][ll] = skip[((size_t)b*128+s0+ss)*Ll + l0+ll];
  }
  __syncthreads();
  for (int it=0;it<16;it++){
    int idx=it*256+tid; int ll=idx>>6, ss=idx&63;
    SKT[((size_t)b*Ll + l0+ll)*128 + s0+ss] = f2bs(tile[ss][ll]);
  }
}

// ---------------------------------------------------------------------------
// MFMA upsample+fuse (see round-4 notes). Block = 64 t x 128 o, one parity.
// ---------------------------------------------------------------------------
__global__ __launch_bounds__(256) void k_up(const unsigned short* __restrict__ XT,
                     const unsigned short* __restrict__ SKT,
                     const unsigned short* __restrict__ WEb, const unsigned short* __restrict__ WOb,
                     const unsigned short* __restrict__ FWSb, const float* __restrict__ B2,
                     float* __restrict__ h0, float* __restrict__ gst){
  __shared__ unsigned short XL[66*264];
  __shared__ unsigned short Wb[128*72];
  __shared__ float red0[256], red1[256];
  int bt = blockIdx.x, par = blockIdx.y, b = blockIdx.z;
  int t0 = bt*64;
  int tid = threadIdx.x;
  int wave = tid>>6, lane = tid&63;
  int wm = wave>>1, wn = wave&1;
  int quad = lane>>4, l16 = lane&15;

  for (int idx=tid; idx<66*32; idx+=256){
    int row = idx>>5, c8 = idx&31;
    *(uint4*)&XL[row*264 + c8*8] = *(const uint4*)&XT[((size_t)b*2050 + t0 + row)*256 + c8*8];
  }

  const unsigned short* Wsrc = par ? WOb : WEb;
  const int Kw = par ? 512 : 768;
  const int tapbase = par ? 1 : 0;
  f32x4 acc[2][4];
  #pragma unroll
  for (int i=0;i<2;i++)
    #pragma unroll
    for (int j=0;j<4;j++) acc[i][j] = (f32x4){0.f,0.f,0.f,0.f};

  int nch = Kw>>6;
  for (int kc=0; kc<nch; kc++){
    __syncthreads();
    #pragma unroll
    for (int it=0; it<4; it++){
      int idx = it*256+tid;
      int row = idx>>3, c8 = idx&7;
      *(uint4*)&Wb[row*72 + c8*8] = *(const uint4*)&Wsrc[(size_t)row*Kw + kc*64 + c8*8];
    }
    __syncthreads();
    #pragma unroll
    for (int ks=0; ks<64; ks+=32){
      int kg = kc*64 + ks;
      int tap = kg>>8, ib = kg&255;
      bf16x8 af[2], bf[4];
      #pragma unroll
      for (int mt=0;mt<2;mt++)
        af[mt] = *(bf16x8*)&XL[(wm*32+mt*16+l16 + tapbase + tap)*264 + ib + quad*8];
      #pragma unroll
      for (int nt=0;nt<4;nt++)
        bf[nt] = *(bf16x8*)&Wb[(wn*64+nt*16+l16)*72 + ks + quad*8];
      #pragma unroll
      for (int mt=0;mt<2;mt++)
        #pragma unroll
        for (int nt=0;nt<4;nt++)
          acc[mt][nt] = __builtin_amdgcn_mfma_f32_16x16x32_bf16(af[mt], bf[nt], acc[mt][nt], 0,0,0);
    }
  }

  __syncthreads();
  for (int idx=tid; idx<64*16; idx+=256){
    int row = idx>>4, c8 = idx&15;
    *(uint4*)&XL[row*136 + c8*8] = *(const uint4*)&SKT[((size_t)b*Ll + 2*(t0+row)+par)*128 + c8*8];
  }
  for (int kc=0; kc<2; kc++){
    __syncthreads();
    #pragma unroll
    for (int it=0; it<4; it++){
      int idx = it*256+tid;
      int row = idx>>3, c8 = idx&7;
      *(uint4*)&Wb[row*72 + c8*8] = *(const uint4*)&FWSb[(size_t)row*128 + kc*64 + c8*8];
    }
    __syncthreads();
    #pragma unroll
    for (int ks=0; ks<64; ks+=32){
      bf16x8 af[2], bf[4];
      #pragma unroll
      for (int mt=0;mt<2;mt++)
        af[mt] = *(bf16x8*)&XL[(wm*32+mt*16+l16)*136 + kc*64 + ks + quad*8];
      #pragma unroll
      for (int nt=0;nt<4;nt++)
        bf[nt] = *(bf16x8*)&Wb[(wn*64+nt*16+l16)*72 + ks + quad*8];
      #pragma unroll
      for (int mt=0;mt<2;mt++)
        #pragma unroll
        for (int nt=0;nt<4;nt++)
          acc[mt][nt] = __builtin_amdgcn_mfma_f32_16x16x32_bf16(af[mt], bf[nt], acc[mt][nt], 0,0,0);
    }
  }

  float s1=0.f, s2=0.f;
  #pragma unroll
  for (int mt=0;mt<2;mt++)
    #pragma unroll
    for (int nt=0;nt<4;nt++)
      #pragma unroll
      for (int r=0;r<4;r++){
        int m = wm*32 + mt*16 + quad*4 + r;
        int lrow = 2*(t0+m) + par;
        int col = wn*64 + nt*16 + l16;
        float v = acc[mt][nt][r] + B2[col];
        h0[((size_t)b*Ll + lrow)*128 + col] = v;
        s1 += v; s2 += v*v;
      }
  red0[tid]=s1; red1[tid]=s2;
  __syncthreads();
  for (int st=128; st>0; st>>=1){
    if (tid<st){ red0[tid]+=red0[tid+st]; red1[tid]+=red1[tid+st]; }
    __syncthreads();
  }
  if (tid==0){ atomicAdd(&gst[b*2], red0[0]); atomicAdd(&gst[b*2+1], red1[0]); }
}

__global__ void k_gnfin(float* gst){
  int b = threadIdx.x;
  if (b < Bsz){
    float n = (float)Ll*128.f;
    float mu = gst[b*2]/n;
    float var = gst[b*2+1]/n - mu*mu;
    gst[8+b]=mu; gst[12+b]=rsqrtf(var+1e-5f);
  }
}

// Fused GroupNorm-apply + PReLU + layer-0 LayerNorm.
// 4 rows/block, one wave per row. Writes HR (fp32) and XNB (bf16).
__global__ __launch_bounds__(256) void k_gnln(const float* __restrict__ h0, const float* __restrict__ gn_w,
                      const float* __restrict__ gn_b, const float* __restrict__ pa,
                      const float* __restrict__ gst, const float* __restrict__ lnw,
                      const float* __restrict__ lnb, float* __restrict__ hres,
                      unsigned short* __restrict__ xn){
  int row = blockIdx.x*4 + (threadIdx.x>>6);
  int lane = threadIdx.x & 63;
  int b = row >> 12;
  float mu_g = gst[8+b], inv_g = gst[12+b];
  float a = pa[0];
  const float* hp = h0 + (size_t)row*128;
  float u0 = (hp[lane]   -mu_g)*inv_g*gn_w[lane]    + gn_b[lane];
  float u1 = (hp[lane+64]-mu_g)*inv_g*gn_w[lane+64] + gn_b[lane+64];
  float v0 = u0>=0.f ? u0 : a*u0;
  float v1 = u1>=0.f ? u1 : a*u1;
  float* rp = hres + (size_t)row*128;
  rp[lane] = v0; rp[lane+64] = v1;
  float s = v0+v1, q = v0*v0+v1*v1;
  #pragma unroll
  for (int off=32; off>0; off>>=1){
    s += __shfl_xor(s, off, 64);
    q += __shfl_xor(q, off, 64);
  }
  float mu = s*(1.f/128.f);
  float rs = rsqrtf(q*(1.f/128.f)-mu*mu + 1e-5f);
  unsigned short* xp = xn + (size_t)row*128;
  xp[lane]    = f2bs((v0-mu)*rs*lnw[lane]    + lnb[lane]);
  xp[lane+64] = f2bs((v1-mu)*rs*lnw[lane+64] + lnb[lane+64]);
}

// LayerNorm over 128 ch; 4 rows/block, one wave per row. Writes bf16 XN.
__global__ __launch_bounds__(256) void k_ln(const float* __restrict__ hres, const float* __restrict__ lnw,
                     const float* __restrict__ lnb, unsigned short* __restrict__ xn){
  int row = blockIdx.x*4 + (threadIdx.x>>6);
  int lane = threadIdx.x & 63;
  const float* hp = hres + (size_t)row*128;
  float v0 = hp[lane], v1 = hp[lane+64];
  float s = v0+v1, q = v0*v0+v1*v1;
  #pragma unroll
  for (int off=32; off>0; off>>=1){
    s += __shfl_xor(s, off, 64);
    q += __shfl_xor(q, off, 64);
  }
  float mu = s*(1.f/128.f);
  float rs = rsqrtf(q*(1.f/128.f)-mu*mu + 1e-5f);
  unsigned short* xp = xn + (size_t)row*128;
  xp[lane]    = f2bs((v0-mu)*rs*lnw[lane]    + lnb[lane]);
  xp[lane+64] = f2bs((v1-mu)*rs*lnw[lane+64] + lnb[lane+64]);
}

// ---------------------------------------------------------------------------
// MFMA GEMM in_proj: XZB[row,0:512](bf16) = XN[amap(row),0:128](bf16) @ W^T
// ---------------------------------------------------------------------------
__global__ __launch_bounds__(256) void k_gemm_in(const unsigned short* __restrict__ A,
                          const unsigned short* __restrict__ W,
                          unsigned short* __restrict__ C, int rev){
  __shared__ unsigned short As[128*72];
  __shared__ unsigned short Bs[128*72];
  int tid = threadIdx.x;
  int row0 = blockIdx.x*128;
  int n0   = blockIdx.y*128;
  int wave = tid>>6, lane = tid&63;
  int wm = wave>>1, wn = wave&1;
  int quad = lane>>4, l16 = lane&15;
  f32x4 acc[4][4];
  #pragma unroll
  for (int i=0;i<4;i++)
    #pragma unroll
    for (int j=0;j<4;j++) acc[i][j] = (f32x4){0.f,0.f,0.f,0.f};

  for (int kb=0; kb<128; kb+=64){
    __syncthreads();
    #pragma unroll
    for (int it=0; it<4; it++){
      int idx = it*256 + tid;
      int row = idx>>3, c8 = idx&7;
      int r = row0 + row;
      int p = r & (Ll-1); int bb = r >> 12;
      int src = (bb<<12) + (rev ? (Ll-1-p) : p);
      *(uint4*)&As[row*72 + c8*8] = *(const uint4*)&A[(size_t)src*128 + kb + c8*8];
      *(uint4*)&Bs[row*72 + c8*8] = *(const uint4*)&W[(size_t)(n0+row)*128 + kb + c8*8];
    }
    __syncthreads();
    #pragma unroll
    for (int ks=0; ks<64; ks+=32){
      bf16x8 af[4], bf[4];
      #pragma unroll
      for (int mt=0;mt<4;mt++)
        af[mt] = *(bf16x8*)&As[(wm*64+mt*16+l16)*72 + ks + quad*8];
      #pragma unroll
      for (int nt=0;nt<4;nt++)
        bf[nt] = *(bf16x8*)&Bs[(wn*64+nt*16+l16)*72 + ks + quad*8];
      #pragma unroll
      for (int mt=0;mt<4;mt++)
        #pragma unroll
        for (int nt=0;nt<4;nt++)
          acc[mt][nt] = __builtin_amdgcn_mfma_f32_16x16x32_bf16(af[mt], bf[nt], acc[mt][nt], 0,0,0);
    }
  }
  #pragma unroll
  for (int mt=0;mt<4;mt++)
    #pragma unroll
    for (int nt=0;nt<4;nt++)
      #pragma unroll
      for (int r=0;r<4;r++){
        int row = row0 + wm*64 + mt*16 + quad*4 + r;
        int col = n0 + wn*64 + nt*16 + l16;
        C[(size_t)row*512 + col] = f2bs(acc[mt][nt][r]);
      }
}

// ---------------------------------------------------------------------------
// MFMA GEMM out_proj: HR[amap(row),0:128] += Y[row,0:256](bf16) @ W^T
// ---------------------------------------------------------------------------
__global__ __launch_bounds__(256) void k_gemm_out(const unsigned short* __restrict__ A,
                           const unsigned short* __restrict__ W,
                           float* __restrict__ C, int rev){
  __shared__ unsigned short As[64*72];
  __shared__ unsigned short Bs[128*72];
  int tid = threadIdx.x;
  int row0 = blockIdx.x*64;
  int wave = tid>>6, lane = tid&63;
  int wm = wave>>1, wn = wave&1;
  int quad = lane>>4, l16 = lane&15;
  f32x4 acc[2][4];
  #pragma unroll
  for (int i=0;i<2;i++)
    #pragma unroll
    for (int j=0;j<4;j++) acc[i][j] = (f32x4){0.f,0.f,0.f,0.f};

  for (int kb=0; kb<256; kb+=64){
    __syncthreads();
    #pragma unroll
    for (int it=0; it<2; it++){
      int idx = it*256 + tid;
      int row = idx>>3, c8 = idx&7;
      *(uint4*)&As[row*72 + c8*8] = *(const uint4*)&A[(size_t)(row0+row)*256 + kb + c8*8];
    }
    #pragma unroll
    for (int it=0; it<4; it++){
      int idx = it*256 + tid;
      int row = idx>>3, c8 = idx&7;
      *(uint4*)&Bs[row*72 + c8*8] = *(const uint4*)&W[(size_t)row*256 + kb + c8*8];
    }
    __syncthreads();
    #pragma unroll
    for (int ks=0; ks<64; ks+=32){
      bf16x8 af[2], bf[4];
      #pragma unroll
      for (int mt=0;mt<2;mt++)
        af[mt] = *(bf16x8*)&As[(wm*32+mt*16+l16)*72 + ks + quad*8];
      #pragma unroll
      for (int nt=0;nt<4;nt++)
        bf[nt] = *(bf16x8*)&Bs[(wn*64+nt*16+l16)*72 + ks + quad*8];
      #pragma unroll
      for (int mt=0;mt<2;mt++)
        #pragma unroll
        for (int nt=0;nt<4;nt++)
          acc[mt][nt] = __builtin_amdgcn_mfma_f32_16x16x32_bf16(af[mt], bf[nt], acc[mt][nt], 0,0,0);
    }
  }
  #pragma unroll
  for (int mt=0;mt<2;mt++)
    #pragma unroll
    for (int nt=0;nt<4;nt++)
      #pragma unroll
      for (int r=0;r<4;r++){
        int row = row0 + wm*32 + mt*16 + quad*4 + r;
        int p = row & (Ll-1), bb = row >> 12;
        int dst = (bb<<12) + (rev ? (Ll-1-p) : p);
        int col = wn*64 + nt*16 + l16;
        C[(size_t)dst*128 + col] += acc[mt][nt][r];
      }
}

// Depthwise causal conv (K=4) + bias + SiLU. One thread = 8 d's of one row.
__global__ void k_conv(const unsigned short* __restrict__ xz, const float* __restrict__ cw,
                       const float* __restrict__ cb, unsigned short* __restrict__ xib){
  size_t gid = (size_t)blockIdx.x*256 + threadIdx.x;   // over B*L*32
  int d8 = (int)(gid & 31);
  size_t row = gid >> 5;
  int p = (int)(row & (Ll-1));
  int d0 = d8*8;
  float wv[8][4];
  #pragma unroll
  for (int j=0;j<8;j++){
    float4 w4 = *(const float4*)&cw[(d0+j)*4];
    wv[j][0]=w4.x; wv[j][1]=w4.y; wv[j][2]=w4.z; wv[j][3]=w4.w;
  }
  float acc[8];
  {
    float4 b0 = *(const float4*)&cb[d0];
    float4 b1 = *(const float4*)&cb[d0+4];
    acc[0]=b0.x; acc[1]=b0.y; acc[2]=b0.z; acc[3]=b0.w;
    acc[4]=b1.x; acc[5]=b1.y; acc[6]=b1.z; acc[7]=b1.w;
  }
  #pragma unroll
  for (int k=0;k<4;k++){
    int q = p-3+k;
    if (q>=0){
      uint4 v = *(const uint4*)&xz[((size_t)row-3+k)*512 + d0];
      const unsigned short* s = (const unsigned short*)&v;
      #pragma unroll
      for (int j=0;j<8;j++) acc[j] += wv[j][k]*bs2f(s[j]);
    }
  }
  unsigned short ob[8];
  #pragma unroll
  for (int j=0;j<8;j++){
    float v = acc[j]/(1.f+__expf(-acc[j]));
    ob[j]=f2bs(v);
  }
  *(uint4*)&xib[row*256+d0] = *(uint4*)ob;
}

// ---------------------------------------------------------------------------
// MFMA x_proj + fused dt_proj/softplus.
// ---------------------------------------------------------------------------
__global__ __launch_bounds__(256) void k_xproj2(const unsigned short* __restrict__ xib,
                        const unsigned short* __restrict__ wxb,
                        const float* __restrict__ dtw, const float* __restrict__ dtb,
                        float* __restrict__ dbl, float* __restrict__ dtt){
  __shared__ unsigned short As[64*72];
  __shared__ unsigned short Bs[64*72];
  __shared__ float dblS[64][44];
  int tid = threadIdx.x;
  size_t row0 = (size_t)blockIdx.x*64;
  int wave = tid>>6, lane = tid&63;
  int quad = lane>>4, l16 = lane&15;
  f32x4 acc[4];
  #pragma unroll
  for (int j=0;j<4;j++) acc[j] = (f32x4){0.f,0.f,0.f,0.f};

  for (int kb=0; kb<256; kb+=64){
    __syncthreads();
    #pragma unroll
    for (int it=0; it<2; it++){
      int idx = it*256 + tid;
      int row = idx>>3, c8 = idx&7;
      *(uint4*)&As[row*72 + c8*8] = *(const uint4*)&xib[(row0+row)*256 + kb + c8*8];
      *(uint4*)&Bs[row*72 + c8*8] = *(const uint4*)&wxb[(size_t)row*256 + kb + c8*8];
    }
    __syncthreads();
    #pragma unroll
    for (int ks=0; ks<64; ks+=32){
      bf16x8 af = *(bf16x8*)&As[(wave*16+l16)*72 + ks + quad*8];
      #pragma unroll
      for (int nt=0;nt<4;nt++){
        bf16x8 bf = *(bf16x8*)&Bs[(nt*16+l16)*72 + ks + quad*8];
        acc[nt] = __builtin_amdgcn_mfma_f32_16x16x32_bf16(af, bf, acc[nt], 0,0,0);
      }
    }
  }
  #pragma unroll
  for (int nt=0;nt<4;nt++)
    #pragma unroll
    for (int r=0;r<4;r++){
      int m = wave*16 + quad*4 + r;
      int col = nt*16 + l16;
      if (col < 40){
        float v = acc[nt][r];
        dbl[(row0+m)*40 + col] = v;
        dblS[m][col] = v;
      }
    }
  __syncthreads();
  // phase B: thread = d (0..255)
  float wv[8];
  {
    float4 w0 = *(const float4*)&dtw[tid*8];
    float4 w1 = *(const float4*)&dtw[tid*8+4];
    wv[0]=w0.x; wv[1]=w0.y; wv[2]=w0.z; wv[3]=w0.w;
    wv[4]=w1.x; wv[5]=w1.y; wv[6]=w1.z; wv[7]=w1.w;
  }
  float bb = dtb[tid];
  for (int rr=0; rr<64; rr++){
    float a = bb;
    #pragma unroll
    for (int r=0;r<8;r++) a += dblS[rr][r]*wv[r];
    float v = (a>20.f)? a : log1pf(__expf(a));
    dtt[(row0+rr)*256 + tid] = v;
  }
}

// ---------------------------------------------------------------------------
// Chunked scan, one thread per d, n-state in registers. xi read as bf16.
// ---------------------------------------------------------------------------
__global__ __launch_bounds__(256) void k_scan1(const float* __restrict__ dt, const float* __restrict__ dbl,
                       const unsigned short* __restrict__ xib, const float* __restrict__ Alog,
                       float* __restrict__ P, float* __restrict__ Q){
  __shared__ float BcS[CH][16];
  int b = blockIdx.y, c = blockIdx.x;
  int d = threadIdx.x;
  size_t base = (size_t)b*Ll + (size_t)c*CH;
  if (d < CH*16){
    int p = d>>4, n = d&15;
    BcS[p][n] = dbl[(base+p)*40 + 8 + n];
  }
  float A[16];
  #pragma unroll
  for (int j=0;j<4;j++){
    float4 a4 = *(const float4*)&Alog[d*16 + j*4];
    A[4*j]=-__expf(a4.x); A[4*j+1]=-__expf(a4.y); A[4*j+2]=-__expf(a4.z); A[4*j+3]=-__expf(a4.w);
  }
  __syncthreads();
  float h[16], pr[16];
  #pragma unroll
  for (int n=0;n<16;n++){ h[n]=0.f; pr[n]=1.f; }
  const float* dtp = dt + base*256 + d;
  const unsigned short* xip = xib + base*256 + d;
  for (int p=0;p<CH;p++){
    float dtv = dtp[(size_t)p*256];
    float xiv = bs2f(xip[(size_t)p*256]);
    float dx = dtv*xiv;
    #pragma unroll
    for (int n=0;n<16;n++){
      float a = __expf(dtv*A[n]);
      h[n] = a*h[n] + BcS[p][n]*dx;
      pr[n] *= a;
    }
  }
  size_t sbase = ((size_t)(b*NC + c))*4096 + d*16;
  #pragma unroll
  for (int j=0;j<4;j++){
    *(float4*)&P[sbase + 4*j] = (float4){pr[4*j],pr[4*j+1],pr[4*j+2],pr[4*j+3]};
    *(float4*)&Q[sbase + 4*j] = (float4){h[4*j],h[4*j+1],h[4*j+2],h[4*j+3]};
  }
}

// In-place: Q[c] is read, then overwritten with the chunk-START state.
__global__ __launch_bounds__(256) void k_scan2(const float* __restrict__ P, float* __restrict__ Q){
  int b = blockIdx.y;
  int dn = blockIdx.x*256 + threadIdx.x;   // 0..4095
  float H = 0.f;
  for (int c=0;c<NC;c++){
    size_t idx = ((size_t)(b*NC + c))*4096 + dn;
    float p = P[idx];
    float q = Q[idx];
    Q[idx] = H;
    H = p*H + q;
  }
}

__global__ __launch_bounds__(256) void k_scan3(const float* __restrict__ dt, const float* __restrict__ dbl,
                       const unsigned short* __restrict__ xib, const float* __restrict__ Alog,
                       const float* __restrict__ Dpw, const float* __restrict__ Hs,
                       const unsigned short* __restrict__ xz, unsigned short* __restrict__ y){
  __shared__ float BcS[CH][16];
  __shared__ float CcS[CH][16];
  int b = blockIdx.y, c = blockIdx.x;
  int d = threadIdx.x;
  size_t base = (size_t)b*Ll + (size_t)c*CH;
  if (d < CH*16){
    int p = d>>4, n = d&15;
    BcS[p][n] = dbl[(base+p)*40 + 8 + n];
    CcS[p][n] = dbl[(base+p)*40 + 24 + n];
  }
  float A[16];
  #pragma unroll
  for (int j=0;j<4;j++){
    float4 a4 = *(const float4*)&Alog[d*16 + j*4];
    A[4*j]=-__expf(a4.x); A[4*j+1]=-__expf(a4.y); A[4*j+2]=-__expf(a4.z); A[4*j+3]=-__expf(a4.w);
  }
  float Dp = Dpw[d];
  float h[16];
  size_t sbase = ((size_t)(b*NC + c))*4096 + d*16;
  #pragma unroll
  for (int j=0;j<4;j++){
    float4 h4 = *(const float4*)&Hs[sbase + 4*j];
    h[4*j]=h4.x; h[4*j+1]=h4.y; h[4*j+2]=h4.z; h[4*j+3]=h4.w;
  }
  __syncthreads();
  const float* dtp = dt + base*256 + d;
  const unsigned short* xip = xib + base*256 + d;
  const unsigned short* zp = xz + base*512 + 256 + d;
  unsigned short* yp = y + base*256 + d;
  for (int p=0;p<CH;p++){
    float dtv = dtp[(size_t)p*256];
    float xiv = bs2f(xip[(size_t)p*256]);
    float dx = dtv*xiv;
    float acc = 0.f;
    #pragma unroll
    for (int n=0;n<16;n++){
      float a = __expf(dtv*A[n]);
      h[n] = a*h[n] + BcS[p][n]*dx;
      acc += h[n]*CcS[p][n];
    }
    float z = bs2f(zp[(size_t)p*512]);
    float g = z/(1.f+__expf(-z));
    yp[(size_t)p*256] = f2bs((acc + Dp*xiv)*g);
  }
}

// final transpose (B,L,128) fp32 -> (B,128,L) fp32
__global__ __launch_bounds__(256) void k_final(const float* __restrict__ hres, float* __restrict__ out){
  __shared__ float tile[64*129];
  int b = blockIdx.y, l0 = blockIdx.x*64;
  int tid = threadIdx.x;
  for (int q=0;q<32;q++){
    int idx = q*256 + tid;
    int l = idx >> 7, c = idx & 127;
    tile[l*129 + c] = hres[((size_t)b*Ll + l0 + l)*128 + c];
  }
  __syncthreads();
  int lo = tid & 63; int cbase = tid >> 6;
  for (int q=0;q<32;q++){
    int c = cbase + q*4;
    out[((size_t)b*128 + c)*Ll + l0 + lo] = tile[lo*129 + c];
  }
}

extern "C" void kernel_launch(void* const* d_in, const int* in_sizes, int n_in,
                              void* d_out, int out_size, void* d_ws, size_t ws_size,
                              hipStream_t stream){
  const float* x      = (const float*)d_in[0];
  const float* skip   = (const float*)d_in[1];
  const float* up_w   = (const float*)d_in[2];
  const float* up_b   = (const float*)d_in[3];
  const float* fus_w  = (const float*)d_in[4];
  const float* fus_b  = (const float*)d_in[5];
  const float* gn_w   = (const float*)d_in[6];
  const float* gn_b   = (const float*)d_in[7];
  const float* pa     = (const float*)d_in[8];
  const float* ln_w   = (const float*)d_in[9];
  const float* ln_b   = (const float*)d_in[10];
  const float* in_w   = (const float*)d_in[11];
  const float* conv_w = (const float*)d_in[12];
  const float* conv_b = (const float*)d_in[13];
  const float* xproj_w= (const float*)d_in[14];
  const float* dtproj_w=(const float*)d_in[15];
  const float* dtproj_b=(const float*)d_in[16];
  const float* A_log  = (const float*)d_in[17];
  const float* Dp     = (const float*)d_in[18];
  const float* out_w  = (const float*)d_in[19];

  // Workspace layout (keep total <= ~100 MB; round-7 post-mortem). ~96 MB now.
  //   U1: XT+SKT (preamble only) / SP,SQ (mamba loop; NC=256; SH aliases SQ in-place)
  //   U2: H0 (preamble only)     / XIB (mamba loop only)
  float* w = (float*)d_ws;
  size_t off=0;
  float* B2 = w+off; off += 128;
  float* GST= w+off; off += 16;
  off = (off+3)&~(size_t)3;
  float* HR = w+off; off += (size_t)Bsz*Ll*128;
  float* DBL= w+off; off += (size_t)Bsz*Ll*40;
  float* DTT= w+off; off += (size_t)Bsz*Ll*256;
  unsigned short* XNB = (unsigned short*)(w+off); off += (size_t)Bsz*Ll*128/2;
  unsigned short* XZB = (unsigned short*)(w+off); off += (size_t)Bsz*Ll*512/2;
  unsigned short* YB  = (unsigned short*)(w+off); off += (size_t)Bsz*Ll*256/2;
  unsigned short* IWB = (unsigned short*)(w+off); off += 2*2*512*128/2;
  unsigned short* OWB = (unsigned short*)(w+off); off += 2*2*128*256/2;
  unsigned short* WXB = (unsigned short*)(w+off); off += 2*2*64*256/2;
  unsigned short* WEb = (unsigned short*)(w+off); off += 768*128/2;
  unsigned short* WOb = (unsigned short*)(w+off); off += 512*128/2;
  unsigned short* FWSb= (unsigned short*)(w+off); off += 128*128/2;
  // U1: max(XT+SKT ~2.1M floats, SP+SQ = 2*Bsz*NC*4096 floats)
  size_t scanbuf = (size_t)Bsz*NC*4096;   // 4,194,304 @ NC=256
  float* U1 = w+off; off += 2*scanbuf;
  unsigned short* XT  = (unsigned short*)U1;
  unsigned short* SKT = (unsigned short*)(U1 + 1049604);
  float* SP = U1;
  float* SQ = U1 + scanbuf;     // after k_scan2, holds chunk-start states
  // U2: max(H0, XIB) = 2,097,152 floats
  float* U2 = w+off; off += (size_t)Bsz*Ll*128;
  float* H0 = U2;
  unsigned short* XIB = (unsigned short*)U2;

  hipMemsetAsync(GST, 0, 16*sizeof(float), stream);
  k_cvt<<<(2*2*512*128+255)/256,256,0,stream>>>(in_w, IWB, 2*2*512*128);
  k_cvt<<<(2*2*128*256+255)/256,256,0,stream>>>(out_w, OWB, 2*2*128*256);
  k_prepx<<<dim3(64,4),256,0,stream>>>(xproj_w, WXB);
  k_compose<<<256,128,0,stream>>>(up_w, fus_w, fus_b, up_b, WEb, WOb, FWSb, B2);
  k_tx<<<dim3(Tt/64, 4, Bsz),256,0,stream>>>(x, XT);
  k_zero<<<1,256,0,stream>>>(XT);
  k_ts<<<dim3(Ll/64, 2, Bsz),256,0,stream>>>(skip, SKT);
  k_up<<<dim3(32, 2, Bsz),256,0,stream>>>(XT, SKT, WEb, WOb, FWSb, B2, H0, GST);
  k_gnfin<<<1,64,0,stream>>>(GST);
  k_gnln<<<Bsz*Ll/4,256,0,stream>>>(H0, gn_w, gn_b, pa, GST, ln_w, ln_b, HR, XNB);
  for (int i=0;i<2;i++){
    if (i==1) k_ln<<<Bsz*Ll/4,256,0,stream>>>(HR, ln_w + 128, ln_b + 128, XNB);
    for (int dir=0;dir<2;dir++){
      int br = i*2+dir;
      k_gemm_in<<<dim3(128,4),256,0,stream>>>(XNB, IWB + (size_t)br*512*128, XZB, dir);
      k_conv<<<Bsz*Ll/8,256,0,stream>>>(XZB, conv_w + br*256*4, conv_b + br*256, XIB);
      k_xproj2<<<Bsz*Ll/64,256,0,stream>>>(XIB, WXB + (size_t)br*64*256,
                                           dtproj_w + br*256*8, dtproj_b + br*256, DBL, DTT);
      k_scan1<<<dim3(NC,Bsz),256,0,stream>>>(DTT, DBL, XIB, A_log + br*256*16, SP, SQ);
      k_scan2<<<dim3(16,Bsz),256,0,stream>>>(SP, SQ);
      k_scan3<<<dim3(NC,Bsz),256,0,stream>>>(DTT, DBL, XIB, A_log + br*256*16, Dp + br*256, SQ, XZB, YB);
      k_gemm_out<<<256,256,0,stream>>>(YB, OWB + (size_t)br*128*256, HR, dir);
    }
  }
  k_final<<<dim3(Ll/64,Bsz),256,0,stream>>>(HR, (float*)d_out);
}

// Round 11
// 633.300 us; speedup vs baseline: 1.1305x; 1.1305x over previous
//
#include <hip/hip_runtime.h>
#include <hip/hip_bf16.h>

#define Bsz 4
#define Tt 2048
#define Ll 4096
#define NC 128     // chunks for scan (round-10 NC=256 regressed: scan2 serial cost ∝ NC)
#define CH 32      // steps per chunk (NC*CH == Ll)

typedef short bf16x8 __attribute__((ext_vector_type(8)));
typedef float f32x4 __attribute__((ext_vector_type(4)));

static __device__ __forceinline__ float bs2f(unsigned short u){
  union{float f; unsigned int i;} v; v.i = ((unsigned int)u)<<16; return v.f;
}
static __device__ __forceinline__ unsigned short f2bs(float f){
  union{float f; unsigned int i;} v; v.f = f;
  unsigned int r = (v.i + 0x7fffu + ((v.i>>16)&1u)) >> 16;
  return (unsigned short)r;
}

// fp32 -> bf16 bulk convert
__global__ void k_cvt(const float* __restrict__ src, unsigned short* __restrict__ dst, int n){
  int i = blockIdx.x*256 + threadIdx.x;
  if (i < n) dst[i] = f2bs(src[i]);
}

// pad xproj_w (4 branches, 40x256) to zero-filled 64x256 bf16
__global__ void k_prepx(const float* __restrict__ xw, unsigned short* __restrict__ wxb){
  int row = blockIdx.x, br = blockIdx.y, col = threadIdx.x;
  float v = (row < 40) ? xw[((size_t)br*40 + row)*256 + col] : 0.f;
  wxb[((size_t)br*64 + row)*256 + col] = f2bs(v);
}

// ---------------------------------------------------------------------------
// Compose upsample-conv weights with fuse matmul; emit bf16 GEMM-ready layouts.
// ---------------------------------------------------------------------------
__global__ void k_compose(const float* __restrict__ up_w, const float* __restrict__ fus_w,
                          const float* __restrict__ fus_b, const float* __restrict__ up_b,
                          unsigned short* __restrict__ WEb, unsigned short* __restrict__ WOb,
                          unsigned short* __restrict__ FWSb, float* __restrict__ BIAS2){
  int i = blockIdx.x;     // 0..255
  int o = threadIdx.x;    // 0..127
  float a0=0.f,a1=0.f,a2=0.f,a3=0.f,a4=0.f;
  for (int c=0;c<256;c++){
    float f = fus_w[o*384+c];
    const float* w = up_w + ((size_t)i*256+c)*5;
    a0 += f*w[0]; a1 += f*w[1]; a2 += f*w[2];
    a3 += f*w[3]; a4 += f*w[4];
  }
  WEb[(size_t)o*768 +       i] = f2bs(a4);
  WEb[(size_t)o*768 + 256 + i] = f2bs(a2);
  WEb[(size_t)o*768 + 512 + i] = f2bs(a0);
  WOb[(size_t)o*512 +       i] = f2bs(a3);
  WOb[(size_t)o*512 + 256 + i] = f2bs(a1);
  if (i<128) FWSb[o*128 + i] = f2bs(fus_w[o*384+256+i]);
  if (i==0){
    float bb = fus_b[o];
    for (int c=0;c<256;c++) bb += fus_w[o*384+c]*up_b[c];
    BIAS2[o]=bb;
  }
}

// transpose x (B,256,T) f32 -> XT (B, T+2, 256) bf16, row t stored at t+1
__global__ __launch_bounds__(256) void k_tx(const float* __restrict__ x, unsigned short* __restrict__ XT){
  __shared__ float tile[64][65];
  int b=blockIdx.z, t0=blockIdx.x*64, i0=blockIdx.y*64;
  int tid=threadIdx.x;
  for (int it=0;it<16;it++){
    int idx=it*256+tid; int ii=idx>>6, tt=idx&63;
    tile[ii][tt] = x[((size_t)b*256+i0+ii)*Tt + t0+tt];
  }
  __syncthreads();
  for (int it=0;it<16;it++){
    int idx=it*256+tid; int tt=idx>>6, ii=idx&63;
    XT[((size_t)b*2050 + t0+tt+1)*256 + i0+ii] = f2bs(tile[ii][tt]);
  }
}

// zero XT halo rows (t=-1 and t=2048)
__global__ void k_zero(unsigned short* __restrict__ XT){
  int tid=threadIdx.x;
  for (int b=0;b<Bsz;b++){
    XT[((size_t)b*2050)*256 + tid] = 0;
    XT[((size_t)b*2050+2049)*256 + tid] = 0;
  }
}

// transpose skip (B,128,L) f32 -> SKT (B,L,128) bf16
__global__ __launch_bounds__(256) void k_ts(const float* __restrict__ skip, unsigned short* __restrict__ SKT){
  __shared__ float tile[64][65];
  int b=blockIdx.z, l0=blockIdx.x*64, s0=blockIdx.y*64;
  int tid=threadIdx.x;
  for (int it=0;it<16;it++){
    int idx=it*256+tid; int ss=idx>>6, ll=idx&63;
    tile[ss][ll] = skip[((size_t)b*128+s0+ss)*Ll + l0+ll];
  }
  __syncthreads();
  for (int it=0;it<16;it++){
    int idx=it*256+tid; int ll=idx>>6, ss=idx&63;
    SKT[((size_t)b*Ll + l0+ll)*128 + s0+ss] = f2bs(tile[ss][ll]);
  }
}

// ---------------------------------------------------------------------------
// MFMA upsample+fuse (see round-4 notes). Block = 64 t x 128 o, one parity.
// ---------------------------------------------------------------------------
__global__ __launch_bounds__(256) void k_up(const unsigned short* __restrict__ XT,
                     const unsigned short* __restrict__ SKT,
                     const unsigned short* __restrict__ WEb, const unsigned short* __restrict__ WOb,
                     const unsigned short* __restrict__ FWSb, const float* __restrict__ B2,
                     float* __restrict__ h0, float* __restrict__ gst){
  __shared__ unsigned short XL[66*264];
  __shared__ unsigned short Wb[128*72];
  __shared__ float red0[256], red1[256];
  int bt = blockIdx.x, par = blockIdx.y, b = blockIdx.z;
  int t0 = bt*64;
  int tid = threadIdx.x;
  int wave = tid>>6, lane = tid&63;
  int wm = wave>>1, wn = wave&1;
  int quad = lane>>4, l16 = lane&15;

  for (int idx=tid; idx<66*32; idx+=256){
    int row = idx>>5, c8 = idx&31;
    *(uint4*)&XL[row*264 + c8*8] = *(const uint4*)&XT[((size_t)b*2050 + t0 + row)*256 + c8*8];
  }

  const unsigned short* Wsrc = par ? WOb : WEb;
  const int Kw = par ? 512 : 768;
  const int tapbase = par ? 1 : 0;
  f32x4 acc[2][4];
  #pragma unroll
  for (int i=0;i<2;i++)
    #pragma unroll
    for (int j=0;j<4;j++) acc[i][j] = (f32x4){0.f,0.f,0.f,0.f};

  int nch = Kw>>6;
  for (int kc=0; kc<nch; kc++){
    __syncthreads();
    #pragma unroll
    for (int it=0; it<4; it++){
      int idx = it*256+tid;
      int row = idx>>3, c8 = idx&7;
      *(uint4*)&Wb[row*72 + c8*8] = *(const uint4*)&Wsrc[(size_t)row*Kw + kc*64 + c8*8];
    }
    __syncthreads();
    #pragma unroll
    for (int ks=0; ks<64; ks+=32){
      int kg = kc*64 + ks;
      int tap = kg>>8, ib = kg&255;
      bf16x8 af[2], bf[4];
      #pragma unroll
      for (int mt=0;mt<2;mt++)
        af[mt] = *(bf16x8*)&XL[(wm*32+mt*16+l16 + tapbase + tap)*264 + ib + quad*8];
      #pragma unroll
      for (int nt=0;nt<4;nt++)
        bf[nt] = *(bf16x8*)&Wb[(wn*64+nt*16+l16)*72 + ks + quad*8];
      #pragma unroll
      for (int mt=0;mt<2;mt++)
        #pragma unroll
        for (int nt=0;nt<4;nt++)
          acc[mt][nt] = __builtin_amdgcn_mfma_f32_16x16x32_bf16(af[mt], bf[nt], acc[mt][nt], 0,0,0);
    }
  }

  __syncthreads();
  for (int idx=tid; idx<64*16; idx+=256){
    int row = idx>>4, c8 = idx&15;
    *(uint4*)&XL[row*136 + c8*8] = *(const uint4*)&SKT[((size_t)b*Ll + 2*(t0+row)+par)*128 + c8*8];
  }
  for (int kc=0; kc<2; kc++){
    __syncthreads();
    #pragma unroll
    for (int it=0; it<4; it++){
      int idx = it*256+tid;
      int row = idx>>3, c8 = idx&7;
      *(uint4*)&Wb[row*72 + c8*8] = *(const uint4*)&FWSb[(size_t)row*128 + kc*64 + c8*8];
    }
    __syncthreads();
    #pragma unroll
    for (int ks=0; ks<64; ks+=32){
      bf16x8 af[2], bf[4];
      #pragma unroll
      for (int mt=0;mt<2;mt++)
        af[mt] = *(bf16x8*)&XL[(wm*32+mt*16+l16)*136 + kc*64 + ks + quad*8];
      #pragma unroll
      for (int nt=0;nt<4;nt++)
        bf[nt] = *(bf16x8*)&Wb[(wn*64+nt*16+l16)*72 + ks + quad*8];
      #pragma unroll
      for (int mt=0;mt<2;mt++)
        #pragma unroll
        for (int nt=0;nt<4;nt++)
          acc[mt][nt] = __builtin_amdgcn_mfma_f32_16x16x32_bf16(af[mt], bf[nt], acc[mt][nt], 0,0,0);
    }
  }

  float s1=0.f, s2=0.f;
  #pragma unroll
  for (int mt=0;mt<2;mt++)
    #pragma unroll
    for (int nt=0;nt<4;nt++)
      #pragma unroll
      for (int r=0;r<4;r++){
        int m = wm*32 + mt*16 + quad*4 + r;
        int lrow = 2*(t0+m) + par;
        int col = wn*64 + nt*16 + l16;
        float v = acc[mt][nt][r] + B2[col];
        h0[((size_t)b*Ll + lrow)*128 + col] = v;
        s1 += v; s2 += v*v;
      }
  red0[tid]=s1; red1[tid]=s2;
  __syncthreads();
  for (int st=128; st>0; st>>=1){
    if (tid<st){ red0[tid]+=red0[tid+st]; red1[tid]+=red1[tid+st]; }
    __syncthreads();
  }
  if (tid==0){ atomicAdd(&gst[b*2], red0[0]); atomicAdd(&gst[b*2+1], red1[0]); }
}

__global__ void k_gnfin(float* gst){
  int b = threadIdx.x;
  if (b < Bsz){
    float n = (float)Ll*128.f;
    float mu = gst[b*2]/n;
    float var = gst[b*2+1]/n - mu*mu;
    gst[8+b]=mu; gst[12+b]=rsqrtf(var+1e-5f);
  }
}

// Fused GroupNorm-apply + PReLU + layer-0 LayerNorm.
__global__ __launch_bounds__(256) void k_gnln(const float* __restrict__ h0, const float* __restrict__ gn_w,
                      const float* __restrict__ gn_b, const float* __restrict__ pa,
                      const float* __restrict__ gst, const float* __restrict__ lnw,
                      const float* __restrict__ lnb, float* __restrict__ hres,
                      unsigned short* __restrict__ xn){
  int row = blockIdx.x*4 + (threadIdx.x>>6);
  int lane = threadIdx.x & 63;
  int b = row >> 12;
  float mu_g = gst[8+b], inv_g = gst[12+b];
  float a = pa[0];
  const float* hp = h0 + (size_t)row*128;
  float u0 = (hp[lane]   -mu_g)*inv_g*gn_w[lane]    + gn_b[lane];
  float u1 = (hp[lane+64]-mu_g)*inv_g*gn_w[lane+64] + gn_b[lane+64];
  float v0 = u0>=0.f ? u0 : a*u0;
  float v1 = u1>=0.f ? u1 : a*u1;
  float* rp = hres + (size_t)row*128;
  rp[lane] = v0; rp[lane+64] = v1;
  float s = v0+v1, q = v0*v0+v1*v1;
  #pragma unroll
  for (int off=32; off>0; off>>=1){
    s += __shfl_xor(s, off, 64);
    q += __shfl_xor(q, off, 64);
  }
  float mu = s*(1.f/128.f);
  float rs = rsqrtf(q*(1.f/128.f)-mu*mu + 1e-5f);
  unsigned short* xp = xn + (size_t)row*128;
  xp[lane]    = f2bs((v0-mu)*rs*lnw[lane]    + lnb[lane]);
  xp[lane+64] = f2bs((v1-mu)*rs*lnw[lane+64] + lnb[lane+64]);
}

// LayerNorm over 128 ch; 4 rows/block, one wave per row. Writes bf16 XN.
__global__ __launch_bounds__(256) void k_ln(const float* __restrict__ hres, const float* __restrict__ lnw,
                     const float* __restrict__ lnb, unsigned short* __restrict__ xn){
  int row = blockIdx.x*4 + (threadIdx.x>>6);
  int lane = threadIdx.x & 63;
  const float* hp = hres + (size_t)row*128;
  float v0 = hp[lane], v1 = hp[lane+64];
  float s = v0+v1, q = v0*v0+v1*v1;
  #pragma unroll
  for (int off=32; off>0; off>>=1){
    s += __shfl_xor(s, off, 64);
    q += __shfl_xor(q, off, 64);
  }
  float mu = s*(1.f/128.f);
  float rs = rsqrtf(q*(1.f/128.f)-mu*mu + 1e-5f);
  unsigned short* xp = xn + (size_t)row*128;
  xp[lane]    = f2bs((v0-mu)*rs*lnw[lane]    + lnb[lane]);
  xp[lane+64] = f2bs((v1-mu)*rs*lnw[lane+64] + lnb[lane+64]);
}

// ---------------------------------------------------------------------------
// MFMA GEMM in_proj: XZB[row,0:512](bf16) = XN[amap(row),0:128](bf16) @ W^T
// ---------------------------------------------------------------------------
__global__ __launch_bounds__(256) void k_gemm_in(const unsigned short* __restrict__ A,
                          const unsigned short* __restrict__ W,
                          unsigned short* __restrict__ C, int rev){
  __shared__ unsigned short As[128*72];
  __shared__ unsigned short Bs[128*72];
  int tid = threadIdx.x;
  int row0 = blockIdx.x*128;
  int n0   = blockIdx.y*128;
  int wave = tid>>6, lane = tid&63;
  int wm = wave>>1, wn = wave&1;
  int quad = lane>>4, l16 = lane&15;
  f32x4 acc[4][4];
  #pragma unroll
  for (int i=0;i<4;i++)
    #pragma unroll
    for (int j=0;j<4;j++) acc[i][j] = (f32x4){0.f,0.f,0.f,0.f};

  for (int kb=0; kb<128; kb+=64){
    __syncthreads();
    #pragma unroll
    for (int it=0; it<4; it++){
      int idx = it*256 + tid;
      int row = idx>>3, c8 = idx&7;
      int r = row0 + row;
      int p = r & (Ll-1); int bb = r >> 12;
      int src = (bb<<12) + (rev ? (Ll-1-p) : p);
      *(uint4*)&As[row*72 + c8*8] = *(const uint4*)&A[(size_t)src*128 + kb + c8*8];
      *(uint4*)&Bs[row*72 + c8*8] = *(const uint4*)&W[(size_t)(n0+row)*128 + kb + c8*8];
    }
    __syncthreads();
    #pragma unroll
    for (int ks=0; ks<64; ks+=32){
      bf16x8 af[4], bf[4];
      #pragma unroll
      for (int mt=0;mt<4;mt++)
        af[mt] = *(bf16x8*)&As[(wm*64+mt*16+l16)*72 + ks + quad*8];
      #pragma unroll
      for (int nt=0;nt<4;nt++)
        bf[nt] = *(bf16x8*)&Bs[(wn*64+nt*16+l16)*72 + ks + quad*8];
      #pragma unroll
      for (int mt=0;mt<4;mt++)
        #pragma unroll
        for (int nt=0;nt<4;nt++)
          acc[mt][nt] = __builtin_amdgcn_mfma_f32_16x16x32_bf16(af[mt], bf[nt], acc[mt][nt], 0,0,0);
    }
  }
  #pragma unroll
  for (int mt=0;mt<4;mt++)
    #pragma unroll
    for (int nt=0;nt<4;nt++)
      #pragma unroll
      for (int r=0;r<4;r++){
        int row = row0 + wm*64 + mt*16 + quad*4 + r;
        int col = n0 + wn*64 + nt*16 + l16;
        C[(size_t)row*512 + col] = f2bs(acc[mt][nt][r]);
      }
}

// ---------------------------------------------------------------------------
// MFMA GEMM out_proj: HR[amap(row),0:128] += Y[row,0:256](bf16) @ W^T
// ---------------------------------------------------------------------------
__global__ __launch_bounds__(256) void k_gemm_out(const unsigned short* __restrict__ A,
                           const unsigned short* __restrict__ W,
                           float* __restrict__ C, int rev){
  __shared__ unsigned short As[64*72];
  __shared__ unsigned short Bs[128*72];
  int tid = threadIdx.x;
  int row0 = blockIdx.x*64;
  int wave = tid>>6, lane = tid&63;
  int wm = wave>>1, wn = wave&1;
  int quad = lane>>4, l16 = lane&15;
  f32x4 acc[2][4];
  #pragma unroll
  for (int i=0;i<2;i++)
    #pragma unroll
    for (int j=0;j<4;j++) acc[i][j] = (f32x4){0.f,0.f,0.f,0.f};

  for (int kb=0; kb<256; kb+=64){
    __syncthreads();
    #pragma unroll
    for (int it=0; it<2; it++){
      int idx = it*256 + tid;
      int row = idx>>3, c8 = idx&7;
      *(uint4*)&As[row*72 + c8*8] = *(const uint4*)&A[(size_t)(row0+row)*256 + kb + c8*8];
    }
    #pragma unroll
    for (int it=0; it<4; it++){
      int idx = it*256 + tid;
      int row = idx>>3, c8 = idx&7;
      *(uint4*)&Bs[row*72 + c8*8] = *(const uint4*)&W[(size_t)row*256 + kb + c8*8];
    }
    __syncthreads();
    #pragma unroll
    for (int ks=0; ks<64; ks+=32){
      bf16x8 af[2], bf[4];
      #pragma unroll
      for (int mt=0;mt<2;mt++)
        af[mt] = *(bf16x8*)&As[(wm*32+mt*16+l16)*72 + ks + quad*8];
      #pragma unroll
      for (int nt=0;nt<4;nt++)
        bf[nt] = *(bf16x8*)&Bs[(wn*64+nt*16+l16)*72 + ks + quad*8];
      #pragma unroll
      for (int mt=0;mt<2;mt++)
        #pragma unroll
        for (int nt=0;nt<4;nt++)
          acc[mt][nt] = __builtin_amdgcn_mfma_f32_16x16x32_bf16(af[mt], bf[nt], acc[mt][nt], 0,0,0);
    }
  }
  #pragma unroll
  for (int mt=0;mt<2;mt++)
    #pragma unroll
    for (int nt=0;nt<4;nt++)
      #pragma unroll
      for (int r=0;r<4;r++){
        int row = row0 + wm*32 + mt*16 + quad*4 + r;
        int p = row & (Ll-1), bb = row >> 12;
        int dst = (bb<<12) + (rev ? (Ll-1-p) : p);
        int col = wn*64 + nt*16 + l16;
        C[(size_t)dst*128 + col] += acc[mt][nt][r];
      }
}

// ---------------------------------------------------------------------------
// Fused depthwise conv (K=4, sliding window) + SiLU + MFMA x_proj + dt_proj.
// Block = 64 rows; thread = d for conv phase. xi lives in LDS for the GEMM
// and is also written to global XIB for the scan kernels.
// ---------------------------------------------------------------------------
__global__ __launch_bounds__(256) void k_xproj3(const unsigned short* __restrict__ xz,
                        const unsigned short* __restrict__ wxb,
                        const float* __restrict__ cw, const float* __restrict__ cb,
                        const float* __restrict__ dtw, const float* __restrict__ dtb,
                        unsigned short* __restrict__ xib,
                        float* __restrict__ dbl, float* __restrict__ dtt){
  __shared__ unsigned short xiS[64*264];
  __shared__ unsigned short Bs[64*72];
  __shared__ float dblS[64][44];
  int tid = threadIdx.x;
  size_t row0 = (size_t)blockIdx.x*64;
  int p0 = (int)(row0 & (Ll-1));

  // ---- conv phase: thread = d ----
  {
    int d = tid;
    float4 w4 = *(const float4*)&cw[d*4];
    float bias = cb[d];
    float w0, w1, w2;
    if (p0 == 0){ w0=0.f; w1=0.f; w2=0.f; }
    else {
      w0 = bs2f(xz[(row0-3)*512 + d]);
      w1 = bs2f(xz[(row0-2)*512 + d]);
      w2 = bs2f(xz[(row0-1)*512 + d]);
    }
    #pragma unroll 4
    for (int rr=0; rr<64; rr++){
      float xv = bs2f(xz[(row0+rr)*512 + d]);
      float acc = bias + w4.x*w0 + w4.y*w1 + w4.z*w2 + w4.w*xv;
      float v = acc/(1.f+__expf(-acc));
      unsigned short us = f2bs(v);
      xiS[rr*264 + d] = us;
      xib[(row0+rr)*256 + d] = us;
      w0=w1; w1=w2; w2=xv;
    }
  }

  // ---- MFMA x_proj: A = xiS (LDS), B = wxb ----
  int wave = tid>>6, lane = tid&63;
  int quad = lane>>4, l16 = lane&15;
  f32x4 acc[4];
  #pragma unroll
  for (int j=0;j<4;j++) acc[j] = (f32x4){0.f,0.f,0.f,0.f};

  for (int kb=0; kb<256; kb+=64){
    __syncthreads();
    #pragma unroll
    for (int it=0; it<2; it++){
      int idx = it*256 + tid;          // 512 = 64 rows x 8 uint4
      int row = idx>>3, c8 = idx&7;
      *(uint4*)&Bs[row*72 + c8*8] = *(const uint4*)&wxb[(size_t)row*256 + kb + c8*8];
    }
    __syncthreads();
    #pragma unroll
    for (int ks=0; ks<64; ks+=32){
      bf16x8 af = *(bf16x8*)&xiS[(wave*16+l16)*264 + kb + ks + quad*8];
      #pragma unroll
      for (int nt=0;nt<4;nt++){
        bf16x8 bf = *(bf16x8*)&Bs[(nt*16+l16)*72 + ks + quad*8];
        acc[nt] = __builtin_amdgcn_mfma_f32_16x16x32_bf16(af, bf, acc[nt], 0,0,0);
      }
    }
  }
  #pragma unroll
  for (int nt=0;nt<4;nt++)
    #pragma unroll
    for (int r=0;r<4;r++){
      int m = wave*16 + quad*4 + r;
      int col = nt*16 + l16;
      if (col < 40){
        float v = acc[nt][r];
        dbl[(row0+m)*40 + col] = v;
        dblS[m][col] = v;
      }
    }
  __syncthreads();
  // ---- dt_proj + softplus: thread = d ----
  float wv[8];
  {
    float4 w0 = *(const float4*)&dtw[tid*8];
    float4 w1 = *(const float4*)&dtw[tid*8+4];
    wv[0]=w0.x; wv[1]=w0.y; wv[2]=w0.z; wv[3]=w0.w;
    wv[4]=w1.x; wv[5]=w1.y; wv[6]=w1.z; wv[7]=w1.w;
  }
  float bb = dtb[tid];
  for (int rr=0; rr<64; rr++){
    float a = bb;
    #pragma unroll
    for (int r=0;r<8;r++) a += dblS[rr][r]*wv[r];
    float v = (a>20.f)? a : log1pf(__expf(a));
    dtt[(row0+rr)*256 + tid] = v;
  }
}

// ---------------------------------------------------------------------------
// Chunked scan, one thread per d, n-state in registers. xi read as bf16.
// ---------------------------------------------------------------------------
__global__ __launch_bounds__(256) void k_scan1(const float* __restrict__ dt, const float* __restrict__ dbl,
                       const unsigned short* __restrict__ xib, const float* __restrict__ Alog,
                       float* __restrict__ P, float* __restrict__ Q){
  __shared__ float BcS[CH][16];
  int b = blockIdx.y, c = blockIdx.x;
  int d = threadIdx.x;
  size_t base = (size_t)b*Ll + (size_t)c*CH;
  for (int idx=d; idx<CH*16; idx+=256){
    int p = idx>>4, n = idx&15;
    BcS[p][n] = dbl[(base+p)*40 + 8 + n];
  }
  float A[16];
  #pragma unroll
  for (int j=0;j<4;j++){
    float4 a4 = *(const float4*)&Alog[d*16 + j*4];
    A[4*j]=-__expf(a4.x); A[4*j+1]=-__expf(a4.y); A[4*j+2]=-__expf(a4.z); A[4*j+3]=-__expf(a4.w);
  }
  __syncthreads();
  float h[16], pr[16];
  #pragma unroll
  for (int n=0;n<16;n++){ h[n]=0.f; pr[n]=1.f; }
  const float* dtp = dt + base*256 + d;
  const unsigned short* xip = xib + base*256 + d;
  for (int p=0;p<CH;p++){
    float dtv = dtp[(size_t)p*256];
    float xiv = bs2f(xip[(size_t)p*256]);
    float dx = dtv*xiv;
    #pragma unroll
    for (int n=0;n<16;n++){
      float a = __expf(dtv*A[n]);
      h[n] = a*h[n] + BcS[p][n]*dx;
      pr[n] *= a;
    }
  }
  size_t sbase = ((size_t)(b*NC + c))*4096 + d*16;
  #pragma unroll
  for (int j=0;j<4;j++){
    *(float4*)&P[sbase + 4*j] = (float4){pr[4*j],pr[4*j+1],pr[4*j+2],pr[4*j+3]};
    *(float4*)&Q[sbase + 4*j] = (float4){h[4*j],h[4*j+1],h[4*j+2],h[4*j+3]};
  }
}

// In-place: Q[c] is read, then overwritten with the chunk-START state.
__global__ __launch_bounds__(256) void k_scan2(const float* __restrict__ P, float* __restrict__ Q){
  int b = blockIdx.y;
  int dn = blockIdx.x*256 + threadIdx.x;   // 0..4095
  float H = 0.f;
  for (int c=0;c<NC;c++){
    size_t idx = ((size_t)(b*NC + c))*4096 + dn;
    float p = P[idx];
    float q = Q[idx];
    Q[idx] = H;
    H = p*H + q;
  }
}

__global__ __launch_bounds__(256) void k_scan3(const float* __restrict__ dt, const float* __restrict__ dbl,
                       const unsigned short* __restrict__ xib, const float* __restrict__ Alog,
                       const float* __restrict__ Dpw, const float* __restrict__ Hs,
                       const unsigned short* __restrict__ xz, unsigned short* __restrict__ y){
  __shared__ float BcS[CH][16];
  __shared__ float CcS[CH][16];
  int b = blockIdx.y, c = blockIdx.x;
  int d = threadIdx.x;
  size_t base = (size_t)b*Ll + (size_t)c*CH;
  for (int idx=d; idx<CH*16; idx+=256){
    int p = idx>>4, n = idx&15;
    BcS[p][n] = dbl[(base+p)*40 + 8 + n];
    CcS[p][n] = dbl[(base+p)*40 + 24 + n];
  }
  float A[16];
  #pragma unroll
  for (int j=0;j<4;j++){
    float4 a4 = *(const float4*)&Alog[d*16 + j*4];
    A[4*j]=-__expf(a4.x); A[4*j+1]=-__expf(a4.y); A[4*j+2]=-__expf(a4.z); A[4*j+3]=-__expf(a4.w);
  }
  float Dp = Dpw[d];
  float h[16];
  size_t sbase = ((size_t)(b*NC + c))*4096 + d*16;
  #pragma unroll
  for (int j=0;j<4;j++){
    float4 h4 = *(const float4*)&Hs[sbase + 4*j];
    h[4*j]=h4.x; h[4*j+1]=h4.y; h[4*j+2]=h4.z; h[4*j+3]=h4.w;
  }
  __syncthreads();
  const float* dtp = dt + base*256 + d;
  const unsigned short* xip = xib + base*256 + d;
  const unsigned short* zp = xz + base*512 + 256 + d;
  unsigned short* yp = y + base*256 + d;
  for (int p=0;p<CH;p++){
    float dtv = dtp[(size_t)p*256];
    float xiv = bs2f(xip[(size_t)p*256]);
    float dx = dtv*xiv;
    float acc = 0.f;
    #pragma unroll
    for (int n=0;n<16;n++){
      float a = __expf(dtv*A[n]);
      h[n] = a*h[n] + BcS[p][n]*dx;
      acc += h[n]*CcS[p][n];
    }
    float z = bs2f(zp[(size_t)p*512]);
    float g = z/(1.f+__expf(-z));
    yp[(size_t)p*256] = f2bs((acc + Dp*xiv)*g);
  }
}

// final transpose (B,L,128) fp32 -> (B,128,L) fp32
__global__ __launch_bounds__(256) void k_final(const float* __restrict__ hres, float* __restrict__ out){
  __shared__ float tile[64*129];
  int b = blockIdx.y, l0 = blockIdx.x*64;
  int tid = threadIdx.x;
  for (int q=0;q<32;q++){
    int idx = q*256 + tid;
    int l = idx >> 7, c = idx & 127;
    tile[l*129 + c] = hres[((size_t)b*Ll + l0 + l)*128 + c];
  }
  __syncthreads();
  int lo = tid & 63; int cbase = tid >> 6;
  for (int q=0;q<32;q++){
    int c = cbase + q*4;
    out[((size_t)b*128 + c)*Ll + l0 + lo] = tile[lo*129 + c];
  }
}

extern "C" void kernel_launch(void* const* d_in, const int* in_sizes, int n_in,
                              void* d_out, int out_size, void* d_ws, size_t ws_size,
                              hipStream_t stream){
  const float* x      = (const float*)d_in[0];
  const float* skip   = (const float*)d_in[1];
  const float* up_w   = (const float*)d_in[2];
  const float* up_b   = (const float*)d_in[3];
  const float* fus_w  = (const float*)d_in[4];
  const float* fus_b  = (const float*)d_in[5];
  const float* gn_w   = (const float*)d_in[6];
  const float* gn_b   = (const float*)d_in[7];
  const float* pa     = (const float*)d_in[8];
  const float* ln_w   = (const float*)d_in[9];
  const float* ln_b   = (const float*)d_in[10];
  const float* in_w   = (const float*)d_in[11];
  const float* conv_w = (const float*)d_in[12];
  const float* conv_b = (const float*)d_in[13];
  const float* xproj_w= (const float*)d_in[14];
  const float* dtproj_w=(const float*)d_in[15];
  const float* dtproj_b=(const float*)d_in[16];
  const float* A_log  = (const float*)d_in[17];
  const float* Dp     = (const float*)d_in[18];
  const float* out_w  = (const float*)d_in[19];

  // Workspace layout (keep total <= ~100 MB; round-7 post-mortem). ~88 MB.
  //   U1: XT+SKT (preamble only) / SP,SQ (mamba loop; NC=128; scan2 in-place)
  //   U2: H0 (preamble only)     / XIB (mamba loop only)
  float* w = (float*)d_ws;
  size_t off=0;
  float* B2 = w+off; off += 128;
  float* GST= w+off; off += 16;
  off = (off+3)&~(size_t)3;
  float* HR = w+off; off += (size_t)Bsz*Ll*128;
  float* DBL= w+off; off += (size_t)Bsz*Ll*40;
  float* DTT= w+off; off += (size_t)Bsz*Ll*256;
  unsigned short* XNB = (unsigned short*)(w+off); off += (size_t)Bsz*Ll*128/2;
  unsigned short* XZB = (unsigned short*)(w+off); off += (size_t)Bsz*Ll*512/2;
  unsigned short* YB  = (unsigned short*)(w+off); off += (size_t)Bsz*Ll*256/2;
  unsigned short* IWB = (unsigned short*)(w+off); off += 2*2*512*128/2;
  unsigned short* OWB = (unsigned short*)(w+off); off += 2*2*128*256/2;
  unsigned short* WXB = (unsigned short*)(w+off); off += 2*2*64*256/2;
  unsigned short* WEb = (unsigned short*)(w+off); off += 768*128/2;
  unsigned short* WOb = (unsigned short*)(w+off); off += 512*128/2;
  unsigned short* FWSb= (unsigned short*)(w+off); off += 128*128/2;
  // U1: max(XT+SKT ~2.1M floats, SP+SQ = 2*Bsz*NC*4096 floats = 4.2M)
  size_t scanbuf = (size_t)Bsz*NC*4096;   // 2,097,152 @ NC=128
  float* U1 = w+off; off += 2*scanbuf;
  unsigned short* XT  = (unsigned short*)U1;
  unsigned short* SKT = (unsigned short*)(U1 + 1049604);
  float* SP = U1;
  float* SQ = U1 + scanbuf;     // after k_scan2, holds chunk-start states
  // U2: max(H0, XIB) = 2,097,152 floats
  float* U2 = w+off; off += (size_t)Bsz*Ll*128;
  float* H0 = U2;
  unsigned short* XIB = (unsigned short*)U2;

  hipMemsetAsync(GST, 0, 16*sizeof(float), stream);
  k_cvt<<<(2*2*512*128+255)/256,256,0,stream>>>(in_w, IWB, 2*2*512*128);
  k_cvt<<<(2*2*128*256+255)/256,256,0,stream>>>(out_w, OWB, 2*2*128*256);
  k_prepx<<<dim3(64,4),256,0,stream>>>(xproj_w, WXB);
  k_compose<<<256,128,0,stream>>>(up_w, fus_w, fus_b, up_b, WEb, WOb, FWSb, B2);
  k_tx<<<dim3(Tt/64, 4, Bsz),256,0,stream>>>(x, XT);
  k_zero<<<1,256,0,stream>>>(XT);
  k_ts<<<dim3(Ll/64, 2, Bsz),256,0,stream>>>(skip, SKT);
  k_up<<<dim3(32, 2, Bsz),256,0,stream>>>(XT, SKT, WEb, WOb, FWSb, B2, H0, GST);
  k_gnfin<<<1,64,0,stream>>>(GST);
  k_gnln<<<Bsz*Ll/4,256,0,stream>>>(H0, gn_w, gn_b, pa, GST, ln_w, ln_b, HR, XNB);
  for (int i=0;i<2;i++){
    if (i==1) k_ln<<<Bsz*Ll/4,256,0,stream>>>(HR, ln_w + 128, ln_b + 128, XNB);
    for (int dir=0;dir<2;dir++){
      int br = i*2+dir;
      k_gemm_in<<<dim3(128,4),256,0,stream>>>(XNB, IWB + (size_t)br*512*128, XZB, dir);
      k_xproj3<<<Bsz*Ll/64,256,0,stream>>>(XZB, WXB + (size_t)br*64*256,
                                           conv_w + br*256*4, conv_b + br*256,
                                           dtproj_w + br*256*8, dtproj_b + br*256,
                                           XIB, DBL, DTT);
      k_scan1<<<dim3(NC,Bsz),256,0,stream>>>(DTT, DBL, XIB, A_log + br*256*16, SP, SQ);
      k_scan2<<<dim3(16,Bsz),256,0,stream>>>(SP, SQ);
      k_scan3<<<dim3(NC,Bsz),256,0,stream>>>(DTT, DBL, XIB, A_log + br*256*16, Dp + br*256, SQ, XZB, YB);
      k_gemm_out<<<256,256,0,stream>>>(YB, OWB + (size_t)br*128*256, HR, dir);
    }
  }
  k_final<<<dim3(Ll/64,Bsz),256,0,stream>>>(HR, (float*)d_out);
}

// Round 12
// 577.289 us; speedup vs baseline: 1.2402x; 1.0970x over previous
//
#include <hip/hip_runtime.h>
#include <hip/hip_bf16.h>

#define Bsz 4
#define Tt 2048
#define Ll 4096
#define NC 64      // chunks for scan (batched over dirs: 512 blocks/dispatch)
#define CH 64      // steps per chunk (NC*CH == Ll)

typedef short bf16x8 __attribute__((ext_vector_type(8)));
typedef float f32x4 __attribute__((ext_vector_type(4)));

static __device__ __forceinline__ float bs2f(unsigned short u){
  union{float f; unsigned int i;} v; v.i = ((unsigned int)u)<<16; return v.f;
}
static __device__ __forceinline__ unsigned short f2bs(float f){
  union{float f; unsigned int i;} v; v.f = f;
  unsigned int r = (v.i + 0x7fffu + ((v.i>>16)&1u)) >> 16;
  return (unsigned short)r;
}

// fp32 -> bf16 bulk convert
__global__ void k_cvt(const float* __restrict__ src, unsigned short* __restrict__ dst, int n){
  int i = blockIdx.x*256 + threadIdx.x;
  if (i < n) dst[i] = f2bs(src[i]);
}

// pad xproj_w (4 branches, 40x256) to zero-filled 64x256 bf16
__global__ void k_prepx(const float* __restrict__ xw, unsigned short* __restrict__ wxb){
  int row = blockIdx.x, br = blockIdx.y, col = threadIdx.x;
  float v = (row < 40) ? xw[((size_t)br*40 + row)*256 + col] : 0.f;
  wxb[((size_t)br*64 + row)*256 + col] = f2bs(v);
}

// ---------------------------------------------------------------------------
// Compose upsample-conv weights with fuse matmul; emit bf16 GEMM-ready layouts.
// ---------------------------------------------------------------------------
__global__ void k_compose(const float* __restrict__ up_w, const float* __restrict__ fus_w,
                          const float* __restrict__ fus_b, const float* __restrict__ up_b,
                          unsigned short* __restrict__ WEb, unsigned short* __restrict__ WOb,
                          unsigned short* __restrict__ FWSb, float* __restrict__ BIAS2){
  int i = blockIdx.x;     // 0..255
  int o = threadIdx.x;    // 0..127
  float a0=0.f,a1=0.f,a2=0.f,a3=0.f,a4=0.f;
  for (int c=0;c<256;c++){
    float f = fus_w[o*384+c];
    const float* w = up_w + ((size_t)i*256+c)*5;
    a0 += f*w[0]; a1 += f*w[1]; a2 += f*w[2];
    a3 += f*w[3]; a4 += f*w[4];
  }
  WEb[(size_t)o*768 +       i] = f2bs(a4);
  WEb[(size_t)o*768 + 256 + i] = f2bs(a2);
  WEb[(size_t)o*768 + 512 + i] = f2bs(a0);
  WOb[(size_t)o*512 +       i] = f2bs(a3);
  WOb[(size_t)o*512 + 256 + i] = f2bs(a1);
  if (i<128) FWSb[o*128 + i] = f2bs(fus_w[o*384+256+i]);
  if (i==0){
    float bb = fus_b[o];
    for (int c=0;c<256;c++) bb += fus_w[o*384+c]*up_b[c];
    BIAS2[o]=bb;
  }
}

// transpose x (B,256,T) f32 -> XT (B, T+2, 256) bf16, row t stored at t+1
__global__ __launch_bounds__(256) void k_tx(const float* __restrict__ x, unsigned short* __restrict__ XT){
  __shared__ float tile[64][65];
  int b=blockIdx.z, t0=blockIdx.x*64, i0=blockIdx.y*64;
  int tid=threadIdx.x;
  for (int it=0;it<16;it++){
    int idx=it*256+tid; int ii=idx>>6, tt=idx&63;
    tile[ii][tt] = x[((size_t)b*256+i0+ii)*Tt + t0+tt];
  }
  __syncthreads();
  for (int it=0;it<16;it++){
    int idx=it*256+tid; int tt=idx>>6, ii=idx&63;
    XT[((size_t)b*2050 + t0+tt+1)*256 + i0+ii] = f2bs(tile[ii][tt]);
  }
}

// zero XT halo rows (t=-1 and t=2048)
__global__ void k_zero(unsigned short* __restrict__ XT){
  int tid=threadIdx.x;
  for (int b=0;b<Bsz;b++){
    XT[((size_t)b*2050)*256 + tid] = 0;
    XT[((size_t)b*2050+2049)*256 + tid] = 0;
  }
}

// transpose skip (B,128,L) f32 -> SKT (B,L,128) bf16
__global__ __launch_bounds__(256) void k_ts(const float* __restrict__ skip, unsigned short* __restrict__ SKT){
  __shared__ float tile[64][65];
  int b=blockIdx.z, l0=blockIdx.x*64, s0=blockIdx.y*64;
  int tid=threadIdx.x;
  for (int it=0;it<16;it++){
    int idx=it*256+tid; int ss=idx>>6, ll=idx&63;
    tile[ss][ll] = skip[((size_t)b*128+s0+ss)*Ll + l0+ll];
  }
  __syncthreads();
  for (int it=0;it<16;it++){
    int idx=it*256+tid; int ll=idx>>6, ss=idx&63;
    SKT[((size_t)b*Ll + l0+ll)*128 + s0+ss] = f2bs(tile[ss][ll]);
  }
}

// ---------------------------------------------------------------------------
// MFMA upsample+fuse (see round-4 notes). Block = 64 t x 128 o, one parity.
// ---------------------------------------------------------------------------
__global__ __launch_bounds__(256) void k_up(const unsigned short* __restrict__ XT,
                     const unsigned short* __restrict__ SKT,
                     const unsigned short* __restrict__ WEb, const unsigned short* __restrict__ WOb,
                     const unsigned short* __restrict__ FWSb, const float* __restrict__ B2,
                     float* __restrict__ h0, float* __restrict__ gst){
  __shared__ unsigned short XL[66*264];
  __shared__ unsigned short Wb[128*72];
  __shared__ float red0[256], red1[256];
  int bt = blockIdx.x, par = blockIdx.y, b = blockIdx.z;
  int t0 = bt*64;
  int tid = threadIdx.x;
  int wave = tid>>6, lane = tid&63;
  int wm = wave>>1, wn = wave&1;
  int quad = lane>>4, l16 = lane&15;

  for (int idx=tid; idx<66*32; idx+=256){
    int row = idx>>5, c8 = idx&31;
    *(uint4*)&XL[row*264 + c8*8] = *(const uint4*)&XT[((size_t)b*2050 + t0 + row)*256 + c8*8];
  }

  const unsigned short* Wsrc = par ? WOb : WEb;
  const int Kw = par ? 512 : 768;
  const int tapbase = par ? 1 : 0;
  f32x4 acc[2][4];
  #pragma unroll
  for (int i=0;i<2;i++)
    #pragma unroll
    for (int j=0;j<4;j++) acc[i][j] = (f32x4){0.f,0.f,0.f,0.f};

  int nch = Kw>>6;
  for (int kc=0; kc<nch; kc++){
    __syncthreads();
    #pragma unroll
    for (int it=0; it<4; it++){
      int idx = it*256+tid;
      int row = idx>>3, c8 = idx&7;
      *(uint4*)&Wb[row*72 + c8*8] = *(const uint4*)&Wsrc[(size_t)row*Kw + kc*64 + c8*8];
    }
    __syncthreads();
    #pragma unroll
    for (int ks=0; ks<64; ks+=32){
      int kg = kc*64 + ks;
      int tap = kg>>8, ib = kg&255;
      bf16x8 af[2], bf[4];
      #pragma unroll
      for (int mt=0;mt<2;mt++)
        af[mt] = *(bf16x8*)&XL[(wm*32+mt*16+l16 + tapbase + tap)*264 + ib + quad*8];
      #pragma unroll
      for (int nt=0;nt<4;nt++)
        bf[nt] = *(bf16x8*)&Wb[(wn*64+nt*16+l16)*72 + ks + quad*8];
      #pragma unroll
      for (int mt=0;mt<2;mt++)
        #pragma unroll
        for (int nt=0;nt<4;nt++)
          acc[mt][nt] = __builtin_amdgcn_mfma_f32_16x16x32_bf16(af[mt], bf[nt], acc[mt][nt], 0,0,0);
    }
  }

  __syncthreads();
  for (int idx=tid; idx<64*16; idx+=256){
    int row = idx>>4, c8 = idx&15;
    *(uint4*)&XL[row*136 + c8*8] = *(const uint4*)&SKT[((size_t)b*Ll + 2*(t0+row)+par)*128 + c8*8];
  }
  for (int kc=0; kc<2; kc++){
    __syncthreads();
    #pragma unroll
    for (int it=0; it<4; it++){
      int idx = it*256+tid;
      int row = idx>>3, c8 = idx&7;
      *(uint4*)&Wb[row*72 + c8*8] = *(const uint4*)&FWSb[(size_t)row*128 + kc*64 + c8*8];
    }
    __syncthreads();
    #pragma unroll
    for (int ks=0; ks<64; ks+=32){
      bf16x8 af[2], bf[4];
      #pragma unroll
      for (int mt=0;mt<2;mt++)
        af[mt] = *(bf16x8*)&XL[(wm*32+mt*16+l16)*136 + kc*64 + ks + quad*8];
      #pragma unroll
      for (int nt=0;nt<4;nt++)
        bf[nt] = *(bf16x8*)&Wb[(wn*64+nt*16+l16)*72 + ks + quad*8];
      #pragma unroll
      for (int mt=0;mt<2;mt++)
        #pragma unroll
        for (int nt=0;nt<4;nt++)
          acc[mt][nt] = __builtin_amdgcn_mfma_f32_16x16x32_bf16(af[mt], bf[nt], acc[mt][nt], 0,0,0);
    }
  }

  float s1=0.f, s2=0.f;
  #pragma unroll
  for (int mt=0;mt<2;mt++)
    #pragma unroll
    for (int nt=0;nt<4;nt++)
      #pragma unroll
      for (int r=0;r<4;r++){
        int m = wm*32 + mt*16 + quad*4 + r;
        int lrow = 2*(t0+m) + par;
        int col = wn*64 + nt*16 + l16;
        float v = acc[mt][nt][r] + B2[col];
        h0[((size_t)b*Ll + lrow)*128 + col] = v;
        s1 += v; s2 += v*v;
      }
  red0[tid]=s1; red1[tid]=s2;
  __syncthreads();
  for (int st=128; st>0; st>>=1){
    if (tid<st){ red0[tid]+=red0[tid+st]; red1[tid]+=red1[tid+st]; }
    __syncthreads();
  }
  if (tid==0){ atomicAdd(&gst[b*2], red0[0]); atomicAdd(&gst[b*2+1], red1[0]); }
}

__global__ void k_gnfin(float* gst){
  int b = threadIdx.x;
  if (b < Bsz){
    float n = (float)Ll*128.f;
    float mu = gst[b*2]/n;
    float var = gst[b*2+1]/n - mu*mu;
    gst[8+b]=mu; gst[12+b]=rsqrtf(var+1e-5f);
  }
}

// Fused GroupNorm-apply + PReLU + layer-0 LayerNorm.
__global__ __launch_bounds__(256) void k_gnln(const float* __restrict__ h0, const float* __restrict__ gn_w,
                      const float* __restrict__ gn_b, const float* __restrict__ pa,
                      const float* __restrict__ gst, const float* __restrict__ lnw,
                      const float* __restrict__ lnb, float* __restrict__ hres,
                      unsigned short* __restrict__ xn){
  int row = blockIdx.x*4 + (threadIdx.x>>6);
  int lane = threadIdx.x & 63;
  int b = row >> 12;
  float mu_g = gst[8+b], inv_g = gst[12+b];
  float a = pa[0];
  const float* hp = h0 + (size_t)row*128;
  float u0 = (hp[lane]   -mu_g)*inv_g*gn_w[lane]    + gn_b[lane];
  float u1 = (hp[lane+64]-mu_g)*inv_g*gn_w[lane+64] + gn_b[lane+64];
  float v0 = u0>=0.f ? u0 : a*u0;
  float v1 = u1>=0.f ? u1 : a*u1;
  float* rp = hres + (size_t)row*128;
  rp[lane] = v0; rp[lane+64] = v1;
  float s = v0+v1, q = v0*v0+v1*v1;
  #pragma unroll
  for (int off=32; off>0; off>>=1){
    s += __shfl_xor(s, off, 64);
    q += __shfl_xor(q, off, 64);
  }
  float mu = s*(1.f/128.f);
  float rs = rsqrtf(q*(1.f/128.f)-mu*mu + 1e-5f);
  unsigned short* xp = xn + (size_t)row*128;
  xp[lane]    = f2bs((v0-mu)*rs*lnw[lane]    + lnb[lane]);
  xp[lane+64] = f2bs((v1-mu)*rs*lnw[lane+64] + lnb[lane+64]);
}

// LayerNorm over 128 ch; 4 rows/block, one wave per row. Writes bf16 XN.
__global__ __launch_bounds__(256) void k_ln(const float* __restrict__ hres, const float* __restrict__ lnw,
                     const float* __restrict__ lnb, unsigned short* __restrict__ xn){
  int row = blockIdx.x*4 + (threadIdx.x>>6);
  int lane = threadIdx.x & 63;
  const float* hp = hres + (size_t)row*128;
  float v0 = hp[lane], v1 = hp[lane+64];
  float s = v0+v1, q = v0*v0+v1*v1;
  #pragma unroll
  for (int off=32; off>0; off>>=1){
    s += __shfl_xor(s, off, 64);
    q += __shfl_xor(q, off, 64);
  }
  float mu = s*(1.f/128.f);
  float rs = rsqrtf(q*(1.f/128.f)-mu*mu + 1e-5f);
  unsigned short* xp = xn + (size_t)row*128;
  xp[lane]    = f2bs((v0-mu)*rs*lnw[lane]    + lnb[lane]);
  xp[lane+64] = f2bs((v1-mu)*rs*lnw[lane+64] + lnb[lane+64]);
}

// ---------------------------------------------------------------------------
// MFMA GEMM in_proj, batched over dirs (blockIdx.z): XZ2[dir] = rev_dir(XN) @ W_dir^T
// ---------------------------------------------------------------------------
__global__ __launch_bounds__(256) void k_gemm_in(const unsigned short* __restrict__ A,
                          const unsigned short* __restrict__ W,
                          unsigned short* __restrict__ C){
  __shared__ unsigned short As[128*72];
  __shared__ unsigned short Bs[128*72];
  int tid = threadIdx.x;
  int row0 = blockIdx.x*128;
  int n0   = blockIdx.y*128;
  int dir  = blockIdx.z;
  const unsigned short* Wp = W + (size_t)dir*512*128;
  unsigned short* Cp = C + (size_t)dir*Bsz*Ll*512;
  int wave = tid>>6, lane = tid&63;
  int wm = wave>>1, wn = wave&1;
  int quad = lane>>4, l16 = lane&15;
  f32x4 acc[4][4];
  #pragma unroll
  for (int i=0;i<4;i++)
    #pragma unroll
    for (int j=0;j<4;j++) acc[i][j] = (f32x4){0.f,0.f,0.f,0.f};

  for (int kb=0; kb<128; kb+=64){
    __syncthreads();
    #pragma unroll
    for (int it=0; it<4; it++){
      int idx = it*256 + tid;
      int row = idx>>3, c8 = idx&7;
      int r = row0 + row;
      int p = r & (Ll-1); int bb = r >> 12;
      int src = (bb<<12) + (dir ? (Ll-1-p) : p);
      *(uint4*)&As[row*72 + c8*8] = *(const uint4*)&A[(size_t)src*128 + kb + c8*8];
      *(uint4*)&Bs[row*72 + c8*8] = *(const uint4*)&Wp[(size_t)(n0+row)*128 + kb + c8*8];
    }
    __syncthreads();
    #pragma unroll
    for (int ks=0; ks<64; ks+=32){
      bf16x8 af[4], bf[4];
      #pragma unroll
      for (int mt=0;mt<4;mt++)
        af[mt] = *(bf16x8*)&As[(wm*64+mt*16+l16)*72 + ks + quad*8];
      #pragma unroll
      for (int nt=0;nt<4;nt++)
        bf[nt] = *(bf16x8*)&Bs[(wn*64+nt*16+l16)*72 + ks + quad*8];
      #pragma unroll
      for (int mt=0;mt<4;mt++)
        #pragma unroll
        for (int nt=0;nt<4;nt++)
          acc[mt][nt] = __builtin_amdgcn_mfma_f32_16x16x32_bf16(af[mt], bf[nt], acc[mt][nt], 0,0,0);
    }
  }
  #pragma unroll
  for (int mt=0;mt<4;mt++)
    #pragma unroll
    for (int nt=0;nt<4;nt++)
      #pragma unroll
      for (int r=0;r<4;r++){
        int row = row0 + wm*64 + mt*16 + quad*4 + r;
        int col = n0 + wn*64 + nt*16 + l16;
        Cp[(size_t)row*512 + col] = f2bs(acc[mt][nt][r]);
      }
}

// ---------------------------------------------------------------------------
// Combined out_proj: HR[l] += Y0[l]@W0^T + Y1[rev l]@W1^T  (K=512, both dirs)
// Y planes hold gated y; dir1 A-rows loaded reversed, store straight.
// ---------------------------------------------------------------------------
__global__ __launch_bounds__(256) void k_gemm_out(const unsigned short* __restrict__ Y,
                           const unsigned short* __restrict__ W,
                           float* __restrict__ C){
  __shared__ unsigned short As[64*72];
  __shared__ unsigned short Bs[128*72];
  int tid = threadIdx.x;
  int row0 = blockIdx.x*64;
  int wave = tid>>6, lane = tid&63;
  int wm = wave>>1, wn = wave&1;
  int quad = lane>>4, l16 = lane&15;
  const size_t planeY = (size_t)Bsz*Ll*256;
  f32x4 acc[2][4];
  #pragma unroll
  for (int i=0;i<2;i++)
    #pragma unroll
    for (int j=0;j<4;j++) acc[i][j] = (f32x4){0.f,0.f,0.f,0.f};

  for (int kc=0; kc<8; kc++){
    int dirp = kc>>2;
    int kb = (kc&3)*64;
    const unsigned short* Wp = W + (size_t)dirp*128*256;
    __syncthreads();
    #pragma unroll
    for (int it=0; it<2; it++){
      int idx = it*256 + tid;
      int row = idx>>3, c8 = idx&7;
      int r = row0 + row;
      int p = r & (Ll-1); int bb = r >> 12;
      int srow = dirp ? ((bb<<12) + (Ll-1-p)) : r;
      *(uint4*)&As[row*72 + c8*8] = *(const uint4*)&Y[dirp*planeY + (size_t)srow*256 + kb + c8*8];
    }
    #pragma unroll
    for (int it=0; it<4; it++){
      int idx = it*256 + tid;
      int row = idx>>3, c8 = idx&7;
      *(uint4*)&Bs[row*72 + c8*8] = *(const uint4*)&Wp[(size_t)row*256 + kb + c8*8];
    }
    __syncthreads();
    #pragma unroll
    for (int ks=0; ks<64; ks+=32){
      bf16x8 af[2], bf[4];
      #pragma unroll
      for (int mt=0;mt<2;mt++)
        af[mt] = *(bf16x8*)&As[(wm*32+mt*16+l16)*72 + ks + quad*8];
      #pragma unroll
      for (int nt=0;nt<4;nt++)
        bf[nt] = *(bf16x8*)&Bs[(wn*64+nt*16+l16)*72 + ks + quad*8];
      #pragma unroll
      for (int mt=0;mt<2;mt++)
        #pragma unroll
        for (int nt=0;nt<4;nt++)
          acc[mt][nt] = __builtin_amdgcn_mfma_f32_16x16x32_bf16(af[mt], bf[nt], acc[mt][nt], 0,0,0);
    }
  }
  #pragma unroll
  for (int mt=0;mt<2;mt++)
    #pragma unroll
    for (int nt=0;nt<4;nt++)
      #pragma unroll
      for (int r=0;r<4;r++){
        int row = row0 + wm*32 + mt*16 + quad*4 + r;
        int col = wn*64 + nt*16 + l16;
        C[(size_t)row*128 + col] += acc[mt][nt][r];
      }
}

// ---------------------------------------------------------------------------
// Fused depthwise conv (K=4, sliding window) + SiLU + MFMA x_proj.
// Batched over dirs (blockIdx.y). dt is computed on the fly in the scans.
// ---------------------------------------------------------------------------
__global__ __launch_bounds__(256) void k_xproj3(const unsigned short* __restrict__ xz,
                        const unsigned short* __restrict__ wxb,
                        const float* __restrict__ cw, const float* __restrict__ cb,
                        unsigned short* __restrict__ xib, float* __restrict__ dbl){
  __shared__ unsigned short xiS[64*264];
  __shared__ unsigned short Bs[64*72];
  int tid = threadIdx.x;
  int dir = blockIdx.y;
  xz  += (size_t)dir*Bsz*Ll*512;
  wxb += (size_t)dir*64*256;
  cw  += dir*1024;
  cb  += dir*256;
  xib += (size_t)dir*Bsz*Ll*256;
  dbl += (size_t)dir*Bsz*Ll*40;
  size_t row0 = (size_t)blockIdx.x*64;
  int p0 = (int)(row0 & (Ll-1));

  // ---- conv phase: thread = d ----
  {
    int d = tid;
    float4 w4 = *(const float4*)&cw[d*4];
    float bias = cb[d];
    float w0, w1, w2;
    if (p0 == 0){ w0=0.f; w1=0.f; w2=0.f; }
    else {
      w0 = bs2f(xz[(row0-3)*512 + d]);
      w1 = bs2f(xz[(row0-2)*512 + d]);
      w2 = bs2f(xz[(row0-1)*512 + d]);
    }
    #pragma unroll 4
    for (int rr=0; rr<64; rr++){
      float xv = bs2f(xz[(row0+rr)*512 + d]);
      float acc = bias + w4.x*w0 + w4.y*w1 + w4.z*w2 + w4.w*xv;
      float v = acc/(1.f+__expf(-acc));
      unsigned short us = f2bs(v);
      xiS[rr*264 + d] = us;
      xib[(row0+rr)*256 + d] = us;
      w0=w1; w1=w2; w2=xv;
    }
  }

  // ---- MFMA x_proj: A = xiS (LDS), B = wxb ----
  int wave = tid>>6, lane = tid&63;
  int quad = lane>>4, l16 = lane&15;
  f32x4 acc[4];
  #pragma unroll
  for (int j=0;j<4;j++) acc[j] = (f32x4){0.f,0.f,0.f,0.f};

  for (int kb=0; kb<256; kb+=64){
    __syncthreads();
    #pragma unroll
    for (int it=0; it<2; it++){
      int idx = it*256 + tid;
      int row = idx>>3, c8 = idx&7;
      *(uint4*)&Bs[row*72 + c8*8] = *(const uint4*)&wxb[(size_t)row*256 + kb + c8*8];
    }
    __syncthreads();
    #pragma unroll
    for (int ks=0; ks<64; ks+=32){
      bf16x8 af = *(bf16x8*)&xiS[(wave*16+l16)*264 + kb + ks + quad*8];
      #pragma unroll
      for (int nt=0;nt<4;nt++){
        bf16x8 bf = *(bf16x8*)&Bs[(nt*16+l16)*72 + ks + quad*8];
        acc[nt] = __builtin_amdgcn_mfma_f32_16x16x32_bf16(af, bf, acc[nt], 0,0,0);
      }
    }
  }
  #pragma unroll
  for (int nt=0;nt<4;nt++)
    #pragma unroll
    for (int r=0;r<4;r++){
      int m = wave*16 + quad*4 + r;
      int col = nt*16 + l16;
      if (col < 40) dbl[(row0+m)*40 + col] = acc[nt][r];
    }
}

// ---------------------------------------------------------------------------
// Chunked scan, batched over dirs; dt computed on the fly from dbl[0:8]+dtw.
// ---------------------------------------------------------------------------
__global__ __launch_bounds__(256) void k_scan1(const float* __restrict__ dbl,
                       const unsigned short* __restrict__ xib, const float* __restrict__ Alog,
                       const float* __restrict__ dtw, const float* __restrict__ dtb,
                       float* __restrict__ P, float* __restrict__ Q){
  __shared__ float dtrS[CH][8];
  __shared__ float BcS[CH][16];
  int b = blockIdx.y, c = blockIdx.x, dir = blockIdx.z;
  int d = threadIdx.x;
  const float* dblP = dbl + (size_t)dir*Bsz*Ll*40;
  const unsigned short* xiP = xib + (size_t)dir*Bsz*Ll*256;
  size_t base = (size_t)b*Ll + (size_t)c*CH;
  for (int idx=d; idx<CH*24; idx+=256){
    int p = idx/24, r = idx%24;
    float v = dblP[(base+p)*40 + r];
    if (r < 8) dtrS[p][r] = v; else BcS[p][r-8] = v;
  }
  float A[16];
  #pragma unroll
  for (int j=0;j<4;j++){
    float4 a4 = *(const float4*)&Alog[(size_t)dir*4096 + d*16 + j*4];
    A[4*j]=-__expf(a4.x); A[4*j+1]=-__expf(a4.y); A[4*j+2]=-__expf(a4.z); A[4*j+3]=-__expf(a4.w);
  }
  float wv[8];
  {
    const float* dw = dtw + (size_t)dir*2048 + d*8;
    float4 w0 = *(const float4*)&dw[0];
    float4 w1 = *(const float4*)&dw[4];
    wv[0]=w0.x; wv[1]=w0.y; wv[2]=w0.z; wv[3]=w0.w;
    wv[4]=w1.x; wv[5]=w1.y; wv[6]=w1.z; wv[7]=w1.w;
  }
  float bbt = dtb[dir*256 + d];
  __syncthreads();
  float h[16], pr[16];
  #pragma unroll
  for (int n=0;n<16;n++){ h[n]=0.f; pr[n]=1.f; }
  const unsigned short* xip = xiP + base*256 + d;
  for (int p=0;p<CH;p++){
    float a0 = bbt;
    #pragma unroll
    for (int r=0;r<8;r++) a0 += dtrS[p][r]*wv[r];
    float dtv = (a0>20.f)? a0 : log1pf(__expf(a0));
    float xiv = bs2f(xip[(size_t)p*256]);
    float dx = dtv*xiv;
    #pragma unroll
    for (int n=0;n<16;n++){
      float a = __expf(dtv*A[n]);
      h[n] = a*h[n] + BcS[p][n]*dx;
      pr[n] *= a;
    }
  }
  size_t sbase = (size_t)dir*Bsz*NC*4096 + ((size_t)(b*NC + c))*4096 + d*16;
  #pragma unroll
  for (int j=0;j<4;j++){
    *(float4*)&P[sbase + 4*j] = (float4){pr[4*j],pr[4*j+1],pr[4*j+2],pr[4*j+3]};
    *(float4*)&Q[sbase + 4*j] = (float4){h[4*j],h[4*j+1],h[4*j+2],h[4*j+3]};
  }
}

// In-place: Q[c] is read, then overwritten with the chunk-START state.
__global__ __launch_bounds__(256) void k_scan2(const float* __restrict__ P, float* __restrict__ Q){
  int b = blockIdx.y, dir = blockIdx.z;
  int dn = blockIdx.x*256 + threadIdx.x;   // 0..4095
  size_t plane = (size_t)dir*Bsz*NC*4096;
  float H = 0.f;
  for (int c=0;c<NC;c++){
    size_t idx = plane + ((size_t)(b*NC + c))*4096 + dn;
    float p = P[idx];
    float q = Q[idx];
    Q[idx] = H;
    H = p*H + q;
  }
}

// Phase 3: re-scan from start states; y = (sum_n h*Cc + Dp*xi)*silu(z),
// written IN-PLACE over the xi plane (same layout; each thread reads its own
// (p,d) element before overwriting it).
__global__ __launch_bounds__(256) void k_scan3(const float* __restrict__ dbl,
                       unsigned short* xiy, const float* __restrict__ Alog,
                       const float* __restrict__ dtw, const float* __restrict__ dtb,
                       const float* __restrict__ Dpw, const float* __restrict__ Hs,
                       const unsigned short* __restrict__ xz){
  __shared__ float dtrS[CH][8];
  __shared__ float BcS[CH][16];
  __shared__ float CcS[CH][16];
  int b = blockIdx.y, c = blockIdx.x, dir = blockIdx.z;
  int d = threadIdx.x;
  const float* dblP = dbl + (size_t)dir*Bsz*Ll*40;
  unsigned short* xiP = xiy + (size_t)dir*Bsz*Ll*256;
  const unsigned short* xzP = xz + (size_t)dir*Bsz*Ll*512;
  size_t base = (size_t)b*Ll + (size_t)c*CH;
  for (int idx=d; idx<CH*40; idx+=256){
    int p = idx/40, r = idx%40;
    float v = dblP[(base+p)*40 + r];
    if (r < 8) dtrS[p][r] = v;
    else if (r < 24) BcS[p][r-8] = v;
    else CcS[p][r-24] = v;
  }
  float A[16];
  #pragma unroll
  for (int j=0;j<4;j++){
    float4 a4 = *(const float4*)&Alog[(size_t)dir*4096 + d*16 + j*4];
    A[4*j]=-__expf(a4.x); A[4*j+1]=-__expf(a4.y); A[4*j+2]=-__expf(a4.z); A[4*j+3]=-__expf(a4.w);
  }
  float wv[8];
  {
    const float* dw = dtw + (size_t)dir*2048 + d*8;
    float4 w0 = *(const float4*)&dw[0];
    float4 w1 = *(const float4*)&dw[4];
    wv[0]=w0.x; wv[1]=w0.y; wv[2]=w0.z; wv[3]=w0.w;
    wv[4]=w1.x; wv[5]=w1.y; wv[6]=w1.z; wv[7]=w1.w;
  }
  float bbt = dtb[dir*256 + d];
  float Dp = Dpw[dir*256 + d];
  float h[16];
  size_t sbase = (size_t)dir*Bsz*NC*4096 + ((size_t)(b*NC + c))*4096 + d*16;
  #pragma unroll
  for (int j=0;j<4;j++){
    float4 h4 = *(const float4*)&Hs[sbase + 4*j];
    h[4*j]=h4.x; h[4*j+1]=h4.y; h[4*j+2]=h4.z; h[4*j+3]=h4.w;
  }
  __syncthreads();
  unsigned short* xip = xiP + base*256 + d;
  const unsigned short* zp = xzP + base*512 + 256 + d;
  for (int p=0;p<CH;p++){
    float a0 = bbt;
    #pragma unroll
    for (int r=0;r<8;r++) a0 += dtrS[p][r]*wv[r];
    float dtv = (a0>20.f)? a0 : log1pf(__expf(a0));
    float xiv = bs2f(xip[(size_t)p*256]);
    float dx = dtv*xiv;
    float acc = 0.f;
    #pragma unroll
    for (int n=0;n<16;n++){
      float a = __expf(dtv*A[n]);
      h[n] = a*h[n] + BcS[p][n]*dx;
      acc += h[n]*CcS[p][n];
    }
    float z = bs2f(zp[(size_t)p*512]);
    float g = z/(1.f+__expf(-z));
    xip[(size_t)p*256] = f2bs((acc + Dp*xiv)*g);
  }
}

// final transpose (B,L,128) fp32 -> (B,128,L) fp32
__global__ __launch_bounds__(256) void k_final(const float* __restrict__ hres, float* __restrict__ out){
  __shared__ float tile[64*129];
  int b = blockIdx.y, l0 = blockIdx.x*64;
  int tid = threadIdx.x;
  for (int q=0;q<32;q++){
    int idx = q*256 + tid;
    int l = idx >> 7, c = idx & 127;
    tile[l*129 + c] = hres[((size_t)b*Ll + l0 + l)*128 + c];
  }
  __syncthreads();
  int lo = tid & 63; int cbase = tid >> 6;
  for (int q=0;q<32;q++){
    int c = cbase + q*4;
    out[((size_t)b*128 + c)*Ll + l0 + lo] = tile[lo*129 + c];
  }
}

extern "C" void kernel_launch(void* const* d_in, const int* in_sizes, int n_in,
                              void* d_out, int out_size, void* d_ws, size_t ws_size,
                              hipStream_t stream){
  const float* x      = (const float*)d_in[0];
  const float* skip   = (const float*)d_in[1];
  const float* up_w   = (const float*)d_in[2];
  const float* up_b   = (const float*)d_in[3];
  const float* fus_w  = (const float*)d_in[4];
  const float* fus_b  = (const float*)d_in[5];
  const float* gn_w   = (const float*)d_in[6];
  const float* gn_b   = (const float*)d_in[7];
  const float* pa     = (const float*)d_in[8];
  const float* ln_w   = (const float*)d_in[9];
  const float* ln_b   = (const float*)d_in[10];
  const float* in_w   = (const float*)d_in[11];
  const float* conv_w = (const float*)d_in[12];
  const float* conv_b = (const float*)d_in[13];
  const float* xproj_w= (const float*)d_in[14];
  const float* dtproj_w=(const float*)d_in[15];
  const float* dtproj_b=(const float*)d_in[16];
  const float* A_log  = (const float*)d_in[17];
  const float* Dp     = (const float*)d_in[18];
  const float* out_w  = (const float*)d_in[19];

  // Workspace (~87 MB; round-7 bracket: <=100 MB safe).
  //   XZB2/XIB2/DBL2: per-dir planes for batched-dir kernels.
  //   U1: XT+SKT (preamble) / SP2,SQ2 (loop).  U2: H0 (preamble) / XIB2 (loop).
  //   DTT eliminated (dt recomputed in scans); y written in-place over XIB2.
  float* w = (float*)d_ws;
  size_t off=0;
  float* B2 = w+off; off += 128;
  float* GST= w+off; off += 16;
  off = (off+3)&~(size_t)3;
  float* HR = w+off; off += (size_t)Bsz*Ll*128;
  float* DBL2= w+off; off += 2*(size_t)Bsz*Ll*40;
  unsigned short* XNB = (unsigned short*)(w+off); off += (size_t)Bsz*Ll*128/2;
  unsigned short* XZB2= (unsigned short*)(w+off); off += 2*(size_t)Bsz*Ll*512/2;
  unsigned short* IWB = (unsigned short*)(w+off); off += 2*2*512*128/2;
  unsigned short* OWB = (unsigned short*)(w+off); off += 2*2*128*256/2;
  unsigned short* WXB = (unsigned short*)(w+off); off += 2*2*64*256/2;
  unsigned short* WEb = (unsigned short*)(w+off); off += 768*128/2;
  unsigned short* WOb = (unsigned short*)(w+off); off += 512*128/2;
  unsigned short* FWSb= (unsigned short*)(w+off); off += 128*128/2;
  // U1: max(XT 1,049,604 + SKT 1,048,576, SP2+SQ2 = 2*2*Bsz*NC*4096) floats
  size_t planeS = (size_t)Bsz*NC*4096;       // 1,048,576 @ NC=64
  float* U1 = w+off; off += 4*planeS;        // 4,194,304 floats
  unsigned short* XT  = (unsigned short*)U1;
  unsigned short* SKT = (unsigned short*)(U1 + 1049604);
  float* SP = U1;                            // 2 dir planes
  float* SQ = U1 + 2*planeS;                 // 2 dir planes; holds start states after scan2
  // U2: max(H0 = Bsz*Ll*128 floats, XIB2 = 2*Bsz*Ll*256 shorts) = 4,194,304 floats
  float* U2 = w+off; off += 2*(size_t)Bsz*Ll*128;
  float* H0 = U2;
  unsigned short* XIB2 = (unsigned short*)U2;

  hipMemsetAsync(GST, 0, 16*sizeof(float), stream);
  k_cvt<<<(2*2*512*128+255)/256,256,0,stream>>>(in_w, IWB, 2*2*512*128);
  k_cvt<<<(2*2*128*256+255)/256,256,0,stream>>>(out_w, OWB, 2*2*128*256);
  k_prepx<<<dim3(64,4),256,0,stream>>>(xproj_w, WXB);
  k_compose<<<256,128,0,stream>>>(up_w, fus_w, fus_b, up_b, WEb, WOb, FWSb, B2);
  k_tx<<<dim3(Tt/64, 4, Bsz),256,0,stream>>>(x, XT);
  k_zero<<<1,256,0,stream>>>(XT);
  k_ts<<<dim3(Ll/64, 2, Bsz),256,0,stream>>>(skip, SKT);
  k_up<<<dim3(32, 2, Bsz),256,0,stream>>>(XT, SKT, WEb, WOb, FWSb, B2, H0, GST);
  k_gnfin<<<1,64,0,stream>>>(GST);
  k_gnln<<<Bsz*Ll/4,256,0,stream>>>(H0, gn_w, gn_b, pa, GST, ln_w, ln_b, HR, XNB);
  for (int i=0;i<2;i++){
    if (i==1) k_ln<<<Bsz*Ll/4,256,0,stream>>>(HR, ln_w + 128, ln_b + 128, XNB);
    k_gemm_in<<<dim3(128,4,2),256,0,stream>>>(XNB, IWB + (size_t)(i*2)*512*128, XZB2);
    k_xproj3<<<dim3(Bsz*Ll/64,2),256,0,stream>>>(XZB2, WXB + (size_t)(i*2)*64*256,
                                                 conv_w + (i*2)*1024, conv_b + (i*2)*256,
                                                 XIB2, DBL2);
    k_scan1<<<dim3(NC,Bsz,2),256,0,stream>>>(DBL2, XIB2, A_log + (i*2)*4096,
                                             dtproj_w + (i*2)*2048, dtproj_b + (i*2)*256, SP, SQ);
    k_scan2<<<dim3(16,Bsz,2),256,0,stream>>>(SP, SQ);
    k_scan3<<<dim3(NC,Bsz,2),256,0,stream>>>(DBL2, XIB2, A_log + (i*2)*4096,
                                             dtproj_w + (i*2)*2048, dtproj_b + (i*2)*256,
                                             Dp + (i*2)*256, SQ, XZB2);
    k_gemm_out<<<256,256,0,stream>>>(XIB2, OWB + (size_t)(i*2)*128*256, HR);
  }
  k_final<<<dim3(Ll/64,Bsz),256,0,stream>>>(HR, (float*)d_out);
}

// Round 13
// 521.408 us; speedup vs baseline: 1.3731x; 1.1072x over previous
//
#include <hip/hip_runtime.h>
#include <hip/hip_bf16.h>

#define Bsz 4
#define Tt 2048
#define Ll 4096
#define NC 64      // chunks for scan (batched over dirs: 512 blocks/dispatch)
#define CH 64      // steps per chunk (NC*CH == Ll)

typedef short bf16x8 __attribute__((ext_vector_type(8)));
typedef float f32x4 __attribute__((ext_vector_type(4)));

static __device__ __forceinline__ float bs2f(unsigned short u){
  union{float f; unsigned int i;} v; v.i = ((unsigned int)u)<<16; return v.f;
}
static __device__ __forceinline__ unsigned short f2bs(float f){
  union{float f; unsigned int i;} v; v.f = f;
  unsigned int r = (v.i + 0x7fffu + ((v.i>>16)&1u)) >> 16;
  return (unsigned short)r;
}

// fp32 -> bf16 bulk convert
__global__ void k_cvt(const float* __restrict__ src, unsigned short* __restrict__ dst, int n){
  int i = blockIdx.x*256 + threadIdx.x;
  if (i < n) dst[i] = f2bs(src[i]);
}

// pad xproj_w (4 branches, 40x256) to zero-filled 64x256 bf16
__global__ void k_prepx(const float* __restrict__ xw, unsigned short* __restrict__ wxb){
  int row = blockIdx.x, br = blockIdx.y, col = threadIdx.x;
  float v = (row < 40) ? xw[((size_t)br*40 + row)*256 + col] : 0.f;
  wxb[((size_t)br*64 + row)*256 + col] = f2bs(v);
}

// ---------------------------------------------------------------------------
// Compose upsample-conv weights with fuse matmul; emit bf16 GEMM-ready layouts.
// ---------------------------------------------------------------------------
__global__ void k_compose(const float* __restrict__ up_w, const float* __restrict__ fus_w,
                          const float* __restrict__ fus_b, const float* __restrict__ up_b,
                          unsigned short* __restrict__ WEb, unsigned short* __restrict__ WOb,
                          unsigned short* __restrict__ FWSb, float* __restrict__ BIAS2){
  int i = blockIdx.x;     // 0..255
  int o = threadIdx.x;    // 0..127
  float a0=0.f,a1=0.f,a2=0.f,a3=0.f,a4=0.f;
  for (int c=0;c<256;c++){
    float f = fus_w[o*384+c];
    const float* w = up_w + ((size_t)i*256+c)*5;
    a0 += f*w[0]; a1 += f*w[1]; a2 += f*w[2];
    a3 += f*w[3]; a4 += f*w[4];
  }
  WEb[(size_t)o*768 +       i] = f2bs(a4);
  WEb[(size_t)o*768 + 256 + i] = f2bs(a2);
  WEb[(size_t)o*768 + 512 + i] = f2bs(a0);
  WOb[(size_t)o*512 +       i] = f2bs(a3);
  WOb[(size_t)o*512 + 256 + i] = f2bs(a1);
  if (i<128) FWSb[o*128 + i] = f2bs(fus_w[o*384+256+i]);
  if (i==0){
    float bb = fus_b[o];
    for (int c=0;c<256;c++) bb += fus_w[o*384+c]*up_b[c];
    BIAS2[o]=bb;
  }
}

// transpose x (B,256,T) f32 -> XT (B, T+2, 256) bf16, row t stored at t+1
__global__ __launch_bounds__(256) void k_tx(const float* __restrict__ x, unsigned short* __restrict__ XT){
  __shared__ float tile[64][65];
  int b=blockIdx.z, t0=blockIdx.x*64, i0=blockIdx.y*64;
  int tid=threadIdx.x;
  for (int it=0;it<16;it++){
    int idx=it*256+tid; int ii=idx>>6, tt=idx&63;
    tile[ii][tt] = x[((size_t)b*256+i0+ii)*Tt + t0+tt];
  }
  __syncthreads();
  for (int it=0;it<16;it++){
    int idx=it*256+tid; int tt=idx>>6, ii=idx&63;
    XT[((size_t)b*2050 + t0+tt+1)*256 + i0+ii] = f2bs(tile[ii][tt]);
  }
}

// zero XT halo rows (t=-1 and t=2048)
__global__ void k_zero(unsigned short* __restrict__ XT){
  int tid=threadIdx.x;
  for (int b=0;b<Bsz;b++){
    XT[((size_t)b*2050)*256 + tid] = 0;
    XT[((size_t)b*2050+2049)*256 + tid] = 0;
  }
}

// transpose skip (B,128,L) f32 -> SKT (B,L,128) bf16
__global__ __launch_bounds__(256) void k_ts(const float* __restrict__ skip, unsigned short* __restrict__ SKT){
  __shared__ float tile[64][65];
  int b=blockIdx.z, l0=blockIdx.x*64, s0=blockIdx.y*64;
  int tid=threadIdx.x;
  for (int it=0;it<16;it++){
    int idx=it*256+tid; int ss=idx>>6, ll=idx&63;
    tile[ss][ll] = skip[((size_t)b*128+s0+ss)*Ll + l0+ll];
  }
  __syncthreads();
  for (int it=0;it<16;it++){
    int idx=it*256+tid; int ll=idx>>6, ss=idx&63;
    SKT[((size_t)b*Ll + l0+ll)*128 + s0+ss] = f2bs(tile[ss][ll]);
  }
}

// ---------------------------------------------------------------------------
// MFMA upsample+fuse (see round-4 notes). Block = 64 t x 128 o, one parity.
// ---------------------------------------------------------------------------
__global__ __launch_bounds__(256) void k_up(const unsigned short* __restrict__ XT,
                     const unsigned short* __restrict__ SKT,
                     const unsigned short* __restrict__ WEb, const unsigned short* __restrict__ WOb,
                     const unsigned short* __restrict__ FWSb, const float* __restrict__ B2,
                     float* __restrict__ h0, float* __restrict__ gst){
  __shared__ unsigned short XL[66*264];
  __shared__ unsigned short Wb[128*72];
  __shared__ float red0[256], red1[256];
  int bt = blockIdx.x, par = blockIdx.y, b = blockIdx.z;
  int t0 = bt*64;
  int tid = threadIdx.x;
  int wave = tid>>6, lane = tid&63;
  int wm = wave>>1, wn = wave&1;
  int quad = lane>>4, l16 = lane&15;

  for (int idx=tid; idx<66*32; idx+=256){
    int row = idx>>5, c8 = idx&31;
    *(uint4*)&XL[row*264 + c8*8] = *(const uint4*)&XT[((size_t)b*2050 + t0 + row)*256 + c8*8];
  }

  const unsigned short* Wsrc = par ? WOb : WEb;
  const int Kw = par ? 512 : 768;
  const int tapbase = par ? 1 : 0;
  f32x4 acc[2][4];
  #pragma unroll
  for (int i=0;i<2;i++)
    #pragma unroll
    for (int j=0;j<4;j++) acc[i][j] = (f32x4){0.f,0.f,0.f,0.f};

  int nch = Kw>>6;
  for (int kc=0; kc<nch; kc++){
    __syncthreads();
    #pragma unroll
    for (int it=0; it<4; it++){
      int idx = it*256+tid;
      int row = idx>>3, c8 = idx&7;
      *(uint4*)&Wb[row*72 + c8*8] = *(const uint4*)&Wsrc[(size_t)row*Kw + kc*64 + c8*8];
    }
    __syncthreads();
    #pragma unroll
    for (int ks=0; ks<64; ks+=32){
      int kg = kc*64 + ks;
      int tap = kg>>8, ib = kg&255;
      bf16x8 af[2], bf[4];
      #pragma unroll
      for (int mt=0;mt<2;mt++)
        af[mt] = *(bf16x8*)&XL[(wm*32+mt*16+l16 + tapbase + tap)*264 + ib + quad*8];
      #pragma unroll
      for (int nt=0;nt<4;nt++)
        bf[nt] = *(bf16x8*)&Wb[(wn*64+nt*16+l16)*72 + ks + quad*8];
      #pragma unroll
      for (int mt=0;mt<2;mt++)
        #pragma unroll
        for (int nt=0;nt<4;nt++)
          acc[mt][nt] = __builtin_amdgcn_mfma_f32_16x16x32_bf16(af[mt], bf[nt], acc[mt][nt], 0,0,0);
    }
  }

  __syncthreads();
  for (int idx=tid; idx<64*16; idx+=256){
    int row = idx>>4, c8 = idx&15;
    *(uint4*)&XL[row*136 + c8*8] = *(const uint4*)&SKT[((size_t)b*Ll + 2*(t0+row)+par)*128 + c8*8];
  }
  for (int kc=0; kc<2; kc++){
    __syncthreads();
    #pragma unroll
    for (int it=0; it<4; it++){
      int idx = it*256+tid;
      int row = idx>>3, c8 = idx&7;
      *(uint4*)&Wb[row*72 + c8*8] = *(const uint4*)&FWSb[(size_t)row*128 + kc*64 + c8*8];
    }
    __syncthreads();
    #pragma unroll
    for (int ks=0; ks<64; ks+=32){
      bf16x8 af[2], bf[4];
      #pragma unroll
      for (int mt=0;mt<2;mt++)
        af[mt] = *(bf16x8*)&XL[(wm*32+mt*16+l16)*136 + kc*64 + ks + quad*8];
      #pragma unroll
      for (int nt=0;nt<4;nt++)
        bf[nt] = *(bf16x8*)&Wb[(wn*64+nt*16+l16)*72 + ks + quad*8];
      #pragma unroll
      for (int mt=0;mt<2;mt++)
        #pragma unroll
        for (int nt=0;nt<4;nt++)
          acc[mt][nt] = __builtin_amdgcn_mfma_f32_16x16x32_bf16(af[mt], bf[nt], acc[mt][nt], 0,0,0);
    }
  }

  float s1=0.f, s2=0.f;
  #pragma unroll
  for (int mt=0;mt<2;mt++)
    #pragma unroll
    for (int nt=0;nt<4;nt++)
      #pragma unroll
      for (int r=0;r<4;r++){
        int m = wm*32 + mt*16 + quad*4 + r;
        int lrow = 2*(t0+m) + par;
        int col = wn*64 + nt*16 + l16;
        float v = acc[mt][nt][r] + B2[col];
        h0[((size_t)b*Ll + lrow)*128 + col] = v;
        s1 += v; s2 += v*v;
      }
  red0[tid]=s1; red1[tid]=s2;
  __syncthreads();
  for (int st=128; st>0; st>>=1){
    if (tid<st){ red0[tid]+=red0[tid+st]; red1[tid]+=red1[tid+st]; }
    __syncthreads();
  }
  if (tid==0){ atomicAdd(&gst[b*2], red0[0]); atomicAdd(&gst[b*2+1], red1[0]); }
}

__global__ void k_gnfin(float* gst){
  int b = threadIdx.x;
  if (b < Bsz){
    float n = (float)Ll*128.f;
    float mu = gst[b*2]/n;
    float var = gst[b*2+1]/n - mu*mu;
    gst[8+b]=mu; gst[12+b]=rsqrtf(var+1e-5f);
  }
}

// Fused GroupNorm-apply + PReLU + layer-0 LayerNorm.
__global__ __launch_bounds__(256) void k_gnln(const float* __restrict__ h0, const float* __restrict__ gn_w,
                      const float* __restrict__ gn_b, const float* __restrict__ pa,
                      const float* __restrict__ gst, const float* __restrict__ lnw,
                      const float* __restrict__ lnb, float* __restrict__ hres,
                      unsigned short* __restrict__ xn){
  int row = blockIdx.x*4 + (threadIdx.x>>6);
  int lane = threadIdx.x & 63;
  int b = row >> 12;
  float mu_g = gst[8+b], inv_g = gst[12+b];
  float a = pa[0];
  const float* hp = h0 + (size_t)row*128;
  float u0 = (hp[lane]   -mu_g)*inv_g*gn_w[lane]    + gn_b[lane];
  float u1 = (hp[lane+64]-mu_g)*inv_g*gn_w[lane+64] + gn_b[lane+64];
  float v0 = u0>=0.f ? u0 : a*u0;
  float v1 = u1>=0.f ? u1 : a*u1;
  float* rp = hres + (size_t)row*128;
  rp[lane] = v0; rp[lane+64] = v1;
  float s = v0+v1, q = v0*v0+v1*v1;
  #pragma unroll
  for (int off=32; off>0; off>>=1){
    s += __shfl_xor(s, off, 64);
    q += __shfl_xor(q, off, 64);
  }
  float mu = s*(1.f/128.f);
  float rs = rsqrtf(q*(1.f/128.f)-mu*mu + 1e-5f);
  unsigned short* xp = xn + (size_t)row*128;
  xp[lane]    = f2bs((v0-mu)*rs*lnw[lane]    + lnb[lane]);
  xp[lane+64] = f2bs((v1-mu)*rs*lnw[lane+64] + lnb[lane+64]);
}

// LayerNorm over 128 ch; 4 rows/block, one wave per row. Writes bf16 XN.
__global__ __launch_bounds__(256) void k_ln(const float* __restrict__ hres, const float* __restrict__ lnw,
                     const float* __restrict__ lnb, unsigned short* __restrict__ xn){
  int row = blockIdx.x*4 + (threadIdx.x>>6);
  int lane = threadIdx.x & 63;
  const float* hp = hres + (size_t)row*128;
  float v0 = hp[lane], v1 = hp[lane+64];
  float s = v0+v1, q = v0*v0+v1*v1;
  #pragma unroll
  for (int off=32; off>0; off>>=1){
    s += __shfl_xor(s, off, 64);
    q += __shfl_xor(q, off, 64);
  }
  float mu = s*(1.f/128.f);
  float rs = rsqrtf(q*(1.f/128.f)-mu*mu + 1e-5f);
  unsigned short* xp = xn + (size_t)row*128;
  xp[lane]    = f2bs((v0-mu)*rs*lnw[lane]    + lnb[lane]);
  xp[lane+64] = f2bs((v1-mu)*rs*lnw[lane+64] + lnb[lane+64]);
}

// ---------------------------------------------------------------------------
// MFMA GEMM in_proj, batched over dirs (blockIdx.z): XZ2[dir] = rev_dir(XN) @ W_dir^T
// ---------------------------------------------------------------------------
__global__ __launch_bounds__(256) void k_gemm_in(const unsigned short* __restrict__ A,
                          const unsigned short* __restrict__ W,
                          unsigned short* __restrict__ C){
  __shared__ unsigned short As[128*72];
  __shared__ unsigned short Bs[128*72];
  int tid = threadIdx.x;
  int row0 = blockIdx.x*128;
  int n0   = blockIdx.y*128;
  int dir  = blockIdx.z;
  const unsigned short* Wp = W + (size_t)dir*512*128;
  unsigned short* Cp = C + (size_t)dir*Bsz*Ll*512;
  int wave = tid>>6, lane = tid&63;
  int wm = wave>>1, wn = wave&1;
  int quad = lane>>4, l16 = lane&15;
  f32x4 acc[4][4];
  #pragma unroll
  for (int i=0;i<4;i++)
    #pragma unroll
    for (int j=0;j<4;j++) acc[i][j] = (f32x4){0.f,0.f,0.f,0.f};

  for (int kb=0; kb<128; kb+=64){
    __syncthreads();
    #pragma unroll
    for (int it=0; it<4; it++){
      int idx = it*256 + tid;
      int row = idx>>3, c8 = idx&7;
      int r = row0 + row;
      int p = r & (Ll-1); int bb = r >> 12;
      int src = (bb<<12) + (dir ? (Ll-1-p) : p);
      *(uint4*)&As[row*72 + c8*8] = *(const uint4*)&A[(size_t)src*128 + kb + c8*8];
      *(uint4*)&Bs[row*72 + c8*8] = *(const uint4*)&Wp[(size_t)(n0+row)*128 + kb + c8*8];
    }
    __syncthreads();
    #pragma unroll
    for (int ks=0; ks<64; ks+=32){
      bf16x8 af[4], bf[4];
      #pragma unroll
      for (int mt=0;mt<4;mt++)
        af[mt] = *(bf16x8*)&As[(wm*64+mt*16+l16)*72 + ks + quad*8];
      #pragma unroll
      for (int nt=0;nt<4;nt++)
        bf[nt] = *(bf16x8*)&Bs[(wn*64+nt*16+l16)*72 + ks + quad*8];
      #pragma unroll
      for (int mt=0;mt<4;mt++)
        #pragma unroll
        for (int nt=0;nt<4;nt++)
          acc[mt][nt] = __builtin_amdgcn_mfma_f32_16x16x32_bf16(af[mt], bf[nt], acc[mt][nt], 0,0,0);
    }
  }
  #pragma unroll
  for (int mt=0;mt<4;mt++)
    #pragma unroll
    for (int nt=0;nt<4;nt++)
      #pragma unroll
      for (int r=0;r<4;r++){
        int row = row0 + wm*64 + mt*16 + quad*4 + r;
        int col = n0 + wn*64 + nt*16 + l16;
        Cp[(size_t)row*512 + col] = f2bs(acc[mt][nt][r]);
      }
}

// ---------------------------------------------------------------------------
// Combined out_proj: HR[l] += Y0[l]@W0^T + Y1[rev l]@W1^T  (K=512, both dirs)
// ---------------------------------------------------------------------------
__global__ __launch_bounds__(256) void k_gemm_out(const unsigned short* __restrict__ Y,
                           const unsigned short* __restrict__ W,
                           float* __restrict__ C){
  __shared__ unsigned short As[64*72];
  __shared__ unsigned short Bs[128*72];
  int tid = threadIdx.x;
  int row0 = blockIdx.x*64;
  int wave = tid>>6, lane = tid&63;
  int wm = wave>>1, wn = wave&1;
  int quad = lane>>4, l16 = lane&15;
  const size_t planeY = (size_t)Bsz*Ll*256;
  f32x4 acc[2][4];
  #pragma unroll
  for (int i=0;i<2;i++)
    #pragma unroll
    for (int j=0;j<4;j++) acc[i][j] = (f32x4){0.f,0.f,0.f,0.f};

  for (int kc=0; kc<8; kc++){
    int dirp = kc>>2;
    int kb = (kc&3)*64;
    const unsigned short* Wp = W + (size_t)dirp*128*256;
    __syncthreads();
    #pragma unroll
    for (int it=0; it<2; it++){
      int idx = it*256 + tid;
      int row = idx>>3, c8 = idx&7;
      int r = row0 + row;
      int p = r & (Ll-1); int bb = r >> 12;
      int srow = dirp ? ((bb<<12) + (Ll-1-p)) : r;
      *(uint4*)&As[row*72 + c8*8] = *(const uint4*)&Y[dirp*planeY + (size_t)srow*256 + kb + c8*8];
    }
    #pragma unroll
    for (int it=0; it<4; it++){
      int idx = it*256 + tid;
      int row = idx>>3, c8 = idx&7;
      *(uint4*)&Bs[row*72 + c8*8] = *(const uint4*)&Wp[(size_t)row*256 + kb + c8*8];
    }
    __syncthreads();
    #pragma unroll
    for (int ks=0; ks<64; ks+=32){
      bf16x8 af[2], bf[4];
      #pragma unroll
      for (int mt=0;mt<2;mt++)
        af[mt] = *(bf16x8*)&As[(wm*32+mt*16+l16)*72 + ks + quad*8];
      #pragma unroll
      for (int nt=0;nt<4;nt++)
        bf[nt] = *(bf16x8*)&Bs[(wn*64+nt*16+l16)*72 + ks + quad*8];
      #pragma unroll
      for (int mt=0;mt<2;mt++)
        #pragma unroll
        for (int nt=0;nt<4;nt++)
          acc[mt][nt] = __builtin_amdgcn_mfma_f32_16x16x32_bf16(af[mt], bf[nt], acc[mt][nt], 0,0,0);
    }
  }
  #pragma unroll
  for (int mt=0;mt<2;mt++)
    #pragma unroll
    for (int nt=0;nt<4;nt++)
      #pragma unroll
      for (int r=0;r<4;r++){
        int row = row0 + wm*32 + mt*16 + quad*4 + r;
        int col = wn*64 + nt*16 + l16;
        C[(size_t)row*128 + col] += acc[mt][nt][r];
      }
}

// ---------------------------------------------------------------------------
// Fused depthwise conv (K=4, sliding window) + SiLU + MFMA x_proj.
// Batched over dirs (blockIdx.y). dt is computed on the fly in the scans.
// ---------------------------------------------------------------------------
__global__ __launch_bounds__(256) void k_xproj3(const unsigned short* __restrict__ xz,
                        const unsigned short* __restrict__ wxb,
                        const float* __restrict__ cw, const float* __restrict__ cb,
                        unsigned short* __restrict__ xib, float* __restrict__ dbl){
  __shared__ unsigned short xiS[64*264];
  __shared__ unsigned short Bs[64*72];
  int tid = threadIdx.x;
  int dir = blockIdx.y;
  xz  += (size_t)dir*Bsz*Ll*512;
  wxb += (size_t)dir*64*256;
  cw  += dir*1024;
  cb  += dir*256;
  xib += (size_t)dir*Bsz*Ll*256;
  dbl += (size_t)dir*Bsz*Ll*40;
  size_t row0 = (size_t)blockIdx.x*64;
  int p0 = (int)(row0 & (Ll-1));

  // ---- conv phase: thread = d ----
  {
    int d = tid;
    float4 w4 = *(const float4*)&cw[d*4];
    float bias = cb[d];
    float w0, w1, w2;
    if (p0 == 0){ w0=0.f; w1=0.f; w2=0.f; }
    else {
      w0 = bs2f(xz[(row0-3)*512 + d]);
      w1 = bs2f(xz[(row0-2)*512 + d]);
      w2 = bs2f(xz[(row0-1)*512 + d]);
    }
    #pragma unroll 4
    for (int rr=0; rr<64; rr++){
      float xv = bs2f(xz[(row0+rr)*512 + d]);
      float acc = bias + w4.x*w0 + w4.y*w1 + w4.z*w2 + w4.w*xv;
      float v = acc/(1.f+__expf(-acc));
      unsigned short us = f2bs(v);
      xiS[rr*264 + d] = us;
      xib[(row0+rr)*256 + d] = us;
      w0=w1; w1=w2; w2=xv;
    }
  }

  // ---- MFMA x_proj: A = xiS (LDS), B = wxb ----
  int wave = tid>>6, lane = tid&63;
  int quad = lane>>4, l16 = lane&15;
  f32x4 acc[4];
  #pragma unroll
  for (int j=0;j<4;j++) acc[j] = (f32x4){0.f,0.f,0.f,0.f};

  for (int kb=0; kb<256; kb+=64){
    __syncthreads();
    #pragma unroll
    for (int it=0; it<2; it++){
      int idx = it*256 + tid;
      int row = idx>>3, c8 = idx&7;
      *(uint4*)&Bs[row*72 + c8*8] = *(const uint4*)&wxb[(size_t)row*256 + kb + c8*8];
    }
    __syncthreads();
    #pragma unroll
    for (int ks=0; ks<64; ks+=32){
      bf16x8 af = *(bf16x8*)&xiS[(wave*16+l16)*264 + kb + ks + quad*8];
      #pragma unroll
      for (int nt=0;nt<4;nt++){
        bf16x8 bf = *(bf16x8*)&Bs[(nt*16+l16)*72 + ks + quad*8];
        acc[nt] = __builtin_amdgcn_mfma_f32_16x16x32_bf16(af, bf, acc[nt], 0,0,0);
      }
    }
  }
  #pragma unroll
  for (int nt=0;nt<4;nt++)
    #pragma unroll
    for (int r=0;r<4;r++){
      int m = wave*16 + quad*4 + r;
      int col = nt*16 + l16;
      if (col < 40) dbl[(row0+m)*40 + col] = acc[nt][r];
    }
}

// ---------------------------------------------------------------------------
// Chunked scan, batched over dirs; dt computed on the fly from dbl[0:8]+dtw.
// Fast path: A[n] == (n+1)*A[0] (true for this model's A_log = log(1..16))
// -> 16 exps collapse to 1 exp + running products.
// ---------------------------------------------------------------------------
__global__ __launch_bounds__(256) void k_scan1(const float* __restrict__ dbl,
                       const unsigned short* __restrict__ xib, const float* __restrict__ Alog,
                       const float* __restrict__ dtw, const float* __restrict__ dtb,
                       float* __restrict__ P, float* __restrict__ Q){
  __shared__ float dtrS[CH][8];
  __shared__ float BcS[CH][16];
  int b = blockIdx.y, c = blockIdx.x, dir = blockIdx.z;
  int d = threadIdx.x;
  const float* dblP = dbl + (size_t)dir*Bsz*Ll*40;
  const unsigned short* xiP = xib + (size_t)dir*Bsz*Ll*256;
  size_t base = (size_t)b*Ll + (size_t)c*CH;
  for (int idx=d; idx<CH*24; idx+=256){
    int p = idx/24, r = idx%24;
    float v = dblP[(base+p)*40 + r];
    if (r < 8) dtrS[p][r] = v; else BcS[p][r-8] = v;
  }
  float A[16];
  #pragma unroll
  for (int j=0;j<4;j++){
    float4 a4 = *(const float4*)&Alog[(size_t)dir*4096 + d*16 + j*4];
    A[4*j]=-__expf(a4.x); A[4*j+1]=-__expf(a4.y); A[4*j+2]=-__expf(a4.z); A[4*j+3]=-__expf(a4.w);
  }
  bool chain = true;
  #pragma unroll
  for (int n=1;n<16;n++){
    float expect = A[0]*(float)(n+1);
    if (fabsf(A[n]-expect) > 1e-3f*fabsf(expect)) chain = false;
  }
  float wv[8];
  {
    const float* dw = dtw + (size_t)dir*2048 + d*8;
    float4 w0 = *(const float4*)&dw[0];
    float4 w1 = *(const float4*)&dw[4];
    wv[0]=w0.x; wv[1]=w0.y; wv[2]=w0.z; wv[3]=w0.w;
    wv[4]=w1.x; wv[5]=w1.y; wv[6]=w1.z; wv[7]=w1.w;
  }
  float bbt = dtb[dir*256 + d];
  __syncthreads();
  float h[16], pr[16];
  #pragma unroll
  for (int n=0;n<16;n++){ h[n]=0.f; pr[n]=1.f; }
  const unsigned short* xip = xiP + base*256 + d;
  if (chain){
    float A0 = A[0];
    float E = 1.f;
    for (int p=0;p<CH;p++){
      float a0 = bbt;
      #pragma unroll
      for (int r=0;r<8;r++) a0 += dtrS[p][r]*wv[r];
      float dtv = (a0>20.f)? a0 : log1pf(__expf(a0));
      float xiv = bs2f(xip[(size_t)p*256]);
      float dx = dtv*xiv;
      float e1 = __expf(dtv*A0);
      E *= e1;
      float a = 1.f;
      #pragma unroll
      for (int n=0;n<16;n++){
        a *= e1;
        h[n] = a*h[n] + BcS[p][n]*dx;
      }
    }
    float t = 1.f;
    #pragma unroll
    for (int n=0;n<16;n++){ t *= E; pr[n] = t; }
  } else {
    for (int p=0;p<CH;p++){
      float a0 = bbt;
      #pragma unroll
      for (int r=0;r<8;r++) a0 += dtrS[p][r]*wv[r];
      float dtv = (a0>20.f)? a0 : log1pf(__expf(a0));
      float xiv = bs2f(xip[(size_t)p*256]);
      float dx = dtv*xiv;
      #pragma unroll
      for (int n=0;n<16;n++){
        float a = __expf(dtv*A[n]);
        h[n] = a*h[n] + BcS[p][n]*dx;
        pr[n] *= a;
      }
    }
  }
  size_t sbase = (size_t)dir*Bsz*NC*4096 + ((size_t)(b*NC + c))*4096 + d*16;
  #pragma unroll
  for (int j=0;j<4;j++){
    *(float4*)&P[sbase + 4*j] = (float4){pr[4*j],pr[4*j+1],pr[4*j+2],pr[4*j+3]};
    *(float4*)&Q[sbase + 4*j] = (float4){h[4*j],h[4*j+1],h[4*j+2],h[4*j+3]};
  }
}

// In-place: Q[c] is read, then overwritten with the chunk-START state.
__global__ __launch_bounds__(256) void k_scan2(const float* __restrict__ P, float* __restrict__ Q){
  int b = blockIdx.y, dir = blockIdx.z;
  int dn = blockIdx.x*256 + threadIdx.x;   // 0..4095
  size_t plane = (size_t)dir*Bsz*NC*4096;
  float H = 0.f;
  for (int c=0;c<NC;c++){
    size_t idx = plane + ((size_t)(b*NC + c))*4096 + dn;
    float p = P[idx];
    float q = Q[idx];
    Q[idx] = H;
    H = p*H + q;
  }
}

// Phase 3: re-scan from start states; y = (sum_n h*Cc + Dp*xi)*silu(z),
// written IN-PLACE over the xi plane.
__global__ __launch_bounds__(256) void k_scan3(const float* __restrict__ dbl,
                       unsigned short* xiy, const float* __restrict__ Alog,
                       const float* __restrict__ dtw, const float* __restrict__ dtb,
                       const float* __restrict__ Dpw, const float* __restrict__ Hs,
                       const unsigned short* __restrict__ xz){
  __shared__ float dtrS[CH][8];
  __shared__ float BcS[CH][16];
  __shared__ float CcS[CH][16];
  int b = blockIdx.y, c = blockIdx.x, dir = blockIdx.z;
  int d = threadIdx.x;
  const float* dblP = dbl + (size_t)dir*Bsz*Ll*40;
  unsigned short* xiP = xiy + (size_t)dir*Bsz*Ll*256;
  const unsigned short* xzP = xz + (size_t)dir*Bsz*Ll*512;
  size_t base = (size_t)b*Ll + (size_t)c*CH;
  for (int idx=d; idx<CH*40; idx+=256){
    int p = idx/40, r = idx%40;
    float v = dblP[(base+p)*40 + r];
    if (r < 8) dtrS[p][r] = v;
    else if (r < 24) BcS[p][r-8] = v;
    else CcS[p][r-24] = v;
  }
  float A[16];
  #pragma unroll
  for (int j=0;j<4;j++){
    float4 a4 = *(const float4*)&Alog[(size_t)dir*4096 + d*16 + j*4];
    A[4*j]=-__expf(a4.x); A[4*j+1]=-__expf(a4.y); A[4*j+2]=-__expf(a4.z); A[4*j+3]=-__expf(a4.w);
  }
  bool chain = true;
  #pragma unroll
  for (int n=1;n<16;n++){
    float expect = A[0]*(float)(n+1);
    if (fabsf(A[n]-expect) > 1e-3f*fabsf(expect)) chain = false;
  }
  float wv[8];
  {
    const float* dw = dtw + (size_t)dir*2048 + d*8;
    float4 w0 = *(const float4*)&dw[0];
    float4 w1 = *(const float4*)&dw[4];
    wv[0]=w0.x; wv[1]=w0.y; wv[2]=w0.z; wv[3]=w0.w;
    wv[4]=w1.x; wv[5]=w1.y; wv[6]=w1.z; wv[7]=w1.w;
  }
  float bbt = dtb[dir*256 + d];
  float Dp = Dpw[dir*256 + d];
  float h[16];
  size_t sbase = (size_t)dir*Bsz*NC*4096 + ((size_t)(b*NC + c))*4096 + d*16;
  #pragma unroll
  for (int j=0;j<4;j++){
    float4 h4 = *(const float4*)&Hs[sbase + 4*j];
    h[4*j]=h4.x; h[4*j+1]=h4.y; h[4*j+2]=h4.z; h[4*j+3]=h4.w;
  }
  __syncthreads();
  unsigned short* xip = xiP + base*256 + d;
  const unsigned short* zp = xzP + base*512 + 256 + d;
  if (chain){
    float A0 = A[0];
    for (int p=0;p<CH;p++){
      float a0 = bbt;
      #pragma unroll
      for (int r=0;r<8;r++) a0 += dtrS[p][r]*wv[r];
      float dtv = (a0>20.f)? a0 : log1pf(__expf(a0));
      float xiv = bs2f(xip[(size_t)p*256]);
      float dx = dtv*xiv;
      float e1 = __expf(dtv*A0);
      float a = 1.f;
      float acc = 0.f;
      #pragma unroll
      for (int n=0;n<16;n++){
        a *= e1;
        h[n] = a*h[n] + BcS[p][n]*dx;
        acc += h[n]*CcS[p][n];
      }
      float z = bs2f(zp[(size_t)p*512]);
      float g = z/(1.f+__expf(-z));
      xip[(size_t)p*256] = f2bs((acc + Dp*xiv)*g);
    }
  } else {
    for (int p=0;p<CH;p++){
      float a0 = bbt;
      #pragma unroll
      for (int r=0;r<8;r++) a0 += dtrS[p][r]*wv[r];
      float dtv = (a0>20.f)? a0 : log1pf(__expf(a0));
      float xiv = bs2f(xip[(size_t)p*256]);
      float dx = dtv*xiv;
      float acc = 0.f;
      #pragma unroll
      for (int n=0;n<16;n++){
        float a = __expf(dtv*A[n]);
        h[n] = a*h[n] + BcS[p][n]*dx;
        acc += h[n]*CcS[p][n];
      }
      float z = bs2f(zp[(size_t)p*512]);
      float g = z/(1.f+__expf(-z));
      xip[(size_t)p*256] = f2bs((acc + Dp*xiv)*g);
    }
  }
}

// final transpose (B,L,128) fp32 -> (B,128,L) fp32
__global__ __launch_bounds__(256) void k_final(const float* __restrict__ hres, float* __restrict__ out){
  __shared__ float tile[64*129];
  int b = blockIdx.y, l0 = blockIdx.x*64;
  int tid = threadIdx.x;
  for (int q=0;q<32;q++){
    int idx = q*256 + tid;
    int l = idx >> 7, c = idx & 127;
    tile[l*129 + c] = hres[((size_t)b*Ll + l0 + l)*128 + c];
  }
  __syncthreads();
  int lo = tid & 63; int cbase = tid >> 6;
  for (int q=0;q<32;q++){
    int c = cbase + q*4;
    out[((size_t)b*128 + c)*Ll + l0 + lo] = tile[lo*129 + c];
  }
}

extern "C" void kernel_launch(void* const* d_in, const int* in_sizes, int n_in,
                              void* d_out, int out_size, void* d_ws, size_t ws_size,
                              hipStream_t stream){
  const float* x      = (const float*)d_in[0];
  const float* skip   = (const float*)d_in[1];
  const float* up_w   = (const float*)d_in[2];
  const float* up_b   = (const float*)d_in[3];
  const float* fus_w  = (const float*)d_in[4];
  const float* fus_b  = (const float*)d_in[5];
  const float* gn_w   = (const float*)d_in[6];
  const float* gn_b   = (const float*)d_in[7];
  const float* pa     = (const float*)d_in[8];
  const float* ln_w   = (const float*)d_in[9];
  const float* ln_b   = (const float*)d_in[10];
  const float* in_w   = (const float*)d_in[11];
  const float* conv_w = (const float*)d_in[12];
  const float* conv_b = (const float*)d_in[13];
  const float* xproj_w= (const float*)d_in[14];
  const float* dtproj_w=(const float*)d_in[15];
  const float* dtproj_b=(const float*)d_in[16];
  const float* A_log  = (const float*)d_in[17];
  const float* Dp     = (const float*)d_in[18];
  const float* out_w  = (const float*)d_in[19];

  // Workspace (~87 MB; round-7 bracket: <=100 MB safe).
  float* w = (float*)d_ws;
  size_t off=0;
  float* B2 = w+off; off += 128;
  float* GST= w+off; off += 16;
  off = (off+3)&~(size_t)3;
  float* HR = w+off; off += (size_t)Bsz*Ll*128;
  float* DBL2= w+off; off += 2*(size_t)Bsz*Ll*40;
  unsigned short* XNB = (unsigned short*)(w+off); off += (size_t)Bsz*Ll*128/2;
  unsigned short* XZB2= (unsigned short*)(w+off); off += 2*(size_t)Bsz*Ll*512/2;
  unsigned short* IWB = (unsigned short*)(w+off); off += 2*2*512*128/2;
  unsigned short* OWB = (unsigned short*)(w+off); off += 2*2*128*256/2;
  unsigned short* WXB = (unsigned short*)(w+off); off += 2*2*64*256/2;
  unsigned short* WEb = (unsigned short*)(w+off); off += 768*128/2;
  unsigned short* WOb = (unsigned short*)(w+off); off += 512*128/2;
  unsigned short* FWSb= (unsigned short*)(w+off); off += 128*128/2;
  size_t planeS = (size_t)Bsz*NC*4096;       // 1,048,576 @ NC=64
  float* U1 = w+off; off += 4*planeS;
  unsigned short* XT  = (unsigned short*)U1;
  unsigned short* SKT = (unsigned short*)(U1 + 1049604);
  float* SP = U1;
  float* SQ = U1 + 2*planeS;
  float* U2 = w+off; off += 2*(size_t)Bsz*Ll*128;
  float* H0 = U2;
  unsigned short* XIB2 = (unsigned short*)U2;

  hipMemsetAsync(GST, 0, 16*sizeof(float), stream);
  k_cvt<<<(2*2*512*128+255)/256,256,0,stream>>>(in_w, IWB, 2*2*512*128);
  k_cvt<<<(2*2*128*256+255)/256,256,0,stream>>>(out_w, OWB, 2*2*128*256);
  k_prepx<<<dim3(64,4),256,0,stream>>>(xproj_w, WXB);
  k_compose<<<256,128,0,stream>>>(up_w, fus_w, fus_b, up_b, WEb, WOb, FWSb, B2);
  k_tx<<<dim3(Tt/64, 4, Bsz),256,0,stream>>>(x, XT);
  k_zero<<<1,256,0,stream>>>(XT);
  k_ts<<<dim3(Ll/64, 2, Bsz),256,0,stream>>>(skip, SKT);
  k_up<<<dim3(32, 2, Bsz),256,0,stream>>>(XT, SKT, WEb, WOb, FWSb, B2, H0, GST);
  k_gnfin<<<1,64,0,stream>>>(GST);
  k_gnln<<<Bsz*Ll/4,256,0,stream>>>(H0, gn_w, gn_b, pa, GST, ln_w, ln_b, HR, XNB);
  for (int i=0;i<2;i++){
    if (i==1) k_ln<<<Bsz*Ll/4,256,0,stream>>>(HR, ln_w + 128, ln_b + 128, XNB);
    k_gemm_in<<<dim3(128,4,2),256,0,stream>>>(XNB, IWB + (size_t)(i*2)*512*128, XZB2);
    k_xproj3<<<dim3(Bsz*Ll/64,2),256,0,stream>>>(XZB2, WXB + (size_t)(i*2)*64*256,
                                                 conv_w + (i*2)*1024, conv_b + (i*2)*256,
                                                 XIB2, DBL2);
    k_scan1<<<dim3(NC,Bsz,2),256,0,stream>>>(DBL2, XIB2, A_log + (i*2)*4096,
                                             dtproj_w + (i*2)*2048, dtproj_b + (i*2)*256, SP, SQ);
    k_scan2<<<dim3(16,Bsz,2),256,0,stream>>>(SP, SQ);
    k_scan3<<<dim3(NC,Bsz,2),256,0,stream>>>(DBL2, XIB2, A_log + (i*2)*4096,
                                             dtproj_w + (i*2)*2048, dtproj_b + (i*2)*256,
                                             Dp + (i*2)*256, SQ, XZB2);
    k_gemm_out<<<256,256,0,stream>>>(XIB2, OWB + (size_t)(i*2)*128*256, HR);
  }
  k_final<<<dim3(Ll/64,Bsz),256,0,stream>>>(HR, (float*)d_out);
}

// Round 14
// 452.441 us; speedup vs baseline: 1.5824x; 1.1524x over previous
//
#include <hip/hip_runtime.h>
#include <hip/hip_bf16.h>

#define Bsz 4
#define Tt 2048
#define Ll 4096
#define NC 64      // chunks for scan (batched over dirs: 512 blocks/dispatch)
#define CH 64      // steps per chunk (NC*CH == Ll)

typedef short bf16x8 __attribute__((ext_vector_type(8)));
typedef float f32x4 __attribute__((ext_vector_type(4)));

static __device__ __forceinline__ float bs2f(unsigned short u){
  union{float f; unsigned int i;} v; v.i = ((unsigned int)u)<<16; return v.f;
}
static __device__ __forceinline__ unsigned short f2bs(float f){
  union{float f; unsigned int i;} v; v.f = f;
  unsigned int r = (v.i + 0x7fffu + ((v.i>>16)&1u)) >> 16;
  return (unsigned short)r;
}

// fp32 -> bf16 bulk convert
__global__ void k_cvt(const float* __restrict__ src, unsigned short* __restrict__ dst, int n){
  int i = blockIdx.x*256 + threadIdx.x;
  if (i < n) dst[i] = f2bs(src[i]);
}

// pad xproj_w (4 branches, 40x256) to zero-filled 64x256 bf16
__global__ void k_prepx(const float* __restrict__ xw, unsigned short* __restrict__ wxb){
  int row = blockIdx.x, br = blockIdx.y, col = threadIdx.x;
  float v = (row < 40) ? xw[((size_t)br*40 + row)*256 + col] : 0.f;
  wxb[((size_t)br*64 + row)*256 + col] = f2bs(v);
}

// ---------------------------------------------------------------------------
// Compose upsample-conv weights with fuse matmul; emit bf16 GEMM-ready layouts.
// ---------------------------------------------------------------------------
__global__ void k_compose(const float* __restrict__ up_w, const float* __restrict__ fus_w,
                          const float* __restrict__ fus_b, const float* __restrict__ up_b,
                          unsigned short* __restrict__ WEb, unsigned short* __restrict__ WOb,
                          unsigned short* __restrict__ FWSb, float* __restrict__ BIAS2){
  int i = blockIdx.x;     // 0..255
  int o = threadIdx.x;    // 0..127
  float a0=0.f,a1=0.f,a2=0.f,a3=0.f,a4=0.f;
  for (int c=0;c<256;c++){
    float f = fus_w[o*384+c];
    const float* w = up_w + ((size_t)i*256+c)*5;
    a0 += f*w[0]; a1 += f*w[1]; a2 += f*w[2];
    a3 += f*w[3]; a4 += f*w[4];
  }
  WEb[(size_t)o*768 +       i] = f2bs(a4);
  WEb[(size_t)o*768 + 256 + i] = f2bs(a2);
  WEb[(size_t)o*768 + 512 + i] = f2bs(a0);
  WOb[(size_t)o*512 +       i] = f2bs(a3);
  WOb[(size_t)o*512 + 256 + i] = f2bs(a1);
  if (i<128) FWSb[o*128 + i] = f2bs(fus_w[o*384+256+i]);
  if (i==0){
    float bb = fus_b[o];
    for (int c=0;c<256;c++) bb += fus_w[o*384+c]*up_b[c];
    BIAS2[o]=bb;
  }
}

// transpose x (B,256,T) f32 -> XT (B, T+2, 256) bf16, row t stored at t+1
__global__ __launch_bounds__(256) void k_tx(const float* __restrict__ x, unsigned short* __restrict__ XT){
  __shared__ float tile[64][65];
  int b=blockIdx.z, t0=blockIdx.x*64, i0=blockIdx.y*64;
  int tid=threadIdx.x;
  for (int it=0;it<16;it++){
    int idx=it*256+tid; int ii=idx>>6, tt=idx&63;
    tile[ii][tt] = x[((size_t)b*256+i0+ii)*Tt + t0+tt];
  }
  __syncthreads();
  for (int it=0;it<16;it++){
    int idx=it*256+tid; int tt=idx>>6, ii=idx&63;
    XT[((size_t)b*2050 + t0+tt+1)*256 + i0+ii] = f2bs(tile[ii][tt]);
  }
}

// zero XT halo rows (t=-1 and t=2048)
__global__ void k_zero(unsigned short* __restrict__ XT){
  int tid=threadIdx.x;
  for (int b=0;b<Bsz;b++){
    XT[((size_t)b*2050)*256 + tid] = 0;
    XT[((size_t)b*2050+2049)*256 + tid] = 0;
  }
}

// transpose skip (B,128,L) f32 -> SKT (B,L,128) bf16
__global__ __launch_bounds__(256) void k_ts(const float* __restrict__ skip, unsigned short* __restrict__ SKT){
  __shared__ float tile[64][65];
  int b=blockIdx.z, l0=blockIdx.x*64, s0=blockIdx.y*64;
  int tid=threadIdx.x;
  for (int it=0;it<16;it++){
    int idx=it*256+tid; int ss=idx>>6, ll=idx&63;
    tile[ss][ll] = skip[((size_t)b*128+s0+ss)*Ll + l0+ll];
  }
  __syncthreads();
  for (int it=0;it<16;it++){
    int idx=it*256+tid; int ll=idx>>6, ss=idx&63;
    SKT[((size_t)b*Ll + l0+ll)*128 + s0+ss] = f2bs(tile[ss][ll]);
  }
}

// ---------------------------------------------------------------------------
// MFMA upsample+fuse (see round-4 notes). Block = 64 t x 128 o, one parity.
// ---------------------------------------------------------------------------
__global__ __launch_bounds__(256) void k_up(const unsigned short* __restrict__ XT,
                     const unsigned short* __restrict__ SKT,
                     const unsigned short* __restrict__ WEb, const unsigned short* __restrict__ WOb,
                     const unsigned short* __restrict__ FWSb, const float* __restrict__ B2,
                     float* __restrict__ h0, float* __restrict__ gst){
  __shared__ unsigned short XL[66*264];
  __shared__ unsigned short Wb[128*72];
  __shared__ float red0[256], red1[256];
  int bt = blockIdx.x, par = blockIdx.y, b = blockIdx.z;
  int t0 = bt*64;
  int tid = threadIdx.x;
  int wave = tid>>6, lane = tid&63;
  int wm = wave>>1, wn = wave&1;
  int quad = lane>>4, l16 = lane&15;

  for (int idx=tid; idx<66*32; idx+=256){
    int row = idx>>5, c8 = idx&31;
    *(uint4*)&XL[row*264 + c8*8] = *(const uint4*)&XT[((size_t)b*2050 + t0 + row)*256 + c8*8];
  }

  const unsigned short* Wsrc = par ? WOb : WEb;
  const int Kw = par ? 512 : 768;
  const int tapbase = par ? 1 : 0;
  f32x4 acc[2][4];
  #pragma unroll
  for (int i=0;i<2;i++)
    #pragma unroll
    for (int j=0;j<4;j++) acc[i][j] = (f32x4){0.f,0.f,0.f,0.f};

  int nch = Kw>>6;
  for (int kc=0; kc<nch; kc++){
    __syncthreads();
    #pragma unroll
    for (int it=0; it<4; it++){
      int idx = it*256+tid;
      int row = idx>>3, c8 = idx&7;
      *(uint4*)&Wb[row*72 + c8*8] = *(const uint4*)&Wsrc[(size_t)row*Kw + kc*64 + c8*8];
    }
    __syncthreads();
    #pragma unroll
    for (int ks=0; ks<64; ks+=32){
      int kg = kc*64 + ks;
      int tap = kg>>8, ib = kg&255;
      bf16x8 af[2], bf[4];
      #pragma unroll
      for (int mt=0;mt<2;mt++)
        af[mt] = *(bf16x8*)&XL[(wm*32+mt*16+l16 + tapbase + tap)*264 + ib + quad*8];
      #pragma unroll
      for (int nt=0;nt<4;nt++)
        bf[nt] = *(bf16x8*)&Wb[(wn*64+nt*16+l16)*72 + ks + quad*8];
      #pragma unroll
      for (int mt=0;mt<2;mt++)
        #pragma unroll
        for (int nt=0;nt<4;nt++)
          acc[mt][nt] = __builtin_amdgcn_mfma_f32_16x16x32_bf16(af[mt], bf[nt], acc[mt][nt], 0,0,0);
    }
  }

  __syncthreads();
  for (int idx=tid; idx<64*16; idx+=256){
    int row = idx>>4, c8 = idx&15;
    *(uint4*)&XL[row*136 + c8*8] = *(const uint4*)&SKT[((size_t)b*Ll + 2*(t0+row)+par)*128 + c8*8];
  }
  for (int kc=0; kc<2; kc++){
    __syncthreads();
    #pragma unroll
    for (int it=0; it<4; it++){
      int idx = it*256+tid;
      int row = idx>>3, c8 = idx&7;
      *(uint4*)&Wb[row*72 + c8*8] = *(const uint4*)&FWSb[(size_t)row*128 + kc*64 + c8*8];
    }
    __syncthreads();
    #pragma unroll
    for (int ks=0; ks<64; ks+=32){
      bf16x8 af[2], bf[4];
      #pragma unroll
      for (int mt=0;mt<2;mt++)
        af[mt] = *(bf16x8*)&XL[(wm*32+mt*16+l16)*136 + kc*64 + ks + quad*8];
      #pragma unroll
      for (int nt=0;nt<4;nt++)
        bf[nt] = *(bf16x8*)&Wb[(wn*64+nt*16+l16)*72 + ks + quad*8];
      #pragma unroll
      for (int mt=0;mt<2;mt++)
        #pragma unroll
        for (int nt=0;nt<4;nt++)
          acc[mt][nt] = __builtin_amdgcn_mfma_f32_16x16x32_bf16(af[mt], bf[nt], acc[mt][nt], 0,0,0);
    }
  }

  float s1=0.f, s2=0.f;
  #pragma unroll
  for (int mt=0;mt<2;mt++)
    #pragma unroll
    for (int nt=0;nt<4;nt++)
      #pragma unroll
      for (int r=0;r<4;r++){
        int m = wm*32 + mt*16 + quad*4 + r;
        int lrow = 2*(t0+m) + par;
        int col = wn*64 + nt*16 + l16;
        float v = acc[mt][nt][r] + B2[col];
        h0[((size_t)b*Ll + lrow)*128 + col] = v;
        s1 += v; s2 += v*v;
      }
  red0[tid]=s1; red1[tid]=s2;
  __syncthreads();
  for (int st=128; st>0; st>>=1){
    if (tid<st){ red0[tid]+=red0[tid+st]; red1[tid]+=red1[tid+st]; }
    __syncthreads();
  }
  if (tid==0){ atomicAdd(&gst[b*2], red0[0]); atomicAdd(&gst[b*2+1], red1[0]); }
}

__global__ void k_gnfin(float* gst){
  int b = threadIdx.x;
  if (b < Bsz){
    float n = (float)Ll*128.f;
    float mu = gst[b*2]/n;
    float var = gst[b*2+1]/n - mu*mu;
    gst[8+b]=mu; gst[12+b]=rsqrtf(var+1e-5f);
  }
}

// Fused GroupNorm-apply + PReLU + layer-0 LayerNorm.
__global__ __launch_bounds__(256) void k_gnln(const float* __restrict__ h0, const float* __restrict__ gn_w,
                      const float* __restrict__ gn_b, const float* __restrict__ pa,
                      const float* __restrict__ gst, const float* __restrict__ lnw,
                      const float* __restrict__ lnb, float* __restrict__ hres,
                      unsigned short* __restrict__ xn){
  int row = blockIdx.x*4 + (threadIdx.x>>6);
  int lane = threadIdx.x & 63;
  int b = row >> 12;
  float mu_g = gst[8+b], inv_g = gst[12+b];
  float a = pa[0];
  const float* hp = h0 + (size_t)row*128;
  float u0 = (hp[lane]   -mu_g)*inv_g*gn_w[lane]    + gn_b[lane];
  float u1 = (hp[lane+64]-mu_g)*inv_g*gn_w[lane+64] + gn_b[lane+64];
  float v0 = u0>=0.f ? u0 : a*u0;
  float v1 = u1>=0.f ? u1 : a*u1;
  float* rp = hres + (size_t)row*128;
  rp[lane] = v0; rp[lane+64] = v1;
  float s = v0+v1, q = v0*v0+v1*v1;
  #pragma unroll
  for (int off=32; off>0; off>>=1){
    s += __shfl_xor(s, off, 64);
    q += __shfl_xor(q, off, 64);
  }
  float mu = s*(1.f/128.f);
  float rs = rsqrtf(q*(1.f/128.f)-mu*mu + 1e-5f);
  unsigned short* xp = xn + (size_t)row*128;
  xp[lane]    = f2bs((v0-mu)*rs*lnw[lane]    + lnb[lane]);
  xp[lane+64] = f2bs((v1-mu)*rs*lnw[lane+64] + lnb[lane+64]);
}

// LayerNorm over 128 ch; 4 rows/block, one wave per row. Writes bf16 XN.
__global__ __launch_bounds__(256) void k_ln(const float* __restrict__ hres, const float* __restrict__ lnw,
                     const float* __restrict__ lnb, unsigned short* __restrict__ xn){
  int row = blockIdx.x*4 + (threadIdx.x>>6);
  int lane = threadIdx.x & 63;
  const float* hp = hres + (size_t)row*128;
  float v0 = hp[lane], v1 = hp[lane+64];
  float s = v0+v1, q = v0*v0+v1*v1;
  #pragma unroll
  for (int off=32; off>0; off>>=1){
    s += __shfl_xor(s, off, 64);
    q += __shfl_xor(q, off, 64);
  }
  float mu = s*(1.f/128.f);
  float rs = rsqrtf(q*(1.f/128.f)-mu*mu + 1e-5f);
  unsigned short* xp = xn + (size_t)row*128;
  xp[lane]    = f2bs((v0-mu)*rs*lnw[lane]    + lnb[lane]);
  xp[lane+64] = f2bs((v1-mu)*rs*lnw[lane+64] + lnb[lane+64]);
}

// ---------------------------------------------------------------------------
// MFMA GEMM in_proj, batched over dirs (blockIdx.z): XZ2[dir] = rev_dir(XN) @ W_dir^T
// ---------------------------------------------------------------------------
__global__ __launch_bounds__(256) void k_gemm_in(const unsigned short* __restrict__ A,
                          const unsigned short* __restrict__ W,
                          unsigned short* __restrict__ C){
  __shared__ unsigned short As[128*72];
  __shared__ unsigned short Bs[128*72];
  int tid = threadIdx.x;
  int row0 = blockIdx.x*128;
  int n0   = blockIdx.y*128;
  int dir  = blockIdx.z;
  const unsigned short* Wp = W + (size_t)dir*512*128;
  unsigned short* Cp = C + (size_t)dir*Bsz*Ll*512;
  int wave = tid>>6, lane = tid&63;
  int wm = wave>>1, wn = wave&1;
  int quad = lane>>4, l16 = lane&15;
  f32x4 acc[4][4];
  #pragma unroll
  for (int i=0;i<4;i++)
    #pragma unroll
    for (int j=0;j<4;j++) acc[i][j] = (f32x4){0.f,0.f,0.f,0.f};

  for (int kb=0; kb<128; kb+=64){
    __syncthreads();
    #pragma unroll
    for (int it=0; it<4; it++){
      int idx = it*256 + tid;
      int row = idx>>3, c8 = idx&7;
      int r = row0 + row;
      int p = r & (Ll-1); int bb = r >> 12;
      int src = (bb<<12) + (dir ? (Ll-1-p) : p);
      *(uint4*)&As[row*72 + c8*8] = *(const uint4*)&A[(size_t)src*128 + kb + c8*8];
      *(uint4*)&Bs[row*72 + c8*8] = *(const uint4*)&Wp[(size_t)(n0+row)*128 + kb + c8*8];
    }
    __syncthreads();
    #pragma unroll
    for (int ks=0; ks<64; ks+=32){
      bf16x8 af[4], bf[4];
      #pragma unroll
      for (int mt=0;mt<4;mt++)
        af[mt] = *(bf16x8*)&As[(wm*64+mt*16+l16)*72 + ks + quad*8];
      #pragma unroll
      for (int nt=0;nt<4;nt++)
        bf[nt] = *(bf16x8*)&Bs[(wn*64+nt*16+l16)*72 + ks + quad*8];
      #pragma unroll
      for (int mt=0;mt<4;mt++)
        #pragma unroll
        for (int nt=0;nt<4;nt++)
          acc[mt][nt] = __builtin_amdgcn_mfma_f32_16x16x32_bf16(af[mt], bf[nt], acc[mt][nt], 0,0,0);
    }
  }
  #pragma unroll
  for (int mt=0;mt<4;mt++)
    #pragma unroll
    for (int nt=0;nt<4;nt++)
      #pragma unroll
      for (int r=0;r<4;r++){
        int row = row0 + wm*64 + mt*16 + quad*4 + r;
        int col = n0 + wn*64 + nt*16 + l16;
        Cp[(size_t)row*512 + col] = f2bs(acc[mt][nt][r]);
      }
}

// ---------------------------------------------------------------------------
// Combined out_proj: HR[l] += Y0[l]@W0^T + Y1[rev l]@W1^T  (K=512, both dirs)
// ---------------------------------------------------------------------------
__global__ __launch_bounds__(256) void k_gemm_out(const unsigned short* __restrict__ Y,
                           const unsigned short* __restrict__ W,
                           float* __restrict__ C){
  __shared__ unsigned short As[64*72];
  __shared__ unsigned short Bs[128*72];
  int tid = threadIdx.x;
  int row0 = blockIdx.x*64;
  int wave = tid>>6, lane = tid&63;
  int wm = wave>>1, wn = wave&1;
  int quad = lane>>4, l16 = lane&15;
  const size_t planeY = (size_t)Bsz*Ll*256;
  f32x4 acc[2][4];
  #pragma unroll
  for (int i=0;i<2;i++)
    #pragma unroll
    for (int j=0;j<4;j++) acc[i][j] = (f32x4){0.f,0.f,0.f,0.f};

  for (int kc=0; kc<8; kc++){
    int dirp = kc>>2;
    int kb = (kc&3)*64;
    const unsigned short* Wp = W + (size_t)dirp*128*256;
    __syncthreads();
    #pragma unroll
    for (int it=0; it<2; it++){
      int idx = it*256 + tid;
      int row = idx>>3, c8 = idx&7;
      int r = row0 + row;
      int p = r & (Ll-1); int bb = r >> 12;
      int srow = dirp ? ((bb<<12) + (Ll-1-p)) : r;
      *(uint4*)&As[row*72 + c8*8] = *(const uint4*)&Y[dirp*planeY + (size_t)srow*256 + kb + c8*8];
    }
    #pragma unroll
    for (int it=0; it<4; it++){
      int idx = it*256 + tid;
      int row = idx>>3, c8 = idx&7;
      *(uint4*)&Bs[row*72 + c8*8] = *(const uint4*)&Wp[(size_t)row*256 + kb + c8*8];
    }
    __syncthreads();
    #pragma unroll
    for (int ks=0; ks<64; ks+=32){
      bf16x8 af[2], bf[4];
      #pragma unroll
      for (int mt=0;mt<2;mt++)
        af[mt] = *(bf16x8*)&As[(wm*32+mt*16+l16)*72 + ks + quad*8];
      #pragma unroll
      for (int nt=0;nt<4;nt++)
        bf[nt] = *(bf16x8*)&Bs[(wn*64+nt*16+l16)*72 + ks + quad*8];
      #pragma unroll
      for (int mt=0;mt<2;mt++)
        #pragma unroll
        for (int nt=0;nt<4;nt++)
          acc[mt][nt] = __builtin_amdgcn_mfma_f32_16x16x32_bf16(af[mt], bf[nt], acc[mt][nt], 0,0,0);
    }
  }
  #pragma unroll
  for (int mt=0;mt<2;mt++)
    #pragma unroll
    for (int nt=0;nt<4;nt++)
      #pragma unroll
      for (int r=0;r<4;r++){
        int row = row0 + wm*32 + mt*16 + quad*4 + r;
        int col = wn*64 + nt*16 + l16;
        C[(size_t)row*128 + col] += acc[mt][nt][r];
      }
}

// ---------------------------------------------------------------------------
// Fused depthwise conv (K=4, sliding window) + SiLU + MFMA x_proj.
// ---------------------------------------------------------------------------
__global__ __launch_bounds__(256) void k_xproj3(const unsigned short* __restrict__ xz,
                        const unsigned short* __restrict__ wxb,
                        const float* __restrict__ cw, const float* __restrict__ cb,
                        unsigned short* __restrict__ xib, float* __restrict__ dbl){
  __shared__ unsigned short xiS[64*264];
  __shared__ unsigned short Bs[64*72];
  int tid = threadIdx.x;
  int dir = blockIdx.y;
  xz  += (size_t)dir*Bsz*Ll*512;
  wxb += (size_t)dir*64*256;
  cw  += dir*1024;
  cb  += dir*256;
  xib += (size_t)dir*Bsz*Ll*256;
  dbl += (size_t)dir*Bsz*Ll*40;
  size_t row0 = (size_t)blockIdx.x*64;
  int p0 = (int)(row0 & (Ll-1));

  // ---- conv phase: thread = d ----
  {
    int d = tid;
    float4 w4 = *(const float4*)&cw[d*4];
    float bias = cb[d];
    float w0, w1, w2;
    if (p0 == 0){ w0=0.f; w1=0.f; w2=0.f; }
    else {
      w0 = bs2f(xz[(row0-3)*512 + d]);
      w1 = bs2f(xz[(row0-2)*512 + d]);
      w2 = bs2f(xz[(row0-1)*512 + d]);
    }
    #pragma unroll 4
    for (int rr=0; rr<64; rr++){
      float xv = bs2f(xz[(row0+rr)*512 + d]);
      float acc = bias + w4.x*w0 + w4.y*w1 + w4.z*w2 + w4.w*xv;
      float v = acc/(1.f+__expf(-acc));
      unsigned short us = f2bs(v);
      xiS[rr*264 + d] = us;
      xib[(row0+rr)*256 + d] = us;
      w0=w1; w1=w2; w2=xv;
    }
  }

  // ---- MFMA x_proj: A = xiS (LDS), B = wxb ----
  int wave = tid>>6, lane = tid&63;
  int quad = lane>>4, l16 = lane&15;
  f32x4 acc[4];
  #pragma unroll
  for (int j=0;j<4;j++) acc[j] = (f32x4){0.f,0.f,0.f,0.f};

  for (int kb=0; kb<256; kb+=64){
    __syncthreads();
    #pragma unroll
    for (int it=0; it<2; it++){
      int idx = it*256 + tid;
      int row = idx>>3, c8 = idx&7;
      *(uint4*)&Bs[row*72 + c8*8] = *(const uint4*)&wxb[(size_t)row*256 + kb + c8*8];
    }
    __syncthreads();
    #pragma unroll
    for (int ks=0; ks<64; ks+=32){
      bf16x8 af = *(bf16x8*)&xiS[(wave*16+l16)*264 + kb + ks + quad*8];
      #pragma unroll
      for (int nt=0;nt<4;nt++){
        bf16x8 bf = *(bf16x8*)&Bs[(nt*16+l16)*72 + ks + quad*8];
        acc[nt] = __builtin_amdgcn_mfma_f32_16x16x32_bf16(af, bf, acc[nt], 0,0,0);
      }
    }
  }
  #pragma unroll
  for (int nt=0;nt<4;nt++)
    #pragma unroll
    for (int r=0;r<4;r++){
      int m = wave*16 + quad*4 + r;
      int col = nt*16 + l16;
      if (col < 40) dbl[(row0+m)*40 + col] = acc[nt][r];
    }
}

// pw[n] = e1^(n+1) via squaring tree (depth 4, all independent FMAs after).
#define POWTREE(e1, pw) { \
  float e2 = (e1)*(e1); float e4 = e2*e2; float e8 = e4*e4; \
  pw[0]=(e1); pw[1]=e2; pw[2]=e2*(e1); pw[3]=e4; pw[4]=e4*(e1); pw[5]=e4*e2; \
  pw[6]=e4*pw[2]; pw[7]=e8; pw[8]=e8*(e1); pw[9]=e8*e2; pw[10]=e8*pw[2]; \
  pw[11]=e8*e4; pw[12]=e8*pw[4]; pw[13]=e8*pw[5]; pw[14]=e8*pw[6]; pw[15]=e8*e8; }

// ---------------------------------------------------------------------------
// Chunked scan, batched over dirs; dt computed on the fly from dbl[0:8]+dtw.
// LDS holds raw 40-float dbl rows; all in-loop LDS reads are b128 broadcasts.
// ---------------------------------------------------------------------------
__global__ __launch_bounds__(256) void k_scan1(const float* __restrict__ dbl,
                       const unsigned short* __restrict__ xib, const float* __restrict__ Alog,
                       const float* __restrict__ dtw, const float* __restrict__ dtb,
                       float* __restrict__ P, float* __restrict__ Q){
  __shared__ float dblS[CH*24];
  int b = blockIdx.y, c = blockIdx.x, dir = blockIdx.z;
  int d = threadIdx.x;
  const float* dblP = dbl + (size_t)dir*Bsz*Ll*40;
  const unsigned short* xiP = xib + (size_t)dir*Bsz*Ll*256;
  size_t base = (size_t)b*Ll + (size_t)c*CH;
  for (int idx=d; idx<CH*6; idx+=256){
    int p = idx/6, j = idx - p*6;
    *(float4*)&dblS[p*24 + j*4] = *(const float4*)&dblP[(base+p)*40 + j*4];
  }
  float A[16];
  #pragma unroll
  for (int j=0;j<4;j++){
    float4 a4 = *(const float4*)&Alog[(size_t)dir*4096 + d*16 + j*4];
    A[4*j]=-__expf(a4.x); A[4*j+1]=-__expf(a4.y); A[4*j+2]=-__expf(a4.z); A[4*j+3]=-__expf(a4.w);
  }
  bool chain = true;
  #pragma unroll
  for (int n=1;n<16;n++){
    float expect = A[0]*(float)(n+1);
    if (fabsf(A[n]-expect) > 1e-3f*fabsf(expect)) chain = false;
  }
  float wv[8];
  {
    const float* dw = dtw + (size_t)dir*2048 + d*8;
    float4 w0 = *(const float4*)&dw[0];
    float4 w1 = *(const float4*)&dw[4];
    wv[0]=w0.x; wv[1]=w0.y; wv[2]=w0.z; wv[3]=w0.w;
    wv[4]=w1.x; wv[5]=w1.y; wv[6]=w1.z; wv[7]=w1.w;
  }
  float bbt = dtb[dir*256 + d];
  __syncthreads();
  float h[16], pr[16];
  #pragma unroll
  for (int n=0;n<16;n++){ h[n]=0.f; pr[n]=1.f; }
  const unsigned short* xip = xiP + base*256 + d;
  if (chain){
    float A0 = A[0];
    float sdt = 0.f;
    for (int p=0;p<CH;p++){
      const float* rw = &dblS[p*24];
      float4 t0 = *(const float4*)&rw[0], t1 = *(const float4*)&rw[4];
      float a0 = bbt + t0.x*wv[0]+t0.y*wv[1]+t0.z*wv[2]+t0.w*wv[3]
                     + t1.x*wv[4]+t1.y*wv[5]+t1.z*wv[6]+t1.w*wv[7];
      float dtv = (a0>20.f)? a0 : __logf(1.f+__expf(a0));
      float xiv = bs2f(xip[(size_t)p*256]);
      float dx = dtv*xiv;
      sdt += dtv;
      float pw[16];
      float e1 = __expf(dtv*A0);
      POWTREE(e1, pw);
      float bc[16];
      *(float4*)&bc[0]  = *(const float4*)&rw[8];
      *(float4*)&bc[4]  = *(const float4*)&rw[12];
      *(float4*)&bc[8]  = *(const float4*)&rw[16];
      *(float4*)&bc[12] = *(const float4*)&rw[20];
      #pragma unroll
      for (int n=0;n<16;n++) h[n] = pw[n]*h[n] + bc[n]*dx;
    }
    float E = __expf(A0*sdt);
    POWTREE(E, pr);
  } else {
    for (int p=0;p<CH;p++){
      const float* rw = &dblS[p*24];
      float4 t0 = *(const float4*)&rw[0], t1 = *(const float4*)&rw[4];
      float a0 = bbt + t0.x*wv[0]+t0.y*wv[1]+t0.z*wv[2]+t0.w*wv[3]
                     + t1.x*wv[4]+t1.y*wv[5]+t1.z*wv[6]+t1.w*wv[7];
      float dtv = (a0>20.f)? a0 : __logf(1.f+__expf(a0));
      float xiv = bs2f(xip[(size_t)p*256]);
      float dx = dtv*xiv;
      float bc[16];
      *(float4*)&bc[0]  = *(const float4*)&rw[8];
      *(float4*)&bc[4]  = *(const float4*)&rw[12];
      *(float4*)&bc[8]  = *(const float4*)&rw[16];
      *(float4*)&bc[12] = *(const float4*)&rw[20];
      #pragma unroll
      for (int n=0;n<16;n++){
        float a = __expf(dtv*A[n]);
        h[n] = a*h[n] + bc[n]*dx;
        pr[n] *= a;
      }
    }
  }
  size_t sbase = (size_t)dir*Bsz*NC*4096 + ((size_t)(b*NC + c))*4096 + d*16;
  #pragma unroll
  for (int j=0;j<4;j++){
    *(float4*)&P[sbase + 4*j] = (float4){pr[4*j],pr[4*j+1],pr[4*j+2],pr[4*j+3]};
    *(float4*)&Q[sbase + 4*j] = (float4){h[4*j],h[4*j+1],h[4*j+2],h[4*j+3]};
  }
}

// In-place: Q[c] is read, then overwritten with the chunk-START state. float4/thread.
__global__ __launch_bounds__(256) void k_scan2(const float* __restrict__ P, float* __restrict__ Q){
  int b = blockIdx.y, dir = blockIdx.z;
  int dn4 = (blockIdx.x*256 + threadIdx.x)*4;   // 0..4095 step 4
  size_t plane = (size_t)dir*Bsz*NC*4096;
  float4 H = {0.f,0.f,0.f,0.f};
  for (int c=0;c<NC;c++){
    size_t idx = plane + ((size_t)(b*NC + c))*4096 + dn4;
    float4 p = *(const float4*)&P[idx];
    float4 q = *(const float4*)&Q[idx];
    *(float4*)&Q[idx] = H;
    H.x = p.x*H.x + q.x; H.y = p.y*H.y + q.y;
    H.z = p.z*H.z + q.z; H.w = p.w*H.w + q.w;
  }
}

// Phase 3: re-scan from start states; y = (sum_n h*Cc + Dp*xi)*silu(z),
// written IN-PLACE over the xi plane.
__global__ __launch_bounds__(256) void k_scan3(const float* __restrict__ dbl,
                       unsigned short* xiy, const float* __restrict__ Alog,
                       const float* __restrict__ dtw, const float* __restrict__ dtb,
                       const float* __restrict__ Dpw, const float* __restrict__ Hs,
                       const unsigned short* __restrict__ xz){
  __shared__ float dblS[CH*40];
  int b = blockIdx.y, c = blockIdx.x, dir = blockIdx.z;
  int d = threadIdx.x;
  const float* dblP = dbl + (size_t)dir*Bsz*Ll*40;
  unsigned short* xiP = xiy + (size_t)dir*Bsz*Ll*256;
  const unsigned short* xzP = xz + (size_t)dir*Bsz*Ll*512;
  size_t base = (size_t)b*Ll + (size_t)c*CH;
  for (int idx=d; idx<CH*10; idx+=256){
    int p = idx/10, j = idx - p*10;
    *(float4*)&dblS[p*40 + j*4] = *(const float4*)&dblP[(base+p)*40 + j*4];
  }
  float A[16];
  #pragma unroll
  for (int j=0;j<4;j++){
    float4 a4 = *(const float4*)&Alog[(size_t)dir*4096 + d*16 + j*4];
    A[4*j]=-__expf(a4.x); A[4*j+1]=-__expf(a4.y); A[4*j+2]=-__expf(a4.z); A[4*j+3]=-__expf(a4.w);
  }
  bool chain = true;
  #pragma unroll
  for (int n=1;n<16;n++){
    float expect = A[0]*(float)(n+1);
    if (fabsf(A[n]-expect) > 1e-3f*fabsf(expect)) chain = false;
  }
  float wv[8];
  {
    const float* dw = dtw + (size_t)dir*2048 + d*8;
    float4 w0 = *(const float4*)&dw[0];
    float4 w1 = *(const float4*)&dw[4];
    wv[0]=w0.x; wv[1]=w0.y; wv[2]=w0.z; wv[3]=w0.w;
    wv[4]=w1.x; wv[5]=w1.y; wv[6]=w1.z; wv[7]=w1.w;
  }
  float bbt = dtb[dir*256 + d];
  float Dp = Dpw[dir*256 + d];
  float h[16];
  size_t sbase = (size_t)dir*Bsz*NC*4096 + ((size_t)(b*NC + c))*4096 + d*16;
  #pragma unroll
  for (int j=0;j<4;j++){
    float4 h4 = *(const float4*)&Hs[sbase + 4*j];
    h[4*j]=h4.x; h[4*j+1]=h4.y; h[4*j+2]=h4.z; h[4*j+3]=h4.w;
  }
  __syncthreads();
  unsigned short* xip = xiP + base*256 + d;
  const unsigned short* zp = xzP + base*512 + 256 + d;
  if (chain){
    float A0 = A[0];
    for (int p=0;p<CH;p++){
      const float* rw = &dblS[p*40];
      float4 t0 = *(const float4*)&rw[0], t1 = *(const float4*)&rw[4];
      float a0 = bbt + t0.x*wv[0]+t0.y*wv[1]+t0.z*wv[2]+t0.w*wv[3]
                     + t1.x*wv[4]+t1.y*wv[5]+t1.z*wv[6]+t1.w*wv[7];
      float dtv = (a0>20.f)? a0 : __logf(1.f+__expf(a0));
      float xiv = bs2f(xip[(size_t)p*256]);
      float dx = dtv*xiv;
      float pw[16];
      float e1 = __expf(dtv*A0);
      POWTREE(e1, pw);
      float bc[16], cc[16];
      *(float4*)&bc[0]  = *(const float4*)&rw[8];
      *(float4*)&bc[4]  = *(const float4*)&rw[12];
      *(float4*)&bc[8]  = *(const float4*)&rw[16];
      *(float4*)&bc[12] = *(const float4*)&rw[20];
      *(float4*)&cc[0]  = *(const float4*)&rw[24];
      *(float4*)&cc[4]  = *(const float4*)&rw[28];
      *(float4*)&cc[8]  = *(const float4*)&rw[32];
      *(float4*)&cc[12] = *(const float4*)&rw[36];
      float acc = 0.f;
      #pragma unroll
      for (int n=0;n<16;n++){
        h[n] = pw[n]*h[n] + bc[n]*dx;
        acc += h[n]*cc[n];
      }
      float z = bs2f(zp[(size_t)p*512]);
      float g = z/(1.f+__expf(-z));
      xip[(size_t)p*256] = f2bs((acc + Dp*xiv)*g);
    }
  } else {
    for (int p=0;p<CH;p++){
      const float* rw = &dblS[p*40];
      float4 t0 = *(const float4*)&rw[0], t1 = *(const float4*)&rw[4];
      float a0 = bbt + t0.x*wv[0]+t0.y*wv[1]+t0.z*wv[2]+t0.w*wv[3]
                     + t1.x*wv[4]+t1.y*wv[5]+t1.z*wv[6]+t1.w*wv[7];
      float dtv = (a0>20.f)? a0 : __logf(1.f+__expf(a0));
      float xiv = bs2f(xip[(size_t)p*256]);
      float dx = dtv*xiv;
      float bc[16], cc[16];
      *(float4*)&bc[0]  = *(const float4*)&rw[8];
      *(float4*)&bc[4]  = *(const float4*)&rw[12];
      *(float4*)&bc[8]  = *(const float4*)&rw[16];
      *(float4*)&bc[12] = *(const float4*)&rw[20];
      *(float4*)&cc[0]  = *(const float4*)&rw[24];
      *(float4*)&cc[4]  = *(const float4*)&rw[28];
      *(float4*)&cc[8]  = *(const float4*)&rw[32];
      *(float4*)&cc[12] = *(const float4*)&rw[36];
      float acc = 0.f;
      #pragma unroll
      for (int n=0;n<16;n++){
        float a = __expf(dtv*A[n]);
        h[n] = a*h[n] + bc[n]*dx;
        acc += h[n]*cc[n];
      }
      float z = bs2f(zp[(size_t)p*512]);
      float g = z/(1.f+__expf(-z));
      xip[(size_t)p*256] = f2bs((acc + Dp*xiv)*g);
    }
  }
}

// final transpose (B,L,128) fp32 -> (B,128,L) fp32
__global__ __launch_bounds__(256) void k_final(const float* __restrict__ hres, float* __restrict__ out){
  __shared__ float tile[64*129];
  int b = blockIdx.y, l0 = blockIdx.x*64;
  int tid = threadIdx.x;
  for (int q=0;q<32;q++){
    int idx = q*256 + tid;
    int l = idx >> 7, c = idx & 127;
    tile[l*129 + c] = hres[((size_t)b*Ll + l0 + l)*128 + c];
  }
  __syncthreads();
  int lo = tid & 63; int cbase = tid >> 6;
  for (int q=0;q<32;q++){
    int c = cbase + q*4;
    out[((size_t)b*128 + c)*Ll + l0 + lo] = tile[lo*129 + c];
  }
}

extern "C" void kernel_launch(void* const* d_in, const int* in_sizes, int n_in,
                              void* d_out, int out_size, void* d_ws, size_t ws_size,
                              hipStream_t stream){
  const float* x      = (const float*)d_in[0];
  const float* skip   = (const float*)d_in[1];
  const float* up_w   = (const float*)d_in[2];
  const float* up_b   = (const float*)d_in[3];
  const float* fus_w  = (const float*)d_in[4];
  const float* fus_b  = (const float*)d_in[5];
  const float* gn_w   = (const float*)d_in[6];
  const float* gn_b   = (const float*)d_in[7];
  const float* pa     = (const float*)d_in[8];
  const float* ln_w   = (const float*)d_in[9];
  const float* ln_b   = (const float*)d_in[10];
  const float* in_w   = (const float*)d_in[11];
  const float* conv_w = (const float*)d_in[12];
  const float* conv_b = (const float*)d_in[13];
  const float* xproj_w= (const float*)d_in[14];
  const float* dtproj_w=(const float*)d_in[15];
  const float* dtproj_b=(const float*)d_in[16];
  const float* A_log  = (const float*)d_in[17];
  const float* Dp     = (const float*)d_in[18];
  const float* out_w  = (const float*)d_in[19];

  // Workspace (~87 MB; round-7 bracket: <=100 MB safe).
  float* w = (float*)d_ws;
  size_t off=0;
  float* B2 = w+off; off += 128;
  float* GST= w+off; off += 16;
  off = (off+3)&~(size_t)3;
  float* HR = w+off; off += (size_t)Bsz*Ll*128;
  float* DBL2= w+off; off += 2*(size_t)Bsz*Ll*40;
  unsigned short* XNB = (unsigned short*)(w+off); off += (size_t)Bsz*Ll*128/2;
  unsigned short* XZB2= (unsigned short*)(w+off); off += 2*(size_t)Bsz*Ll*512/2;
  unsigned short* IWB = (unsigned short*)(w+off); off += 2*2*512*128/2;
  unsigned short* OWB = (unsigned short*)(w+off); off += 2*2*128*256/2;
  unsigned short* WXB = (unsigned short*)(w+off); off += 2*2*64*256/2;
  unsigned short* WEb = (unsigned short*)(w+off); off += 768*128/2;
  unsigned short* WOb = (unsigned short*)(w+off); off += 512*128/2;
  unsigned short* FWSb= (unsigned short*)(w+off); off += 128*128/2;
  size_t planeS = (size_t)Bsz*NC*4096;       // 1,048,576 @ NC=64
  float* U1 = w+off; off += 4*planeS;
  unsigned short* XT  = (unsigned short*)U1;
  unsigned short* SKT = (unsigned short*)(U1 + 1049604);
  float* SP = U1;
  float* SQ = U1 + 2*planeS;
  float* U2 = w+off; off += 2*(size_t)Bsz*Ll*128;
  float* H0 = U2;
  unsigned short* XIB2 = (unsigned short*)U2;

  hipMemsetAsync(GST, 0, 16*sizeof(float), stream);
  k_cvt<<<(2*2*512*128+255)/256,256,0,stream>>>(in_w, IWB, 2*2*512*128);
  k_cvt<<<(2*2*128*256+255)/256,256,0,stream>>>(out_w, OWB, 2*2*128*256);
  k_prepx<<<dim3(64,4),256,0,stream>>>(xproj_w, WXB);
  k_compose<<<256,128,0,stream>>>(up_w, fus_w, fus_b, up_b, WEb, WOb, FWSb, B2);
  k_tx<<<dim3(Tt/64, 4, Bsz),256,0,stream>>>(x, XT);
  k_zero<<<1,256,0,stream>>>(XT);
  k_ts<<<dim3(Ll/64, 2, Bsz),256,0,stream>>>(skip, SKT);
  k_up<<<dim3(32, 2, Bsz),256,0,stream>>>(XT, SKT, WEb, WOb, FWSb, B2, H0, GST);
  k_gnfin<<<1,64,0,stream>>>(GST);
  k_gnln<<<Bsz*Ll/4,256,0,stream>>>(H0, gn_w, gn_b, pa, GST, ln_w, ln_b, HR, XNB);
  for (int i=0;i<2;i++){
    if (i==1) k_ln<<<Bsz*Ll/4,256,0,stream>>>(HR, ln_w + 128, ln_b + 128, XNB);
    k_gemm_in<<<dim3(128,4,2),256,0,stream>>>(XNB, IWB + (size_t)(i*2)*512*128, XZB2);
    k_xproj3<<<dim3(Bsz*Ll/64,2),256,0,stream>>>(XZB2, WXB + (size_t)(i*2)*64*256,
                                                 conv_w + (i*2)*1024, conv_b + (i*2)*256,
                                                 XIB2, DBL2);
    k_scan1<<<dim3(NC,Bsz,2),256,0,stream>>>(DBL2, XIB2, A_log + (i*2)*4096,
                                             dtproj_w + (i*2)*2048, dtproj_b + (i*2)*256, SP, SQ);
    k_scan2<<<dim3(4,Bsz,2),256,0,stream>>>(SP, SQ);
    k_scan3<<<dim3(NC,Bsz,2),256,0,stream>>>(DBL2, XIB2, A_log + (i*2)*4096,
                                             dtproj_w + (i*2)*2048, dtproj_b + (i*2)*256,
                                             Dp + (i*2)*256, SQ, XZB2);
    k_gemm_out<<<256,256,0,stream>>>(XIB2, OWB + (size_t)(i*2)*128*256, HR);
  }
  k_final<<<dim3(Ll/64,Bsz),256,0,stream>>>(HR, (float*)d_out);
}

// Round 15
// 438.188 us; speedup vs baseline: 1.6339x; 1.0325x over previous
//
#include <hip/hip_runtime.h>
#include <hip/hip_bf16.h>

#define Bsz 4
#define Tt 2048
#define Ll 4096
#define NC 128     // chunks for scan (1024 blocks/dispatch batched over dirs)
#define CH 32      // steps per chunk (NC*CH == Ll)

typedef short bf16x8 __attribute__((ext_vector_type(8)));
typedef float f32x4 __attribute__((ext_vector_type(4)));

static __device__ __forceinline__ float bs2f(unsigned short u){
  union{float f; unsigned int i;} v; v.i = ((unsigned int)u)<<16; return v.f;
}
static __device__ __forceinline__ unsigned short f2bs(float f){
  union{float f; unsigned int i;} v; v.f = f;
  unsigned int r = (v.i + 0x7fffu + ((v.i>>16)&1u)) >> 16;
  return (unsigned short)r;
}

// fp32 -> bf16 bulk convert
__global__ void k_cvt(const float* __restrict__ src, unsigned short* __restrict__ dst, int n){
  int i = blockIdx.x*256 + threadIdx.x;
  if (i < n) dst[i] = f2bs(src[i]);
}

// pad xproj_w (4 branches, 40x256) to zero-filled 64x256 bf16
__global__ void k_prepx(const float* __restrict__ xw, unsigned short* __restrict__ wxb){
  int row = blockIdx.x, br = blockIdx.y, col = threadIdx.x;
  float v = (row < 40) ? xw[((size_t)br*40 + row)*256 + col] : 0.f;
  wxb[((size_t)br*64 + row)*256 + col] = f2bs(v);
}

// ---------------------------------------------------------------------------
// Compose upsample-conv weights with fuse matmul; emit bf16 GEMM-ready layouts.
// ---------------------------------------------------------------------------
__global__ void k_compose(const float* __restrict__ up_w, const float* __restrict__ fus_w,
                          const float* __restrict__ fus_b, const float* __restrict__ up_b,
                          unsigned short* __restrict__ WEb, unsigned short* __restrict__ WOb,
                          unsigned short* __restrict__ FWSb, float* __restrict__ BIAS2){
  int i = blockIdx.x;     // 0..255
  int o = threadIdx.x;    // 0..127
  float a0=0.f,a1=0.f,a2=0.f,a3=0.f,a4=0.f;
  for (int c=0;c<256;c++){
    float f = fus_w[o*384+c];
    const float* w = up_w + ((size_t)i*256+c)*5;
    a0 += f*w[0]; a1 += f*w[1]; a2 += f*w[2];
    a3 += f*w[3]; a4 += f*w[4];
  }
  WEb[(size_t)o*768 +       i] = f2bs(a4);
  WEb[(size_t)o*768 + 256 + i] = f2bs(a2);
  WEb[(size_t)o*768 + 512 + i] = f2bs(a0);
  WOb[(size_t)o*512 +       i] = f2bs(a3);
  WOb[(size_t)o*512 + 256 + i] = f2bs(a1);
  if (i<128) FWSb[o*128 + i] = f2bs(fus_w[o*384+256+i]);
  if (i==0){
    float bb = fus_b[o];
    for (int c=0;c<256;c++) bb += fus_w[o*384+c]*up_b[c];
    BIAS2[o]=bb;
  }
}

// transpose x (B,256,T) f32 -> XT (B, T+2, 256) bf16, row t stored at t+1
__global__ __launch_bounds__(256) void k_tx(const float* __restrict__ x, unsigned short* __restrict__ XT){
  __shared__ float tile[64][65];
  int b=blockIdx.z, t0=blockIdx.x*64, i0=blockIdx.y*64;
  int tid=threadIdx.x;
  for (int it=0;it<16;it++){
    int idx=it*256+tid; int ii=idx>>6, tt=idx&63;
    tile[ii][tt] = x[((size_t)b*256+i0+ii)*Tt + t0+tt];
  }
  __syncthreads();
  for (int it=0;it<16;it++){
    int idx=it*256+tid; int tt=idx>>6, ii=idx&63;
    XT[((size_t)b*2050 + t0+tt+1)*256 + i0+ii] = f2bs(tile[ii][tt]);
  }
}

// zero XT halo rows (t=-1 and t=2048)
__global__ void k_zero(unsigned short* __restrict__ XT){
  int tid=threadIdx.x;
  for (int b=0;b<Bsz;b++){
    XT[((size_t)b*2050)*256 + tid] = 0;
    XT[((size_t)b*2050+2049)*256 + tid] = 0;
  }
}

// transpose skip (B,128,L) f32 -> SKT (B,L,128) bf16
__global__ __launch_bounds__(256) void k_ts(const float* __restrict__ skip, unsigned short* __restrict__ SKT){
  __shared__ float tile[64][65];
  int b=blockIdx.z, l0=blockIdx.x*64, s0=blockIdx.y*64;
  int tid=threadIdx.x;
  for (int it=0;it<16;it++){
    int idx=it*256+tid; int ss=idx>>6, ll=idx&63;
    tile[ss][ll] = skip[((size_t)b*128+s0+ss)*Ll + l0+ll];
  }
  __syncthreads();
  for (int it=0;it<16;it++){
    int idx=it*256+tid; int ll=idx>>6, ss=idx&63;
    SKT[((size_t)b*Ll + l0+ll)*128 + s0+ss] = f2bs(tile[ss][ll]);
  }
}

// ---------------------------------------------------------------------------
// MFMA upsample+fuse (see round-4 notes). Block = 64 t x 128 o, one parity.
// ---------------------------------------------------------------------------
__global__ __launch_bounds__(256) void k_up(const unsigned short* __restrict__ XT,
                     const unsigned short* __restrict__ SKT,
                     const unsigned short* __restrict__ WEb, const unsigned short* __restrict__ WOb,
                     const unsigned short* __restrict__ FWSb, const float* __restrict__ B2,
                     float* __restrict__ h0, float* __restrict__ gst){
  __shared__ unsigned short XL[66*264];
  __shared__ unsigned short Wb[128*72];
  __shared__ float red0[256], red1[256];
  int bt = blockIdx.x, par = blockIdx.y, b = blockIdx.z;
  int t0 = bt*64;
  int tid = threadIdx.x;
  int wave = tid>>6, lane = tid&63;
  int wm = wave>>1, wn = wave&1;
  int quad = lane>>4, l16 = lane&15;

  for (int idx=tid; idx<66*32; idx+=256){
    int row = idx>>5, c8 = idx&31;
    *(uint4*)&XL[row*264 + c8*8] = *(const uint4*)&XT[((size_t)b*2050 + t0 + row)*256 + c8*8];
  }

  const unsigned short* Wsrc = par ? WOb : WEb;
  const int Kw = par ? 512 : 768;
  const int tapbase = par ? 1 : 0;
  f32x4 acc[2][4];
  #pragma unroll
  for (int i=0;i<2;i++)
    #pragma unroll
    for (int j=0;j<4;j++) acc[i][j] = (f32x4){0.f,0.f,0.f,0.f};

  int nch = Kw>>6;
  for (int kc=0; kc<nch; kc++){
    __syncthreads();
    #pragma unroll
    for (int it=0; it<4; it++){
      int idx = it*256+tid;
      int row = idx>>3, c8 = idx&7;
      *(uint4*)&Wb[row*72 + c8*8] = *(const uint4*)&Wsrc[(size_t)row*Kw + kc*64 + c8*8];
    }
    __syncthreads();
    #pragma unroll
    for (int ks=0; ks<64; ks+=32){
      int kg = kc*64 + ks;
      int tap = kg>>8, ib = kg&255;
      bf16x8 af[2], bf[4];
      #pragma unroll
      for (int mt=0;mt<2;mt++)
        af[mt] = *(bf16x8*)&XL[(wm*32+mt*16+l16 + tapbase + tap)*264 + ib + quad*8];
      #pragma unroll
      for (int nt=0;nt<4;nt++)
        bf[nt] = *(bf16x8*)&Wb[(wn*64+nt*16+l16)*72 + ks + quad*8];
      #pragma unroll
      for (int mt=0;mt<2;mt++)
        #pragma unroll
        for (int nt=0;nt<4;nt++)
          acc[mt][nt] = __builtin_amdgcn_mfma_f32_16x16x32_bf16(af[mt], bf[nt], acc[mt][nt], 0,0,0);
    }
  }

  __syncthreads();
  for (int idx=tid; idx<64*16; idx+=256){
    int row = idx>>4, c8 = idx&15;
    *(uint4*)&XL[row*136 + c8*8] = *(const uint4*)&SKT[((size_t)b*Ll + 2*(t0+row)+par)*128 + c8*8];
  }
  for (int kc=0; kc<2; kc++){
    __syncthreads();
    #pragma unroll
    for (int it=0; it<4; it++){
      int idx = it*256+tid;
      int row = idx>>3, c8 = idx&7;
      *(uint4*)&Wb[row*72 + c8*8] = *(const uint4*)&FWSb[(size_t)row*128 + kc*64 + c8*8];
    }
    __syncthreads();
    #pragma unroll
    for (int ks=0; ks<64; ks+=32){
      bf16x8 af[2], bf[4];
      #pragma unroll
      for (int mt=0;mt<2;mt++)
        af[mt] = *(bf16x8*)&XL[(wm*32+mt*16+l16)*136 + kc*64 + ks + quad*8];
      #pragma unroll
      for (int nt=0;nt<4;nt++)
        bf[nt] = *(bf16x8*)&Wb[(wn*64+nt*16+l16)*72 + ks + quad*8];
      #pragma unroll
      for (int mt=0;mt<2;mt++)
        #pragma unroll
        for (int nt=0;nt<4;nt++)
          acc[mt][nt] = __builtin_amdgcn_mfma_f32_16x16x32_bf16(af[mt], bf[nt], acc[mt][nt], 0,0,0);
    }
  }

  float s1=0.f, s2=0.f;
  #pragma unroll
  for (int mt=0;mt<2;mt++)
    #pragma unroll
    for (int nt=0;nt<4;nt++)
      #pragma unroll
      for (int r=0;r<4;r++){
        int m = wm*32 + mt*16 + quad*4 + r;
        int lrow = 2*(t0+m) + par;
        int col = wn*64 + nt*16 + l16;
        float v = acc[mt][nt][r] + B2[col];
        h0[((size_t)b*Ll + lrow)*128 + col] = v;
        s1 += v; s2 += v*v;
      }
  red0[tid]=s1; red1[tid]=s2;
  __syncthreads();
  for (int st=128; st>0; st>>=1){
    if (tid<st){ red0[tid]+=red0[tid+st]; red1[tid]+=red1[tid+st]; }
    __syncthreads();
  }
  if (tid==0){ atomicAdd(&gst[b*2], red0[0]); atomicAdd(&gst[b*2+1], red1[0]); }
}

__global__ void k_gnfin(float* gst){
  int b = threadIdx.x;
  if (b < Bsz){
    float n = (float)Ll*128.f;
    float mu = gst[b*2]/n;
    float var = gst[b*2+1]/n - mu*mu;
    gst[8+b]=mu; gst[12+b]=rsqrtf(var+1e-5f);
  }
}

// Fused GroupNorm-apply + PReLU + layer-0 LayerNorm.
__global__ __launch_bounds__(256) void k_gnln(const float* __restrict__ h0, const float* __restrict__ gn_w,
                      const float* __restrict__ gn_b, const float* __restrict__ pa,
                      const float* __restrict__ gst, const float* __restrict__ lnw,
                      const float* __restrict__ lnb, float* __restrict__ hres,
                      unsigned short* __restrict__ xn){
  int row = blockIdx.x*4 + (threadIdx.x>>6);
  int lane = threadIdx.x & 63;
  int b = row >> 12;
  float mu_g = gst[8+b], inv_g = gst[12+b];
  float a = pa[0];
  const float* hp = h0 + (size_t)row*128;
  float u0 = (hp[lane]   -mu_g)*inv_g*gn_w[lane]    + gn_b[lane];
  float u1 = (hp[lane+64]-mu_g)*inv_g*gn_w[lane+64] + gn_b[lane+64];
  float v0 = u0>=0.f ? u0 : a*u0;
  float v1 = u1>=0.f ? u1 : a*u1;
  float* rp = hres + (size_t)row*128;
  rp[lane] = v0; rp[lane+64] = v1;
  float s = v0+v1, q = v0*v0+v1*v1;
  #pragma unroll
  for (int off=32; off>0; off>>=1){
    s += __shfl_xor(s, off, 64);
    q += __shfl_xor(q, off, 64);
  }
  float mu = s*(1.f/128.f);
  float rs = rsqrtf(q*(1.f/128.f)-mu*mu + 1e-5f);
  unsigned short* xp = xn + (size_t)row*128;
  xp[lane]    = f2bs((v0-mu)*rs*lnw[lane]    + lnb[lane]);
  xp[lane+64] = f2bs((v1-mu)*rs*lnw[lane+64] + lnb[lane+64]);
}

// LayerNorm over 128 ch; 4 rows/block, one wave per row. Writes bf16 XN.
__global__ __launch_bounds__(256) void k_ln(const float* __restrict__ hres, const float* __restrict__ lnw,
                     const float* __restrict__ lnb, unsigned short* __restrict__ xn){
  int row = blockIdx.x*4 + (threadIdx.x>>6);
  int lane = threadIdx.x & 63;
  const float* hp = hres + (size_t)row*128;
  float v0 = hp[lane], v1 = hp[lane+64];
  float s = v0+v1, q = v0*v0+v1*v1;
  #pragma unroll
  for (int off=32; off>0; off>>=1){
    s += __shfl_xor(s, off, 64);
    q += __shfl_xor(q, off, 64);
  }
  float mu = s*(1.f/128.f);
  float rs = rsqrtf(q*(1.f/128.f)-mu*mu + 1e-5f);
  unsigned short* xp = xn + (size_t)row*128;
  xp[lane]    = f2bs((v0-mu)*rs*lnw[lane]    + lnb[lane]);
  xp[lane+64] = f2bs((v1-mu)*rs*lnw[lane+64] + lnb[lane+64]);
}

// ---------------------------------------------------------------------------
// MFMA GEMM in_proj, batched over dirs (blockIdx.z): XZ2[dir] = rev_dir(XN) @ W_dir^T
// ---------------------------------------------------------------------------
__global__ __launch_bounds__(256) void k_gemm_in(const unsigned short* __restrict__ A,
                          const unsigned short* __restrict__ W,
                          unsigned short* __restrict__ C){
  __shared__ unsigned short As[128*72];
  __shared__ unsigned short Bs[128*72];
  int tid = threadIdx.x;
  int row0 = blockIdx.x*128;
  int n0   = blockIdx.y*128;
  int dir  = blockIdx.z;
  const unsigned short* Wp = W + (size_t)dir*512*128;
  unsigned short* Cp = C + (size_t)dir*Bsz*Ll*512;
  int wave = tid>>6, lane = tid&63;
  int wm = wave>>1, wn = wave&1;
  int quad = lane>>4, l16 = lane&15;
  f32x4 acc[4][4];
  #pragma unroll
  for (int i=0;i<4;i++)
    #pragma unroll
    for (int j=0;j<4;j++) acc[i][j] = (f32x4){0.f,0.f,0.f,0.f};

  for (int kb=0; kb<128; kb+=64){
    __syncthreads();
    #pragma unroll
    for (int it=0; it<4; it++){
      int idx = it*256 + tid;
      int row = idx>>3, c8 = idx&7;
      int r = row0 + row;
      int p = r & (Ll-1); int bb = r >> 12;
      int src = (bb<<12) + (dir ? (Ll-1-p) : p);
      *(uint4*)&As[row*72 + c8*8] = *(const uint4*)&A[(size_t)src*128 + kb + c8*8];
      *(uint4*)&Bs[row*72 + c8*8] = *(const uint4*)&Wp[(size_t)(n0+row)*128 + kb + c8*8];
    }
    __syncthreads();
    #pragma unroll
    for (int ks=0; ks<64; ks+=32){
      bf16x8 af[4], bf[4];
      #pragma unroll
      for (int mt=0;mt<4;mt++)
        af[mt] = *(bf16x8*)&As[(wm*64+mt*16+l16)*72 + ks + quad*8];
      #pragma unroll
      for (int nt=0;nt<4;nt++)
        bf[nt] = *(bf16x8*)&Bs[(wn*64+nt*16+l16)*72 + ks + quad*8];
      #pragma unroll
      for (int mt=0;mt<4;mt++)
        #pragma unroll
        for (int nt=0;nt<4;nt++)
          acc[mt][nt] = __builtin_amdgcn_mfma_f32_16x16x32_bf16(af[mt], bf[nt], acc[mt][nt], 0,0,0);
    }
  }
  #pragma unroll
  for (int mt=0;mt<4;mt++)
    #pragma unroll
    for (int nt=0;nt<4;nt++)
      #pragma unroll
      for (int r=0;r<4;r++){
        int row = row0 + wm*64 + mt*16 + quad*4 + r;
        int col = n0 + wn*64 + nt*16 + l16;
        Cp[(size_t)row*512 + col] = f2bs(acc[mt][nt][r]);
      }
}

// ---------------------------------------------------------------------------
// Combined out_proj: HR[l] += Y0[l]@W0^T + Y1[rev l]@W1^T  (K=512, both dirs)
// ---------------------------------------------------------------------------
__global__ __launch_bounds__(256) void k_gemm_out(const unsigned short* __restrict__ Y,
                           const unsigned short* __restrict__ W,
                           float* __restrict__ C){
  __shared__ unsigned short As[64*72];
  __shared__ unsigned short Bs[128*72];
  int tid = threadIdx.x;
  int row0 = blockIdx.x*64;
  int wave = tid>>6, lane = tid&63;
  int wm = wave>>1, wn = wave&1;
  int quad = lane>>4, l16 = lane&15;
  const size_t planeY = (size_t)Bsz*Ll*256;
  f32x4 acc[2][4];
  #pragma unroll
  for (int i=0;i<2;i++)
    #pragma unroll
    for (int j=0;j<4;j++) acc[i][j] = (f32x4){0.f,0.f,0.f,0.f};

  for (int kc=0; kc<8; kc++){
    int dirp = kc>>2;
    int kb = (kc&3)*64;
    const unsigned short* Wp = W + (size_t)dirp*128*256;
    __syncthreads();
    #pragma unroll
    for (int it=0; it<2; it++){
      int idx = it*256 + tid;
      int row = idx>>3, c8 = idx&7;
      int r = row0 + row;
      int p = r & (Ll-1); int bb = r >> 12;
      int srow = dirp ? ((bb<<12) + (Ll-1-p)) : r;
      *(uint4*)&As[row*72 + c8*8] = *(const uint4*)&Y[dirp*planeY + (size_t)srow*256 + kb + c8*8];
    }
    #pragma unroll
    for (int it=0; it<4; it++){
      int idx = it*256 + tid;
      int row = idx>>3, c8 = idx&7;
      *(uint4*)&Bs[row*72 + c8*8] = *(const uint4*)&Wp[(size_t)row*256 + kb + c8*8];
    }
    __syncthreads();
    #pragma unroll
    for (int ks=0; ks<64; ks+=32){
      bf16x8 af[2], bf[4];
      #pragma unroll
      for (int mt=0;mt<2;mt++)
        af[mt] = *(bf16x8*)&As[(wm*32+mt*16+l16)*72 + ks + quad*8];
      #pragma unroll
      for (int nt=0;nt<4;nt++)
        bf[nt] = *(bf16x8*)&Bs[(wn*64+nt*16+l16)*72 + ks + quad*8];
      #pragma unroll
      for (int mt=0;mt<2;mt++)
        #pragma unroll
        for (int nt=0;nt<4;nt++)
          acc[mt][nt] = __builtin_amdgcn_mfma_f32_16x16x32_bf16(af[mt], bf[nt], acc[mt][nt], 0,0,0);
    }
  }
  #pragma unroll
  for (int mt=0;mt<2;mt++)
    #pragma unroll
    for (int nt=0;nt<4;nt++)
      #pragma unroll
      for (int r=0;r<4;r++){
        int row = row0 + wm*32 + mt*16 + quad*4 + r;
        int col = wn*64 + nt*16 + l16;
        C[(size_t)row*128 + col] += acc[mt][nt][r];
      }
}

// ---------------------------------------------------------------------------
// Fused depthwise conv (K=4, sliding window) + SiLU + MFMA x_proj.
// ---------------------------------------------------------------------------
__global__ __launch_bounds__(256) void k_xproj3(const unsigned short* __restrict__ xz,
                        const unsigned short* __restrict__ wxb,
                        const float* __restrict__ cw, const float* __restrict__ cb,
                        unsigned short* __restrict__ xib, float* __restrict__ dbl){
  __shared__ unsigned short xiS[64*264];
  __shared__ unsigned short Bs[64*72];
  int tid = threadIdx.x;
  int dir = blockIdx.y;
  xz  += (size_t)dir*Bsz*Ll*512;
  wxb += (size_t)dir*64*256;
  cw  += dir*1024;
  cb  += dir*256;
  xib += (size_t)dir*Bsz*Ll*256;
  dbl += (size_t)dir*Bsz*Ll*40;
  size_t row0 = (size_t)blockIdx.x*64;
  int p0 = (int)(row0 & (Ll-1));

  {
    int d = tid;
    float4 w4 = *(const float4*)&cw[d*4];
    float bias = cb[d];
    float w0, w1, w2;
    if (p0 == 0){ w0=0.f; w1=0.f; w2=0.f; }
    else {
      w0 = bs2f(xz[(row0-3)*512 + d]);
      w1 = bs2f(xz[(row0-2)*512 + d]);
      w2 = bs2f(xz[(row0-1)*512 + d]);
    }
    #pragma unroll 4
    for (int rr=0; rr<64; rr++){
      float xv = bs2f(xz[(row0+rr)*512 + d]);
      float acc = bias + w4.x*w0 + w4.y*w1 + w4.z*w2 + w4.w*xv;
      float v = acc/(1.f+__expf(-acc));
      unsigned short us = f2bs(v);
      xiS[rr*264 + d] = us;
      xib[(row0+rr)*256 + d] = us;
      w0=w1; w1=w2; w2=xv;
    }
  }

  int wave = tid>>6, lane = tid&63;
  int quad = lane>>4, l16 = lane&15;
  f32x4 acc[4];
  #pragma unroll
  for (int j=0;j<4;j++) acc[j] = (f32x4){0.f,0.f,0.f,0.f};

  for (int kb=0; kb<256; kb+=64){
    __syncthreads();
    #pragma unroll
    for (int it=0; it<2; it++){
      int idx = it*256 + tid;
      int row = idx>>3, c8 = idx&7;
      *(uint4*)&Bs[row*72 + c8*8] = *(const uint4*)&wxb[(size_t)row*256 + kb + c8*8];
    }
    __syncthreads();
    #pragma unroll
    for (int ks=0; ks<64; ks+=32){
      bf16x8 af = *(bf16x8*)&xiS[(wave*16+l16)*264 + kb + ks + quad*8];
      #pragma unroll
      for (int nt=0;nt<4;nt++){
        bf16x8 bf = *(bf16x8*)&Bs[(nt*16+l16)*72 + ks + quad*8];
        acc[nt] = __builtin_amdgcn_mfma_f32_16x16x32_bf16(af, bf, acc[nt], 0,0,0);
      }
    }
  }
  #pragma unroll
  for (int nt=0;nt<4;nt++)
    #pragma unroll
    for (int r=0;r<4;r++){
      int m = wave*16 + quad*4 + r;
      int col = nt*16 + l16;
      if (col < 40) dbl[(row0+m)*40 + col] = acc[nt][r];
    }
}

// pw[n] = e1^(n+1) via squaring tree (depth 4, all independent FMAs after).
#define POWTREE(e1, pw) { \
  float e2 = (e1)*(e1); float e4 = e2*e2; float e8 = e4*e4; \
  pw[0]=(e1); pw[1]=e2; pw[2]=e2*(e1); pw[3]=e4; pw[4]=e4*(e1); pw[5]=e4*e2; \
  pw[6]=e4*pw[2]; pw[7]=e8; pw[8]=e8*(e1); pw[9]=e8*e2; pw[10]=e8*pw[2]; \
  pw[11]=e8*e4; pw[12]=e8*pw[4]; pw[13]=e8*pw[5]; pw[14]=e8*pw[6]; pw[15]=e8*e8; }

// ---------------------------------------------------------------------------
// Chunked scan, batched over dirs; dt computed on the fly from dbl[0:8]+dtw.
// ---------------------------------------------------------------------------
__global__ __launch_bounds__(256) void k_scan1(const float* __restrict__ dbl,
                       const unsigned short* __restrict__ xib, const float* __restrict__ Alog,
                       const float* __restrict__ dtw, const float* __restrict__ dtb,
                       float* __restrict__ P, float* __restrict__ Q){
  __shared__ float dblS[CH*24];
  int b = blockIdx.y, c = blockIdx.x, dir = blockIdx.z;
  int d = threadIdx.x;
  const float* dblP = dbl + (size_t)dir*Bsz*Ll*40;
  const unsigned short* xiP = xib + (size_t)dir*Bsz*Ll*256;
  size_t base = (size_t)b*Ll + (size_t)c*CH;
  if (d < CH*6){
    int p = d/6, j = d - p*6;
    *(float4*)&dblS[p*24 + j*4] = *(const float4*)&dblP[(base+p)*40 + j*4];
  }
  float A[16];
  #pragma unroll
  for (int j=0;j<4;j++){
    float4 a4 = *(const float4*)&Alog[(size_t)dir*4096 + d*16 + j*4];
    A[4*j]=-__expf(a4.x); A[4*j+1]=-__expf(a4.y); A[4*j+2]=-__expf(a4.z); A[4*j+3]=-__expf(a4.w);
  }
  bool chain = true;
  #pragma unroll
  for (int n=1;n<16;n++){
    float expect = A[0]*(float)(n+1);
    if (fabsf(A[n]-expect) > 1e-3f*fabsf(expect)) chain = false;
  }
  float wv[8];
  {
    const float* dw = dtw + (size_t)dir*2048 + d*8;
    float4 w0 = *(const float4*)&dw[0];
    float4 w1 = *(const float4*)&dw[4];
    wv[0]=w0.x; wv[1]=w0.y; wv[2]=w0.z; wv[3]=w0.w;
    wv[4]=w1.x; wv[5]=w1.y; wv[6]=w1.z; wv[7]=w1.w;
  }
  float bbt = dtb[dir*256 + d];
  __syncthreads();
  float h[16], pr[16];
  #pragma unroll
  for (int n=0;n<16;n++){ h[n]=0.f; pr[n]=1.f; }
  const unsigned short* xip = xiP + base*256 + d;
  if (chain){
    float A0 = A[0];
    float sdt = 0.f;
    #pragma unroll 2
    for (int p=0;p<CH;p++){
      const float* rw = &dblS[p*24];
      float4 t0 = *(const float4*)&rw[0], t1 = *(const float4*)&rw[4];
      float a0 = bbt + t0.x*wv[0]+t0.y*wv[1]+t0.z*wv[2]+t0.w*wv[3]
                     + t1.x*wv[4]+t1.y*wv[5]+t1.z*wv[6]+t1.w*wv[7];
      float dtv = (a0>20.f)? a0 : __logf(1.f+__expf(a0));
      float xiv = bs2f(xip[(size_t)p*256]);
      float dx = dtv*xiv;
      sdt += dtv;
      float pw[16];
      float e1 = __expf(dtv*A0);
      POWTREE(e1, pw);
      float bc[16];
      *(float4*)&bc[0]  = *(const float4*)&rw[8];
      *(float4*)&bc[4]  = *(const float4*)&rw[12];
      *(float4*)&bc[8]  = *(const float4*)&rw[16];
      *(float4*)&bc[12] = *(const float4*)&rw[20];
      #pragma unroll
      for (int n=0;n<16;n++) h[n] = pw[n]*h[n] + bc[n]*dx;
    }
    float E = __expf(A0*sdt);
    POWTREE(E, pr);
  } else {
    for (int p=0;p<CH;p++){
      const float* rw = &dblS[p*24];
      float4 t0 = *(const float4*)&rw[0], t1 = *(const float4*)&rw[4];
      float a0 = bbt + t0.x*wv[0]+t0.y*wv[1]+t0.z*wv[2]+t0.w*wv[3]
                     + t1.x*wv[4]+t1.y*wv[5]+t1.z*wv[6]+t1.w*wv[7];
      float dtv = (a0>20.f)? a0 : __logf(1.f+__expf(a0));
      float xiv = bs2f(xip[(size_t)p*256]);
      float dx = dtv*xiv;
      float bc[16];
      *(float4*)&bc[0]  = *(const float4*)&rw[8];
      *(float4*)&bc[4]  = *(const float4*)&rw[12];
      *(float4*)&bc[8]  = *(const float4*)&rw[16];
      *(float4*)&bc[12] = *(const float4*)&rw[20];
      #pragma unroll
      for (int n=0;n<16;n++){
        float a = __expf(dtv*A[n]);
        h[n] = a*h[n] + bc[n]*dx;
        pr[n] *= a;
      }
    }
  }
  size_t sbase = (size_t)dir*Bsz*NC*4096 + ((size_t)(b*NC + c))*4096 + d*16;
  #pragma unroll
  for (int j=0;j<4;j++){
    *(float4*)&P[sbase + 4*j] = (float4){pr[4*j],pr[4*j+1],pr[4*j+2],pr[4*j+3]};
    *(float4*)&Q[sbase + 4*j] = (float4){h[4*j],h[4*j+1],h[4*j+2],h[4*j+3]};
  }
}

// In-place: Q[c] is read, then overwritten with the chunk-START state.
// 64-thread blocks spread over 256 CUs; float4 per thread.
__global__ __launch_bounds__(64) void k_scan2(const float* __restrict__ P, float* __restrict__ Q){
  int b = blockIdx.y, dir = blockIdx.z;
  int dn4 = (blockIdx.x*64 + threadIdx.x)*4;   // 0..4095 step 4
  size_t plane = (size_t)dir*Bsz*NC*4096;
  float4 H = {0.f,0.f,0.f,0.f};
  for (int c=0;c<NC;c++){
    size_t idx = plane + ((size_t)(b*NC + c))*4096 + dn4;
    float4 p = *(const float4*)&P[idx];
    float4 q = *(const float4*)&Q[idx];
    *(float4*)&Q[idx] = H;
    H.x = p.x*H.x + q.x; H.y = p.y*H.y + q.y;
    H.z = p.z*H.z + q.z; H.w = p.w*H.w + q.w;
  }
}

// Phase 3: re-scan from start states; y written IN-PLACE over the xi plane.
__global__ __launch_bounds__(256) void k_scan3(const float* __restrict__ dbl,
                       unsigned short* xiy, const float* __restrict__ Alog,
                       const float* __restrict__ dtw, const float* __restrict__ dtb,
                       const float* __restrict__ Dpw, const float* __restrict__ Hs,
                       const unsigned short* __restrict__ xz){
  __shared__ float dblS[CH*40];
  int b = blockIdx.y, c = blockIdx.x, dir = blockIdx.z;
  int d = threadIdx.x;
  const float* dblP = dbl + (size_t)dir*Bsz*Ll*40;
  unsigned short* xiP = xiy + (size_t)dir*Bsz*Ll*256;
  const unsigned short* xzP = xz + (size_t)dir*Bsz*Ll*512;
  size_t base = (size_t)b*Ll + (size_t)c*CH;
  for (int idx=d; idx<CH*10; idx+=256){
    int p = idx/10, j = idx - p*10;
    *(float4*)&dblS[p*40 + j*4] = *(const float4*)&dblP[(base+p)*40 + j*4];
  }
  float A[16];
  #pragma unroll
  for (int j=0;j<4;j++){
    float4 a4 = *(const float4*)&Alog[(size_t)dir*4096 + d*16 + j*4];
    A[4*j]=-__expf(a4.x); A[4*j+1]=-__expf(a4.y); A[4*j+2]=-__expf(a4.z); A[4*j+3]=-__expf(a4.w);
  }
  bool chain = true;
  #pragma unroll
  for (int n=1;n<16;n++){
    float expect = A[0]*(float)(n+1);
    if (fabsf(A[n]-expect) > 1e-3f*fabsf(expect)) chain = false;
  }
  float wv[8];
  {
    const float* dw = dtw + (size_t)dir*2048 + d*8;
    float4 w0 = *(const float4*)&dw[0];
    float4 w1 = *(const float4*)&dw[4];
    wv[0]=w0.x; wv[1]=w0.y; wv[2]=w0.z; wv[3]=w0.w;
    wv[4]=w1.x; wv[5]=w1.y; wv[6]=w1.z; wv[7]=w1.w;
  }
  float bbt = dtb[dir*256 + d];
  float Dp = Dpw[dir*256 + d];
  float h[16];
  size_t sbase = (size_t)dir*Bsz*NC*4096 + ((size_t)(b*NC + c))*4096 + d*16;
  #pragma unroll
  for (int j=0;j<4;j++){
    float4 h4 = *(const float4*)&Hs[sbase + 4*j];
    h[4*j]=h4.x; h[4*j+1]=h4.y; h[4*j+2]=h4.z; h[4*j+3]=h4.w;
  }
  __syncthreads();
  unsigned short* xip = xiP + base*256 + d;
  const unsigned short* zp = xzP + base*512 + 256 + d;
  if (chain){
    float A0 = A[0];
    #pragma unroll 2
    for (int p=0;p<CH;p++){
      const float* rw = &dblS[p*40];
      float4 t0 = *(const float4*)&rw[0], t1 = *(const float4*)&rw[4];
      float a0 = bbt + t0.x*wv[0]+t0.y*wv[1]+t0.z*wv[2]+t0.w*wv[3]
                     + t1.x*wv[4]+t1.y*wv[5]+t1.z*wv[6]+t1.w*wv[7];
      float dtv = (a0>20.f)? a0 : __logf(1.f+__expf(a0));
      float xiv = bs2f(xip[(size_t)p*256]);
      float dx = dtv*xiv;
      float pw[16];
      float e1 = __expf(dtv*A0);
      POWTREE(e1, pw);
      float bc[16], cc[16];
      *(float4*)&bc[0]  = *(const float4*)&rw[8];
      *(float4*)&bc[4]  = *(const float4*)&rw[12];
      *(float4*)&bc[8]  = *(const float4*)&rw[16];
      *(float4*)&bc[12] = *(const float4*)&rw[20];
      *(float4*)&cc[0]  = *(const float4*)&rw[24];
      *(float4*)&cc[4]  = *(const float4*)&rw[28];
      *(float4*)&cc[8]  = *(const float4*)&rw[32];
      *(float4*)&cc[12] = *(const float4*)&rw[36];
      float acc = 0.f;
      #pragma unroll
      for (int n=0;n<16;n++){
        h[n] = pw[n]*h[n] + bc[n]*dx;
        acc += h[n]*cc[n];
      }
      float z = bs2f(zp[(size_t)p*512]);
      float g = z/(1.f+__expf(-z));
      xip[(size_t)p*256] = f2bs((acc + Dp*xiv)*g);
    }
  } else {
    for (int p=0;p<CH;p++){
      const float* rw = &dblS[p*40];
      float4 t0 = *(const float4*)&rw[0], t1 = *(const float4*)&rw[4];
      float a0 = bbt + t0.x*wv[0]+t0.y*wv[1]+t0.z*wv[2]+t0.w*wv[3]
                     + t1.x*wv[4]+t1.y*wv[5]+t1.z*wv[6]+t1.w*wv[7];
      float dtv = (a0>20.f)? a0 : __logf(1.f+__expf(a0));
      float xiv = bs2f(xip[(size_t)p*256]);
      float dx = dtv*xiv;
      float bc[16], cc[16];
      *(float4*)&bc[0]  = *(const float4*)&rw[8];
      *(float4*)&bc[4]  = *(const float4*)&rw[12];
      *(float4*)&bc[8]  = *(const float4*)&rw[16];
      *(float4*)&bc[12] = *(const float4*)&rw[20];
      *(float4*)&cc[0]  = *(const float4*)&rw[24];
      *(float4*)&cc[4]  = *(const float4*)&rw[28];
      *(float4*)&cc[8]  = *(const float4*)&rw[32];
      *(float4*)&cc[12] = *(const float4*)&rw[36];
      float acc = 0.f;
      #pragma unroll
      for (int n=0;n<16;n++){
        float a = __expf(dtv*A[n]);
        h[n] = a*h[n] + bc[n]*dx;
        acc += h[n]*cc[n];
      }
      float z = bs2f(zp[(size_t)p*512]);
      float g = z/(1.f+__expf(-z));
      xip[(size_t)p*256] = f2bs((acc + Dp*xiv)*g);
    }
  }
}

// final transpose (B,L,128) fp32 -> (B,128,L) fp32
__global__ __launch_bounds__(256) void k_final(const float* __restrict__ hres, float* __restrict__ out){
  __shared__ float tile[64*129];
  int b = blockIdx.y, l0 = blockIdx.x*64;
  int tid = threadIdx.x;
  for (int q=0;q<32;q++){
    int idx = q*256 + tid;
    int l = idx >> 7, c = idx & 127;
    tile[l*129 + c] = hres[((size_t)b*Ll + l0 + l)*128 + c];
  }
  __syncthreads();
  int lo = tid & 63; int cbase = tid >> 6;
  for (int q=0;q<32;q++){
    int c = cbase + q*4;
    out[((size_t)b*128 + c)*Ll + l0 + lo] = tile[lo*129 + c];
  }
}

extern "C" void kernel_launch(void* const* d_in, const int* in_sizes, int n_in,
                              void* d_out, int out_size, void* d_ws, size_t ws_size,
                              hipStream_t stream){
  const float* x      = (const float*)d_in[0];
  const float* skip   = (const float*)d_in[1];
  const float* up_w   = (const float*)d_in[2];
  const float* up_b   = (const float*)d_in[3];
  const float* fus_w  = (const float*)d_in[4];
  const float* fus_b  = (const float*)d_in[5];
  const float* gn_w   = (const float*)d_in[6];
  const float* gn_b   = (const float*)d_in[7];
  const float* pa     = (const float*)d_in[8];
  const float* ln_w   = (const float*)d_in[9];
  const float* ln_b   = (const float*)d_in[10];
  const float* in_w   = (const float*)d_in[11];
  const float* conv_w = (const float*)d_in[12];
  const float* conv_b = (const float*)d_in[13];
  const float* xproj_w= (const float*)d_in[14];
  const float* dtproj_w=(const float*)d_in[15];
  const float* dtproj_b=(const float*)d_in[16];
  const float* A_log  = (const float*)d_in[17];
  const float* Dp     = (const float*)d_in[18];
  const float* out_w  = (const float*)d_in[19];

  // Workspace ~86 MB (<=100 MB bracket). U1 holds XT+SKT (preamble) then
  // SP/SQ (loop, NC=128, scan2 in-place). U2 holds H0 then XIB2.
  float* w = (float*)d_ws;
  size_t off=0;
  float* B2 = w+off; off += 128;
  float* GST= w+off; off += 16;
  off = (off+3)&~(size_t)3;
  float* HR = w+off; off += (size_t)Bsz*Ll*128;
  float* DBL2= w+off; off += 2*(size_t)Bsz*Ll*40;
  unsigned short* XNB = (unsigned short*)(w+off); off += (size_t)Bsz*Ll*128/2;
  unsigned short* XZB2= (unsigned short*)(w+off); off += 2*(size_t)Bsz*Ll*512/2;
  unsigned short* IWB = (unsigned short*)(w+off); off += 2*2*512*128/2;
  unsigned short* OWB = (unsigned short*)(w+off); off += 2*2*128*256/2;
  unsigned short* WXB = (unsigned short*)(w+off); off += 2*2*64*256/2;
  unsigned short* WEb = (unsigned short*)(w+off); off += 768*128/2;
  unsigned short* WOb = (unsigned short*)(w+off); off += 512*128/2;
  unsigned short* FWSb= (unsigned short*)(w+off); off += 128*128/2;
  size_t planeS = (size_t)Bsz*NC*4096;       // 2,097,152 @ NC=128
  float* U1 = w+off; off += 4*planeS;
  unsigned short* XT  = (unsigned short*)U1;
  unsigned short* SKT = (unsigned short*)(U1 + 1049604);
  float* SP = U1;
  float* SQ = U1 + 2*planeS;
  float* U2 = w+off; off += 2*(size_t)Bsz*Ll*128;
  float* H0 = U2;
  unsigned short* XIB2 = (unsigned short*)U2;

  hipMemsetAsync(GST, 0, 16*sizeof(float), stream);
  k_cvt<<<(2*2*512*128+255)/256,256,0,stream>>>(in_w, IWB, 2*2*512*128);
  k_cvt<<<(2*2*128*256+255)/256,256,0,stream>>>(out_w, OWB, 2*2*128*256);
  k_prepx<<<dim3(64,4),256,0,stream>>>(xproj_w, WXB);
  k_compose<<<256,128,0,stream>>>(up_w, fus_w, fus_b, up_b, WEb, WOb, FWSb, B2);
  k_tx<<<dim3(Tt/64, 4, Bsz),256,0,stream>>>(x, XT);
  k_zero<<<1,256,0,stream>>>(XT);
  k_ts<<<dim3(Ll/64, 2, Bsz),256,0,stream>>>(skip, SKT);
  k_up<<<dim3(32, 2, Bsz),256,0,stream>>>(XT, SKT, WEb, WOb, FWSb, B2, H0, GST);
  k_gnfin<<<1,64,0,stream>>>(GST);
  k_gnln<<<Bsz*Ll/4,256,0,stream>>>(H0, gn_w, gn_b, pa, GST, ln_w, ln_b, HR, XNB);
  for (int i=0;i<2;i++){
    if (i==1) k_ln<<<Bsz*Ll/4,256,0,stream>>>(HR, ln_w + 128, ln_b + 128, XNB);
    k_gemm_in<<<dim3(128,4,2),256,0,stream>>>(XNB, IWB + (size_t)(i*2)*512*128, XZB2);
    k_xproj3<<<dim3(Bsz*Ll/64,2),256,0,stream>>>(XZB2, WXB + (size_t)(i*2)*64*256,
                                                 conv_w + (i*2)*1024, conv_b + (i*2)*256,
                                                 XIB2, DBL2);
    k_scan1<<<dim3(NC,Bsz,2),256,0,stream>>>(DBL2, XIB2, A_log + (i*2)*4096,
                                             dtproj_w + (i*2)*2048, dtproj_b + (i*2)*256, SP, SQ);
    k_scan2<<<dim3(16,Bsz,2),64,0,stream>>>(SP, SQ);
    k_scan3<<<dim3(NC,Bsz,2),256,0,stream>>>(DBL2, XIB2, A_log + (i*2)*4096,
                                             dtproj_w + (i*2)*2048, dtproj_b + (i*2)*256,
                                             Dp + (i*2)*256, SQ, XZB2);
    k_gemm_out<<<256,256,0,stream>>>(XIB2, OWB + (size_t)(i*2)*128*256, HR);
  }
  k_final<<<dim3(Ll/64,Bsz),256,0,stream>>>(HR, (float*)d_out);
}